// Round 1
// baseline (2904.940 us; speedup 1.0000x reference)
//
#include <hip/hip_runtime.h>

#define D_DIM 2048
#define H_DIM 8192
#define NTOK  4096
#define R_DIM 16
#define DEPTH 2

typedef float f32x4 __attribute__((ext_vector_type(4)));
typedef __bf16 bf16x8 __attribute__((ext_vector_type(8)));
typedef unsigned short u16x4 __attribute__((ext_vector_type(4)));
typedef unsigned short u16x8 __attribute__((ext_vector_type(8)));

typedef __attribute__((address_space(1))) void void_g;
typedef __attribute__((address_space(3))) void void_l;

__device__ __forceinline__ unsigned short f2bf(float f){
  __bf16 b = (__bf16)f;
  return __builtin_bit_cast(unsigned short, b);
}

__device__ __forceinline__ float wredf(float v){
#pragma unroll
  for(int o=32;o;o>>=1) v += __shfl_xor(v,o,64);
  return v;
}
__device__ __forceinline__ double wredd(double v){
#pragma unroll
  for(int o=32;o;o>>=1) v += __shfl_xor(v,o,64);
  return v;
}

__device__ __forceinline__ void gload_lds16(const void* g, void* l){
  __builtin_amdgcn_global_load_lds((void_g*)g, (void_l*)l, 16, 0, 0);
}

// ---------------------------------------------------------------------------
// Row pass 1: xn = rms_norm(x, nw) -> bf16 ; active = sigmoid(xn . rw) > 0.35
// one block per row, 256 threads, 8 elems/thread
// ---------------------------------------------------------------------------
__global__ __launch_bounds__(256) void rowpass1(
    const float* __restrict__ x, const float* __restrict__ nw,
    const float* __restrict__ rw, unsigned short* __restrict__ xn,
    float* __restrict__ act)
{
  const int row = blockIdx.x, tid = threadIdx.x;
  const int lane = tid & 63, wid = tid >> 6;
  const float* xr = x + (size_t)row*D_DIM + tid*8;
  f32x4 v0 = *(const f32x4*)xr;
  f32x4 v1 = *(const f32x4*)(xr+4);
  float ssq = 0.0f;
#pragma unroll
  for(int j=0;j<4;++j) ssq += v0[j]*v0[j] + v1[j]*v1[j];
  __shared__ float red[4];
  float t = wredf(ssq);
  if(lane==0) red[wid] = t;
  __syncthreads();
  const float rs = rsqrtf((red[0]+red[1]+red[2]+red[3])*(1.0f/D_DIM) + 1e-6f);

  f32x4 n0 = *(const f32x4*)(nw + tid*8);
  f32x4 n1 = *(const f32x4*)(nw + tid*8 + 4);
  f32x4 r0 = *(const f32x4*)(rw + tid*8);
  f32x4 r1 = *(const f32x4*)(rw + tid*8 + 4);
  float gp = 0.0f;
  u16x4 o0, o1;
#pragma unroll
  for(int j=0;j<4;++j){
    float a = v0[j]*rs*n0[j];
    float b = v1[j]*rs*n1[j];
    gp += a*r0[j] + b*r1[j];
    o0[j] = f2bf(a);
    o1[j] = f2bf(b);
  }
  unsigned short* xp = xn + (size_t)row*D_DIM + tid*8;
  *(u16x4*)xp = o0;
  *(u16x4*)(xp+4) = o1;

  float gd = wredf(gp);
  __syncthreads();            // red reuse
  if(lane==0) red[wid] = gd;
  __syncthreads();
  if(tid==0){
    float dot = red[0]+red[1]+red[2]+red[3];
    float g = 1.0f/(1.0f+expf(-dot));
    act[row] = (g > 0.35f) ? 1.0f : 0.0f;
  }
}

// ---------------------------------------------------------------------------
// Row pass 2 (ARL fused + next RMSNorm):
//  xn2 = rms_norm(x, anw); low = (xn2 @ U) * (S*keep); x += (low @ V)*agam;
//  xn3 = rms_norm(x, bnw) -> bf16
// ---------------------------------------------------------------------------
__global__ __launch_bounds__(256) void rowpass2(
    float* __restrict__ x, const float* __restrict__ anw,
    const float* __restrict__ U, const float* __restrict__ Sv,
    const float* __restrict__ V, const float* __restrict__ agam,
    const float* __restrict__ bnw, unsigned short* __restrict__ xn3)
{
  const int row = blockIdx.x, tid = threadIdx.x;
  const int lane = tid & 63, wid = tid >> 6;
  float* xr = x + (size_t)row*D_DIM + tid*8;
  f32x4 v0 = *(const f32x4*)xr;
  f32x4 v1 = *(const f32x4*)(xr+4);
  float ssq = 0.0f;
#pragma unroll
  for(int j=0;j<4;++j) ssq += v0[j]*v0[j] + v1[j]*v1[j];
  __shared__ float red[4];
  float t = wredf(ssq);
  if(lane==0) red[wid] = t;
  __syncthreads();
  const float rs = rsqrtf((red[0]+red[1]+red[2]+red[3])*(1.0f/D_DIM) + 1e-6f);

  f32x4 a0 = *(const f32x4*)(anw + tid*8);
  f32x4 a1 = *(const f32x4*)(anw + tid*8 + 4);
  float xn2[8];
#pragma unroll
  for(int j=0;j<4;++j){ xn2[j] = v0[j]*rs*a0[j]; xn2[4+j] = v1[j]*rs*a1[j]; }

  float pl[16];
#pragma unroll
  for(int r2=0;r2<16;++r2) pl[r2] = 0.0f;
#pragma unroll
  for(int j=0;j<8;++j){
    const int k = tid*8 + j;
    const f32x4* Up = (const f32x4*)(U + (size_t)k*R_DIM);
    f32x4 u0=Up[0], u1=Up[1], u2=Up[2], u3=Up[3];
    const float xv = xn2[j];
#pragma unroll
    for(int q=0;q<4;++q){
      pl[q]    += xv*u0[q];
      pl[4+q]  += xv*u1[q];
      pl[8+q]  += xv*u2[q];
      pl[12+q] += xv*u3[q];
    }
  }
#pragma unroll
  for(int r2=0;r2<16;++r2) pl[r2] = wredf(pl[r2]);
  __shared__ float lred[4][16];
  if(lane==0){
#pragma unroll
    for(int r2=0;r2<16;++r2) lred[wid][r2] = pl[r2];
  }
  __syncthreads();
  __shared__ float lowS[16];
  if(tid==0){
    float sa[16]; float totS = 0.0f;
#pragma unroll
    for(int r2=0;r2<16;++r2){ sa[r2] = fabsf(Sv[r2]); totS += sa[r2]; }
    totS = fmaxf(totS, 1e-8f);
    float c = 0.0f;
#pragma unroll
    for(int r2=0;r2<16;++r2){
      float lraw = lred[0][r2]+lred[1][r2]+lred[2][r2]+lred[3][r2];
      float keep = (r2==0) ? 1.0f : ((c/totS < 0.95f) ? 1.0f : 0.0f);
      c += sa[r2];
      lowS[r2] = lraw * Sv[r2] * keep;
    }
  }
  __syncthreads();

  f32x4 d0 = {0,0,0,0}, d1 = {0,0,0,0};
#pragma unroll
  for(int r2=0;r2<16;++r2){
    const float lr = lowS[r2];
    const f32x4* Vp = (const f32x4*)(V + (size_t)r2*D_DIM + tid*8);
    f32x4 q0 = Vp[0], q1 = Vp[1];
#pragma unroll
    for(int j=0;j<4;++j){ d0[j] += lr*q0[j]; d1[j] += lr*q1[j]; }
  }
  f32x4 g0 = *(const f32x4*)(agam + tid*8);
  f32x4 g1 = *(const f32x4*)(agam + tid*8 + 4);
  f32x4 xo0, xo1;
  float ssq2 = 0.0f;
#pragma unroll
  for(int j=0;j<4;++j){
    xo0[j] = v0[j] + d0[j]*g0[j];
    xo1[j] = v1[j] + d1[j]*g1[j];
    ssq2 += xo0[j]*xo0[j] + xo1[j]*xo1[j];
  }
  __syncthreads();            // red reuse
  float t2 = wredf(ssq2);
  if(lane==0) red[wid] = t2;
  __syncthreads();
  const float rs2 = rsqrtf((red[0]+red[1]+red[2]+red[3])*(1.0f/D_DIM) + 1e-6f);
  f32x4 b0 = *(const f32x4*)(bnw + tid*8);
  f32x4 b1 = *(const f32x4*)(bnw + tid*8 + 4);
  u16x4 o0, o1;
#pragma unroll
  for(int j=0;j<4;++j){
    o0[j] = f2bf(xo0[j]*rs2*b0[j]);
    o1[j] = f2bf(xo1[j]*rs2*b1[j]);
  }
  *(f32x4*)xr = xo0;
  *(f32x4*)(xr+4) = xo1;
  unsigned short* xp = xn3 + (size_t)row*D_DIM + tid*8;
  *(u16x4*)xp = o0;
  *(u16x4*)(xp+4) = o1;
}

// ---------------------------------------------------------------------------
// Ternary quantization: two-stage deterministic absmean + quantize to bf16
// ---------------------------------------------------------------------------
__global__ __launch_bounds__(256) void abs_part(const float* __restrict__ w,
                                                double* __restrict__ part)
{
  const long long n4 = (long long)H_DIM*D_DIM/4;
  const int tid = threadIdx.x;
  const int lane = tid & 63, wid = tid >> 6;
  float s = 0.0f;
  for(long long i = (long long)blockIdx.x*256 + tid; i < n4;
      i += (long long)gridDim.x*256){
    f32x4 v = ((const f32x4*)w)[i];
    s += fabsf(v[0]) + fabsf(v[1]) + fabsf(v[2]) + fabsf(v[3]);
  }
  double ds = wredd((double)s);
  __shared__ double sred[4];
  if(lane==0) sred[wid] = ds;
  __syncthreads();
  if(tid==0) part[blockIdx.x] = sred[0]+sred[1]+sred[2]+sred[3];
}

__global__ __launch_bounds__(256) void abs_final(const double* __restrict__ part,
                                                 float* __restrict__ scale)
{
  const int tid = threadIdx.x;
  const int lane = tid & 63, wid = tid >> 6;
  double s = 0.0;
  for(int i=tid;i<1024;i+=256) s += part[i];
  s = wredd(s);
  __shared__ double sred[4];
  if(lane==0) sred[wid] = s;
  __syncthreads();
  if(tid==0){
    double m = (sred[0]+sred[1]+sred[2]+sred[3]) / ((double)H_DIM*(double)D_DIM);
    scale[0] = (float)fmax(m, 1e-8);
  }
}

__global__ __launch_bounds__(256) void tquant(const float* __restrict__ w,
                                              const float* __restrict__ scale,
                                              unsigned short* __restrict__ q)
{
  const long long n4 = (long long)H_DIM*D_DIM/4;
  const float s = scale[0];
  for(long long i = (long long)blockIdx.x*256 + threadIdx.x; i < n4;
      i += (long long)gridDim.x*256){
    f32x4 v = ((const f32x4*)w)[i];
    u16x4 o;
#pragma unroll
    for(int j=0;j<4;++j){
      float r = rintf(v[j]/s);
      r = fminf(1.0f, fmaxf(-1.0f, r));
      o[j] = f2bf(r*s);
    }
    ((u16x4*)q)[i] = o;
  }
}

// ---------------------------------------------------------------------------
// GEMM: C[M,Nout] = A[M,K](bf16) @ B[Nout,K]^T, 128x128 tile, BK=32,
// 4 waves (2x2), 16x16x32 bf16 MFMA. Fused epilogues:
//  EPI 0: dual-B -> obf = bf16(silu(accB0) * accB1)     (SwiGLU)
//  EPI 1: obf = bf16(silu(acc))                          (BitLinear up)
//  EPI 2: xacc += act[row] ? acc*gamma[col] : 0          (ACB residual)
//  EPI 3: xacc += acc*gamma[col]                         (BitLinear residual)
// BBF16: B already bf16 (global_load_lds); else fp32 reg-staged + cvt.
// ---------------------------------------------------------------------------
template<int EPI, bool BBF16, bool DUAL>
__global__ __launch_bounds__(256, DUAL?2:3) void gemm128(
    const unsigned short* __restrict__ A,
    const void* __restrict__ B0v,
    const void* __restrict__ B1v,
    const int Nout, const int K,
    unsigned short* __restrict__ obf,
    float* __restrict__ xacc,
    const float* __restrict__ gamma,
    const float* __restrict__ act)
{
  __shared__ __align__(16) unsigned short smA[128*32];
  __shared__ __align__(16) unsigned short smB[128*32];
  __shared__ __align__(16) unsigned short smB2[DUAL?(128*32):8];

  const int tid  = threadIdx.x;
  const int lane = tid & 63;
  const int wid  = tid >> 6;
  const int wr   = wid >> 1;
  const int wc   = wid & 1;
  const int frow = lane & 15;
  const int k16  = lane >> 4;

  const int nbx = Nout >> 7;
  const int nwg = (int)gridDim.x;
  const int bid = (int)blockIdx.x;
  const int swz = ((bid & 7) * (nwg >> 3)) + (bid >> 3);   // nwg % 8 == 0 always here
  const int rowBase = (swz / nbx) << 7;
  const int colBase = (swz % nbx) << 7;

  int srow[2], schk[2];
#pragma unroll
  for(int r=0;r<2;++r){
    int t = tid + (r<<8);
    srow[r] = t >> 2;
    schk[r] = (t & 3) ^ ((srow[r] >> 1) & 3);   // XOR swizzle (bank-conflict fix)
  }

  const f32x4 vzero = {0.0f,0.0f,0.0f,0.0f};
  f32x4 acc[4][4];
  f32x4 acc2[4][4];
#pragma unroll
  for(int m=0;m<4;++m)
#pragma unroll
    for(int n=0;n<4;++n){ acc[m][n] = vzero; acc2[m][n] = vzero; }

  for(int k0=0;k0<K;k0+=32){
    // ---- stage A (bf16, async direct-to-LDS, pre-swizzled source)
#pragma unroll
    for(int r=0;r<2;++r){
      const unsigned short* s = A + (size_t)(rowBase+srow[r])*K + k0 + schk[r]*8;
      gload_lds16(s, &smA[((r<<8)+(wid<<6))*8]);
    }
    // ---- stage B
    if constexpr (BBF16){
      const unsigned short* B0 = (const unsigned short*)B0v;
#pragma unroll
      for(int r=0;r<2;++r){
        const unsigned short* s = B0 + (size_t)(colBase+srow[r])*K + k0 + schk[r]*8;
        gload_lds16(s, &smB[((r<<8)+(wid<<6))*8]);
      }
    } else {
      const float* B0 = (const float*)B0v;
#pragma unroll
      for(int r=0;r<2;++r){
        const float* s = B0 + (size_t)(colBase+srow[r])*K + k0 + schk[r]*8;
        f32x4 f0 = *(const f32x4*)s;
        f32x4 f1 = *(const f32x4*)(s+4);
        u16x8 o;
#pragma unroll
        for(int j=0;j<4;++j){ o[j] = f2bf(f0[j]); o[4+j] = f2bf(f1[j]); }
        *(u16x8*)&smB[(size_t)(tid+(r<<8))*8] = o;
      }
      if constexpr (DUAL){
        const float* B1 = (const float*)B1v;
#pragma unroll
        for(int r=0;r<2;++r){
          const float* s = B1 + (size_t)(colBase+srow[r])*K + k0 + schk[r]*8;
          f32x4 f0 = *(const f32x4*)s;
          f32x4 f1 = *(const f32x4*)(s+4);
          u16x8 o;
#pragma unroll
          for(int j=0;j<4;++j){ o[j] = f2bf(f0[j]); o[4+j] = f2bf(f1[j]); }
          *(u16x8*)&smB2[(size_t)(tid+(r<<8))*8] = o;
        }
      }
    }
    __syncthreads();

    bf16x8 af[4];
#pragma unroll
    for(int m=0;m<4;++m){
      int rr = (wr<<6)+(m<<4)+frow;
      int ch = k16 ^ ((rr>>1)&3);
      af[m] = *(const bf16x8*)&smA[rr*32 + ch*8];
    }
    bf16x8 bfr[4];
    bf16x8 bfr2[4];
#pragma unroll
    for(int n=0;n<4;++n){
      int rr = (wc<<6)+(n<<4)+frow;
      int ch = k16 ^ ((rr>>1)&3);
      bfr[n] = *(const bf16x8*)&smB[rr*32 + ch*8];
      if constexpr (DUAL) bfr2[n] = *(const bf16x8*)&smB2[rr*32 + ch*8];
    }
#pragma unroll
    for(int m=0;m<4;++m)
#pragma unroll
      for(int n=0;n<4;++n){
        acc[m][n] = __builtin_amdgcn_mfma_f32_16x16x32_bf16(af[m], bfr[n], acc[m][n], 0,0,0);
        if constexpr (DUAL)
          acc2[m][n] = __builtin_amdgcn_mfma_f32_16x16x32_bf16(af[m], bfr2[n], acc2[m][n], 0,0,0);
      }
    __syncthreads();
  }

  // ---- epilogue.  C/D layout: col = lane&15, row = (lane>>4)*4 + j
  const int growB = rowBase + (wr<<6) + (k16<<2);
  const int gcolB = colBase + (wc<<6) + frow;
#pragma unroll
  for(int m=0;m<4;++m){
#pragma unroll
    for(int n=0;n<4;++n){
      const int grow0 = growB + (m<<4);
      const int gcol  = gcolB + (n<<4);
      f32x4 v = acc[m][n];
      if constexpr (EPI==0){
        f32x4 v2 = acc2[m][n];
#pragma unroll
        for(int j=0;j<4;++j){
          float t1 = v[j];
          float hv = (t1/(1.0f+expf(-t1))) * v2[j];
          obf[(size_t)(grow0+j)*Nout + gcol] = f2bf(hv);
        }
      } else if constexpr (EPI==1){
#pragma unroll
        for(int j=0;j<4;++j){
          float t1 = v[j];
          obf[(size_t)(grow0+j)*Nout + gcol] = f2bf(t1/(1.0f+expf(-t1)));
        }
      } else if constexpr (EPI==2){
        const float g = gamma[gcol];
#pragma unroll
        for(int j=0;j<4;++j){
          if(act[grow0+j] != 0.0f){
            const size_t ix = (size_t)(grow0+j)*Nout + gcol;
            xacc[ix] += v[j]*g;
          }
        }
      } else {
        const float g = gamma[gcol];
#pragma unroll
        for(int j=0;j<4;++j){
          const size_t ix = (size_t)(grow0+j)*Nout + gcol;
          xacc[ix] += v[j]*g;
        }
      }
    }
  }
}

// ---------------------------------------------------------------------------
extern "C" void kernel_launch(void* const* d_in, const int* in_sizes, int n_in,
                              void* d_out, int out_size, void* d_ws, size_t ws_size,
                              hipStream_t stream)
{
  (void)in_sizes; (void)n_in; (void)out_size; (void)ws_size;
  const float* x_in  = (const float*)d_in[0];
  const float* acbnw = (const float*)d_in[1];
  const float* routw = (const float*)d_in[2];
  const float* w1    = (const float*)d_in[3];
  const float* w2    = (const float*)d_in[4];
  const float* w3    = (const float*)d_in[5];
  const float* acbg  = (const float*)d_in[6];
  const float* arlnw = (const float*)d_in[7];
  const float* U     = (const float*)d_in[8];
  const float* Sv    = (const float*)d_in[9];
  const float* V     = (const float*)d_in[10];
  const float* arlg  = (const float*)d_in[11];
  const float* bitnw = (const float*)d_in[12];
  const float* wup   = (const float*)d_in[13];
  const float* wdn   = (const float*)d_in[14];
  const float* bitg  = (const float*)d_in[15];

  // x state lives in d_out (fp32 [NTOK, D_DIM])
  float* xs = (float*)d_out;

  char* ws = (char*)d_ws;
  unsigned short* xn = (unsigned short*)(ws);                 // 16 MiB  bf16 [N,D]
  unsigned short* hb = (unsigned short*)(ws + 16777216);      // 64 MiB  bf16 [N,H]
  unsigned short* qb = (unsigned short*)(ws + 83886080);      // 32 MiB  bf16 [H,D] / [D,H]
  float*  act   = (float*)(ws + 117440512);                   // 16 KiB
  double* parts = (double*)(ws + 117456896);                  // 8 KiB
  float*  scal  = (float*)(ws + 117465088);

  hipMemcpyAsync(xs, x_in, (size_t)NTOK*D_DIM*sizeof(float),
                 hipMemcpyDeviceToDevice, stream);

  const int gH = (NTOK/128)*(H_DIM/128);   // 2048
  const int gD = (NTOK/128)*(D_DIM/128);   // 512

  for(int d=0; d<DEPTH; ++d){
    const size_t oD  = (size_t)d*D_DIM;
    const size_t oHD = (size_t)d*H_DIM*D_DIM;
    const size_t oR  = (size_t)d*R_DIM;
    const size_t oDR = (size_t)d*D_DIM*R_DIM;

    // ---- AdaptiveComputeBlock
    rowpass1<<<NTOK,256,0,stream>>>(xs, acbnw+oD, routw+oD, xn, act);
    gemm128<0,false,true><<<gH,256,0,stream>>>(
        xn, w1+oHD, w3+oHD, H_DIM, D_DIM, hb, nullptr, nullptr, nullptr);
    gemm128<2,false,false><<<gD,256,0,stream>>>(
        hb, w2+oHD, nullptr, D_DIM, H_DIM, nullptr, xs, acbg+oD, act);

    // ---- AdaptiveRankLinear + BitLinear input norm
    rowpass2<<<NTOK,256,0,stream>>>(xs, arlnw+oD, U+oDR, Sv+oR, V+oDR,
                                    arlg+oD, bitnw+oD, xn);

    // ---- BitLinear
    abs_part<<<1024,256,0,stream>>>(wup+oHD, parts);
    abs_final<<<1,256,0,stream>>>(parts, scal);
    tquant<<<2048,256,0,stream>>>(wup+oHD, scal, qb);
    gemm128<1,true,false><<<gH,256,0,stream>>>(
        xn, qb, nullptr, H_DIM, D_DIM, hb, nullptr, nullptr, nullptr);

    abs_part<<<1024,256,0,stream>>>(wdn+oHD, parts);
    abs_final<<<1,256,0,stream>>>(parts, scal);
    tquant<<<2048,256,0,stream>>>(wdn+oHD, scal, qb);
    gemm128<3,true,false><<<gD,256,0,stream>>>(
        hb, qb, nullptr, D_DIM, H_DIM, nullptr, xs, bitg+oD, nullptr);
  }
}

// Round 2
// 2299.355 us; speedup vs baseline: 1.2634x; 1.2634x over previous
//
#include <hip/hip_runtime.h>

#define D_DIM 2048
#define H_DIM 8192
#define NTOK  4096
#define R_DIM 16
#define DEPTH 2

typedef float f32x4 __attribute__((ext_vector_type(4)));
typedef __bf16 bf16x8 __attribute__((ext_vector_type(8)));
typedef unsigned short u16x4 __attribute__((ext_vector_type(4)));
typedef unsigned short u16x8 __attribute__((ext_vector_type(8)));

typedef __attribute__((address_space(1))) void void_g;
typedef __attribute__((address_space(3))) void void_l;

__device__ __forceinline__ unsigned short f2bf(float f){
  __bf16 b = (__bf16)f;
  return __builtin_bit_cast(unsigned short, b);
}

__device__ __forceinline__ float wredf(float v){
#pragma unroll
  for(int o=32;o;o>>=1) v += __shfl_xor(v,o,64);
  return v;
}
__device__ __forceinline__ double wredd(double v){
#pragma unroll
  for(int o=32;o;o>>=1) v += __shfl_xor(v,o,64);
  return v;
}

__device__ __forceinline__ void gload_lds16(const void* g, void* l){
  __builtin_amdgcn_global_load_lds((void_g*)g, (void_l*)l, 16, 0, 0);
}

// ---------------------------------------------------------------------------
// fp32 -> bf16 bulk convert (grid-stride, 8 elems/thread)
// ---------------------------------------------------------------------------
__global__ __launch_bounds__(256) void cvt_bf16(const float* __restrict__ w,
                                                unsigned short* __restrict__ o,
                                                long long n8)
{
  for(long long i = (long long)blockIdx.x*256 + threadIdx.x; i < n8;
      i += (long long)gridDim.x*256){
    f32x4 a = ((const f32x4*)w)[2*i];
    f32x4 b = ((const f32x4*)w)[2*i+1];
    u16x8 v;
#pragma unroll
    for(int j=0;j<4;++j){ v[j] = f2bf(a[j]); v[4+j] = f2bf(b[j]); }
    ((u16x8*)o)[i] = v;
  }
}

// ---------------------------------------------------------------------------
// Row pass 1: xn = rms_norm(x, nw) -> bf16 ; active = sigmoid(xn . rw) > 0.35
// ---------------------------------------------------------------------------
__global__ __launch_bounds__(256) void rowpass1(
    const float* __restrict__ x, const float* __restrict__ nw,
    const float* __restrict__ rw, unsigned short* __restrict__ xn,
    float* __restrict__ act)
{
  const int row = blockIdx.x, tid = threadIdx.x;
  const int lane = tid & 63, wid = tid >> 6;
  const float* xr = x + (size_t)row*D_DIM + tid*8;
  f32x4 v0 = *(const f32x4*)xr;
  f32x4 v1 = *(const f32x4*)(xr+4);
  float ssq = 0.0f;
#pragma unroll
  for(int j=0;j<4;++j) ssq += v0[j]*v0[j] + v1[j]*v1[j];
  __shared__ float red[4];
  float t = wredf(ssq);
  if(lane==0) red[wid] = t;
  __syncthreads();
  const float rs = rsqrtf((red[0]+red[1]+red[2]+red[3])*(1.0f/D_DIM) + 1e-6f);

  f32x4 n0 = *(const f32x4*)(nw + tid*8);
  f32x4 n1 = *(const f32x4*)(nw + tid*8 + 4);
  f32x4 r0 = *(const f32x4*)(rw + tid*8);
  f32x4 r1 = *(const f32x4*)(rw + tid*8 + 4);
  float gp = 0.0f;
  u16x4 o0, o1;
#pragma unroll
  for(int j=0;j<4;++j){
    float a = v0[j]*rs*n0[j];
    float b = v1[j]*rs*n1[j];
    gp += a*r0[j] + b*r1[j];
    o0[j] = f2bf(a);
    o1[j] = f2bf(b);
  }
  unsigned short* xp = xn + (size_t)row*D_DIM + tid*8;
  *(u16x4*)xp = o0;
  *(u16x4*)(xp+4) = o1;

  float gd = wredf(gp);
  __syncthreads();
  if(lane==0) red[wid] = gd;
  __syncthreads();
  if(tid==0){
    float dot = red[0]+red[1]+red[2]+red[3];
    float g = 1.0f/(1.0f+expf(-dot));
    act[row] = (g > 0.35f) ? 1.0f : 0.0f;
  }
}

// ---------------------------------------------------------------------------
// Row pass 2 (ARL fused + next RMSNorm)
// ---------------------------------------------------------------------------
__global__ __launch_bounds__(256) void rowpass2(
    float* __restrict__ x, const float* __restrict__ anw,
    const float* __restrict__ U, const float* __restrict__ Sv,
    const float* __restrict__ V, const float* __restrict__ agam,
    const float* __restrict__ bnw, unsigned short* __restrict__ xn3)
{
  const int row = blockIdx.x, tid = threadIdx.x;
  const int lane = tid & 63, wid = tid >> 6;
  float* xr = x + (size_t)row*D_DIM + tid*8;
  f32x4 v0 = *(const f32x4*)xr;
  f32x4 v1 = *(const f32x4*)(xr+4);
  float ssq = 0.0f;
#pragma unroll
  for(int j=0;j<4;++j) ssq += v0[j]*v0[j] + v1[j]*v1[j];
  __shared__ float red[4];
  float t = wredf(ssq);
  if(lane==0) red[wid] = t;
  __syncthreads();
  const float rs = rsqrtf((red[0]+red[1]+red[2]+red[3])*(1.0f/D_DIM) + 1e-6f);

  f32x4 a0 = *(const f32x4*)(anw + tid*8);
  f32x4 a1 = *(const f32x4*)(anw + tid*8 + 4);
  float xn2[8];
#pragma unroll
  for(int j=0;j<4;++j){ xn2[j] = v0[j]*rs*a0[j]; xn2[4+j] = v1[j]*rs*a1[j]; }

  float pl[16];
#pragma unroll
  for(int r2=0;r2<16;++r2) pl[r2] = 0.0f;
#pragma unroll
  for(int j=0;j<8;++j){
    const int k = tid*8 + j;
    const f32x4* Up = (const f32x4*)(U + (size_t)k*R_DIM);
    f32x4 u0=Up[0], u1=Up[1], u2=Up[2], u3=Up[3];
    const float xv = xn2[j];
#pragma unroll
    for(int q=0;q<4;++q){
      pl[q]    += xv*u0[q];
      pl[4+q]  += xv*u1[q];
      pl[8+q]  += xv*u2[q];
      pl[12+q] += xv*u3[q];
    }
  }
#pragma unroll
  for(int r2=0;r2<16;++r2) pl[r2] = wredf(pl[r2]);
  __shared__ float lred[4][16];
  if(lane==0){
#pragma unroll
    for(int r2=0;r2<16;++r2) lred[wid][r2] = pl[r2];
  }
  __syncthreads();
  __shared__ float lowS[16];
  if(tid==0){
    float sa[16]; float totS = 0.0f;
#pragma unroll
    for(int r2=0;r2<16;++r2){ sa[r2] = fabsf(Sv[r2]); totS += sa[r2]; }
    totS = fmaxf(totS, 1e-8f);
    float c = 0.0f;
#pragma unroll
    for(int r2=0;r2<16;++r2){
      float lraw = lred[0][r2]+lred[1][r2]+lred[2][r2]+lred[3][r2];
      float keep = (r2==0) ? 1.0f : ((c/totS < 0.95f) ? 1.0f : 0.0f);
      c += sa[r2];
      lowS[r2] = lraw * Sv[r2] * keep;
    }
  }
  __syncthreads();

  f32x4 d0 = {0,0,0,0}, d1 = {0,0,0,0};
#pragma unroll
  for(int r2=0;r2<16;++r2){
    const float lr = lowS[r2];
    const f32x4* Vp = (const f32x4*)(V + (size_t)r2*D_DIM + tid*8);
    f32x4 q0 = Vp[0], q1 = Vp[1];
#pragma unroll
    for(int j=0;j<4;++j){ d0[j] += lr*q0[j]; d1[j] += lr*q1[j]; }
  }
  f32x4 g0 = *(const f32x4*)(agam + tid*8);
  f32x4 g1 = *(const f32x4*)(agam + tid*8 + 4);
  f32x4 xo0, xo1;
  float ssq2 = 0.0f;
#pragma unroll
  for(int j=0;j<4;++j){
    xo0[j] = v0[j] + d0[j]*g0[j];
    xo1[j] = v1[j] + d1[j]*g1[j];
    ssq2 += xo0[j]*xo0[j] + xo1[j]*xo1[j];
  }
  __syncthreads();
  float t2 = wredf(ssq2);
  if(lane==0) red[wid] = t2;
  __syncthreads();
  const float rs2 = rsqrtf((red[0]+red[1]+red[2]+red[3])*(1.0f/D_DIM) + 1e-6f);
  f32x4 b0 = *(const f32x4*)(bnw + tid*8);
  f32x4 b1 = *(const f32x4*)(bnw + tid*8 + 4);
  u16x4 o0, o1;
#pragma unroll
  for(int j=0;j<4;++j){
    o0[j] = f2bf(xo0[j]*rs2*b0[j]);
    o1[j] = f2bf(xo1[j]*rs2*b1[j]);
  }
  *(f32x4*)xr = xo0;
  *(f32x4*)(xr+4) = xo1;
  unsigned short* xp = xn3 + (size_t)row*D_DIM + tid*8;
  *(u16x4*)xp = o0;
  *(u16x4*)(xp+4) = o1;
}

// ---------------------------------------------------------------------------
// Ternary quantization: two-stage deterministic absmean + quantize to bf16
// ---------------------------------------------------------------------------
__global__ __launch_bounds__(256) void abs_part(const float* __restrict__ w,
                                                double* __restrict__ part)
{
  const long long n4 = (long long)H_DIM*D_DIM/4;
  const int tid = threadIdx.x;
  const int lane = tid & 63, wid = tid >> 6;
  float s = 0.0f;
  for(long long i = (long long)blockIdx.x*256 + tid; i < n4;
      i += (long long)gridDim.x*256){
    f32x4 v = ((const f32x4*)w)[i];
    s += fabsf(v[0]) + fabsf(v[1]) + fabsf(v[2]) + fabsf(v[3]);
  }
  double ds = wredd((double)s);
  __shared__ double sred[4];
  if(lane==0) sred[wid] = ds;
  __syncthreads();
  if(tid==0) part[blockIdx.x] = sred[0]+sred[1]+sred[2]+sred[3];
}

__global__ __launch_bounds__(256) void abs_final(const double* __restrict__ part,
                                                 float* __restrict__ scale)
{
  const int tid = threadIdx.x;
  const int lane = tid & 63, wid = tid >> 6;
  double s = 0.0;
  for(int i=tid;i<1024;i+=256) s += part[i];
  s = wredd(s);
  __shared__ double sred[4];
  if(lane==0) sred[wid] = s;
  __syncthreads();
  if(tid==0){
    double m = (sred[0]+sred[1]+sred[2]+sred[3]) / ((double)H_DIM*(double)D_DIM);
    scale[0] = (float)fmax(m, 1e-8);
  }
}

__global__ __launch_bounds__(256) void tquant(const float* __restrict__ w,
                                              const float* __restrict__ scale,
                                              unsigned short* __restrict__ q)
{
  const long long n4 = (long long)H_DIM*D_DIM/4;
  const float s = scale[0];
  for(long long i = (long long)blockIdx.x*256 + threadIdx.x; i < n4;
      i += (long long)gridDim.x*256){
    f32x4 v = ((const f32x4*)w)[i];
    u16x4 o;
#pragma unroll
    for(int j=0;j<4;++j){
      float r = rintf(v[j]/s);
      r = fminf(1.0f, fmaxf(-1.0f, r));
      o[j] = f2bf(r*s);
    }
    ((u16x4*)q)[i] = o;
  }
}

// ---------------------------------------------------------------------------
// GEMM: C[M,Nout] = A[M,K](bf16) @ B[Nout,K]^T, 128x128 tile, BK=32,
// 4 waves (2x2), 16x16x32 bf16 MFMA.
// Ordering: XCD-chunked, rows fast within chunk (B-panel stays hot in L2).
// Epilogues: 0 dual SwiGLU->bf16, 1 silu->bf16, 2 masked residual RMW,
//            3 residual RMW.
// ---------------------------------------------------------------------------
template<int EPI, bool BBF16, bool DUAL>
__global__ __launch_bounds__(256, DUAL?2:3) void gemm128(
    const unsigned short* __restrict__ A,
    const void* __restrict__ B0v,
    const void* __restrict__ B1v,
    const int Nout, const int K,
    unsigned short* __restrict__ obf,
    float* __restrict__ xacc,
    const float* __restrict__ gamma,
    const float* __restrict__ act)
{
  __shared__ __align__(16) unsigned short smA[128*32];
  __shared__ __align__(16) unsigned short smB[128*32];
  __shared__ __align__(16) unsigned short smB2[DUAL?(128*32):8];

  const int tid  = threadIdx.x;
  const int lane = tid & 63;
  const int wid  = tid >> 6;
  const int wr   = wid >> 1;
  const int wc   = wid & 1;
  const int frow = lane & 15;
  const int k16  = lane >> 4;

  const int nwg = (int)gridDim.x;
  const int bid = (int)blockIdx.x;
  const int swz = ((bid & 7) * (nwg >> 3)) + (bid >> 3);   // nwg % 8 == 0 here
  // rows fast within an XCD chunk: B-panel hot in L2 across 32 row-blocks
  const int rowBase = (swz & 31) << 7;                      // M/128 == 32
  const int colBase = (swz >> 5) << 7;

  int srow[2], schk[2];
#pragma unroll
  for(int r=0;r<2;++r){
    int t = tid + (r<<8);
    srow[r] = t >> 2;
    schk[r] = (t & 3) ^ ((srow[r] >> 1) & 3);   // XOR swizzle (bank-conflict fix)
  }

  const f32x4 vzero = {0.0f,0.0f,0.0f,0.0f};
  f32x4 acc[4][4];
  f32x4 acc2[4][4];
#pragma unroll
  for(int m=0;m<4;++m)
#pragma unroll
    for(int n=0;n<4;++n){ acc[m][n] = vzero; acc2[m][n] = vzero; }

  for(int k0=0;k0<K;k0+=32){
    // ---- stage A (bf16, async direct-to-LDS, pre-swizzled source)
#pragma unroll
    for(int r=0;r<2;++r){
      const unsigned short* s = A + (size_t)(rowBase+srow[r])*K + k0 + schk[r]*8;
      gload_lds16(s, &smA[((r<<8)+(wid<<6))*8]);
    }
    // ---- stage B
    if constexpr (BBF16){
      const unsigned short* B0 = (const unsigned short*)B0v;
#pragma unroll
      for(int r=0;r<2;++r){
        const unsigned short* s = B0 + (size_t)(colBase+srow[r])*K + k0 + schk[r]*8;
        gload_lds16(s, &smB[((r<<8)+(wid<<6))*8]);
      }
      if constexpr (DUAL){
        const unsigned short* B1 = (const unsigned short*)B1v;
#pragma unroll
        for(int r=0;r<2;++r){
          const unsigned short* s = B1 + (size_t)(colBase+srow[r])*K + k0 + schk[r]*8;
          gload_lds16(s, &smB2[((r<<8)+(wid<<6))*8]);
        }
      }
    } else {
      const float* B0 = (const float*)B0v;
#pragma unroll
      for(int r=0;r<2;++r){
        const float* s = B0 + (size_t)(colBase+srow[r])*K + k0 + schk[r]*8;
        f32x4 f0 = *(const f32x4*)s;
        f32x4 f1 = *(const f32x4*)(s+4);
        u16x8 o;
#pragma unroll
        for(int j=0;j<4;++j){ o[j] = f2bf(f0[j]); o[4+j] = f2bf(f1[j]); }
        *(u16x8*)&smB[(size_t)(tid+(r<<8))*8] = o;
      }
      if constexpr (DUAL){
        const float* B1 = (const float*)B1v;
#pragma unroll
        for(int r=0;r<2;++r){
          const float* s = B1 + (size_t)(colBase+srow[r])*K + k0 + schk[r]*8;
          f32x4 f0 = *(const f32x4*)s;
          f32x4 f1 = *(const f32x4*)(s+4);
          u16x8 o;
#pragma unroll
          for(int j=0;j<4;++j){ o[j] = f2bf(f0[j]); o[4+j] = f2bf(f1[j]); }
          *(u16x8*)&smB2[(size_t)(tid+(r<<8))*8] = o;
        }
      }
    }
    __syncthreads();

    bf16x8 af[4];
#pragma unroll
    for(int m=0;m<4;++m){
      int rr = (wr<<6)+(m<<4)+frow;
      int ch = k16 ^ ((rr>>1)&3);
      af[m] = *(const bf16x8*)&smA[rr*32 + ch*8];
    }
    bf16x8 bfr[4];
    bf16x8 bfr2[4];
#pragma unroll
    for(int n=0;n<4;++n){
      int rr = (wc<<6)+(n<<4)+frow;
      int ch = k16 ^ ((rr>>1)&3);
      bfr[n] = *(const bf16x8*)&smB[rr*32 + ch*8];
      if constexpr (DUAL) bfr2[n] = *(const bf16x8*)&smB2[rr*32 + ch*8];
    }
#pragma unroll
    for(int m=0;m<4;++m)
#pragma unroll
      for(int n=0;n<4;++n){
        acc[m][n] = __builtin_amdgcn_mfma_f32_16x16x32_bf16(af[m], bfr[n], acc[m][n], 0,0,0);
        if constexpr (DUAL)
          acc2[m][n] = __builtin_amdgcn_mfma_f32_16x16x32_bf16(af[m], bfr2[n], acc2[m][n], 0,0,0);
      }
    __syncthreads();
  }

  // ---- epilogue.  C/D layout: col = lane&15, row = (lane>>4)*4 + j
  const int growB = rowBase + (wr<<6) + (k16<<2);
  const int gcolB = colBase + (wc<<6) + frow;
#pragma unroll
  for(int m=0;m<4;++m){
#pragma unroll
    for(int n=0;n<4;++n){
      const int grow0 = growB + (m<<4);
      const int gcol  = gcolB + (n<<4);
      f32x4 v = acc[m][n];
      if constexpr (EPI==0){
        f32x4 v2 = acc2[m][n];
#pragma unroll
        for(int j=0;j<4;++j){
          float t1 = v[j];
          float hv = (t1/(1.0f+expf(-t1))) * v2[j];
          obf[(size_t)(grow0+j)*Nout + gcol] = f2bf(hv);
        }
      } else if constexpr (EPI==1){
#pragma unroll
        for(int j=0;j<4;++j){
          float t1 = v[j];
          obf[(size_t)(grow0+j)*Nout + gcol] = f2bf(t1/(1.0f+expf(-t1)));
        }
      } else if constexpr (EPI==2){
        const float g = gamma[gcol];
#pragma unroll
        for(int j=0;j<4;++j){
          if(act[grow0+j] != 0.0f){
            const size_t ix = (size_t)(grow0+j)*Nout + gcol;
            xacc[ix] += v[j]*g;
          }
        }
      } else {
        const float g = gamma[gcol];
#pragma unroll
        for(int j=0;j<4;++j){
          const size_t ix = (size_t)(grow0+j)*Nout + gcol;
          xacc[ix] += v[j]*g;
        }
      }
    }
  }
}

// ---------------------------------------------------------------------------
extern "C" void kernel_launch(void* const* d_in, const int* in_sizes, int n_in,
                              void* d_out, int out_size, void* d_ws, size_t ws_size,
                              hipStream_t stream)
{
  (void)in_sizes; (void)n_in; (void)out_size;
  const float* x_in  = (const float*)d_in[0];
  const float* acbnw = (const float*)d_in[1];
  const float* routw = (const float*)d_in[2];
  const float* w1    = (const float*)d_in[3];
  const float* w2    = (const float*)d_in[4];
  const float* w3    = (const float*)d_in[5];
  const float* acbg  = (const float*)d_in[6];
  const float* arlnw = (const float*)d_in[7];
  const float* U     = (const float*)d_in[8];
  const float* Sv    = (const float*)d_in[9];
  const float* V     = (const float*)d_in[10];
  const float* arlg  = (const float*)d_in[11];
  const float* bitnw = (const float*)d_in[12];
  const float* wup   = (const float*)d_in[13];
  const float* wdn   = (const float*)d_in[14];
  const float* bitg  = (const float*)d_in[15];

  float* xs = (float*)d_out;           // x state lives in d_out (fp32 [N,D])
  char* ws = (char*)d_ws;

  const bool big = (ws_size >= (size_t)185000000);

  hipMemcpyAsync(xs, x_in, (size_t)NTOK*D_DIM*sizeof(float),
                 hipMemcpyDeviceToDevice, stream);

  const int gH = (NTOK/128)*(H_DIM/128);   // 2048
  const int gD = (NTOK/128)*(D_DIM/128);   // 512
  const long long n8w = (long long)H_DIM*D_DIM/8;

  if (big) {
    unsigned short* xn  = (unsigned short*)(ws);                  // 16 MiB
    unsigned short* hb  = (unsigned short*)(ws + 16777216);       // 64 MiB
    unsigned short* wb1 = (unsigned short*)(ws + 83886080);       // 32 MiB
    unsigned short* wb3 = (unsigned short*)(ws + 117440512);      // 32 MiB
    unsigned short* wb2 = (unsigned short*)(ws + 150994944);      // 32 MiB
    float*  act   = (float*)(ws + 184549376);
    double* parts = (double*)(ws + 184565760);
    float*  scal  = (float*)(ws + 184573952);

    for(int d=0; d<DEPTH; ++d){
      const size_t oD  = (size_t)d*D_DIM;
      const size_t oHD = (size_t)d*H_DIM*D_DIM;
      const size_t oR  = (size_t)d*R_DIM;
      const size_t oDR = (size_t)d*D_DIM*R_DIM;

      // weight conversion fp32 -> bf16 (wb1/wb3/wb2 reused per layer)
      cvt_bf16<<<4096,256,0,stream>>>(w1+oHD, wb1, n8w);
      cvt_bf16<<<4096,256,0,stream>>>(w3+oHD, wb3, n8w);
      cvt_bf16<<<4096,256,0,stream>>>(w2+oHD, wb2, n8w);

      // ---- AdaptiveComputeBlock
      rowpass1<<<NTOK,256,0,stream>>>(xs, acbnw+oD, routw+oD, xn, act);
      gemm128<0,true,true><<<gH,256,0,stream>>>(
          xn, wb1, wb3, H_DIM, D_DIM, hb, nullptr, nullptr, nullptr);
      gemm128<2,true,false><<<gD,256,0,stream>>>(
          hb, wb2, nullptr, D_DIM, H_DIM, nullptr, xs, acbg+oD, act);

      // ---- AdaptiveRankLinear + BitLinear input norm
      rowpass2<<<NTOK,256,0,stream>>>(xs, arlnw+oD, U+oDR, Sv+oR, V+oDR,
                                      arlg+oD, bitnw+oD, xn);

      // ---- BitLinear (quantized weights into wb1 / wb2 regions)
      abs_part<<<1024,256,0,stream>>>(wup+oHD, parts);
      abs_final<<<1,256,0,stream>>>(parts, scal);
      tquant<<<2048,256,0,stream>>>(wup+oHD, scal, wb1);
      gemm128<1,true,false><<<gH,256,0,stream>>>(
          xn, wb1, nullptr, H_DIM, D_DIM, hb, nullptr, nullptr, nullptr);

      abs_part<<<1024,256,0,stream>>>(wdn+oHD, parts);
      abs_final<<<1,256,0,stream>>>(parts, scal);
      tquant<<<2048,256,0,stream>>>(wdn+oHD, scal, wb2);
      gemm128<3,true,false><<<gD,256,0,stream>>>(
          hb, wb2, nullptr, D_DIM, H_DIM, nullptr, xs, bitg+oD, nullptr);
    }
  } else {
    // fallback: round-1 layout (fp32 B reg-staged for w1/w3/w2)
    unsigned short* xn = (unsigned short*)(ws);                 // 16 MiB
    unsigned short* hb = (unsigned short*)(ws + 16777216);      // 64 MiB
    unsigned short* qb = (unsigned short*)(ws + 83886080);      // 32 MiB
    float*  act   = (float*)(ws + 117440512);
    double* parts = (double*)(ws + 117456896);
    float*  scal  = (float*)(ws + 117465088);

    for(int d=0; d<DEPTH; ++d){
      const size_t oD  = (size_t)d*D_DIM;
      const size_t oHD = (size_t)d*H_DIM*D_DIM;
      const size_t oR  = (size_t)d*R_DIM;
      const size_t oDR = (size_t)d*D_DIM*R_DIM;

      rowpass1<<<NTOK,256,0,stream>>>(xs, acbnw+oD, routw+oD, xn, act);
      gemm128<0,false,true><<<gH,256,0,stream>>>(
          xn, w1+oHD, w3+oHD, H_DIM, D_DIM, hb, nullptr, nullptr, nullptr);
      gemm128<2,false,false><<<gD,256,0,stream>>>(
          hb, w2+oHD, nullptr, D_DIM, H_DIM, nullptr, xs, acbg+oD, act);

      rowpass2<<<NTOK,256,0,stream>>>(xs, arlnw+oD, U+oDR, Sv+oR, V+oDR,
                                      arlg+oD, bitnw+oD, xn);

      abs_part<<<1024,256,0,stream>>>(wup+oHD, parts);
      abs_final<<<1,256,0,stream>>>(parts, scal);
      tquant<<<2048,256,0,stream>>>(wup+oHD, scal, qb);
      gemm128<1,true,false><<<gH,256,0,stream>>>(
          xn, qb, nullptr, H_DIM, D_DIM, hb, nullptr, nullptr, nullptr);

      abs_part<<<1024,256,0,stream>>>(wdn+oHD, parts);
      abs_final<<<1,256,0,stream>>>(parts, scal);
      tquant<<<2048,256,0,stream>>>(wdn+oHD, scal, qb);
      gemm128<3,true,false><<<gD,256,0,stream>>>(
          hb, qb, nullptr, D_DIM, H_DIM, nullptr, xs, bitg+oD, nullptr);
    }
  }
}

// Round 3
// 2288.370 us; speedup vs baseline: 1.2694x; 1.0048x over previous
//
#include <hip/hip_runtime.h>

#define D_DIM 2048
#define H_DIM 8192
#define NTOK  4096
#define R_DIM 16
#define DEPTH 2

typedef float f32x4 __attribute__((ext_vector_type(4)));
typedef __bf16 bf16x8 __attribute__((ext_vector_type(8)));
typedef unsigned short u16x4 __attribute__((ext_vector_type(4)));
typedef unsigned short u16x8 __attribute__((ext_vector_type(8)));

typedef __attribute__((address_space(1))) void void_g;
typedef __attribute__((address_space(3))) void void_l;

__device__ __forceinline__ unsigned short f2bf(float f){
  __bf16 b = (__bf16)f;
  return __builtin_bit_cast(unsigned short, b);
}
__device__ __forceinline__ float bf2f(unsigned short u){
  unsigned int x = ((unsigned int)u) << 16;
  return __builtin_bit_cast(float, x);
}

__device__ __forceinline__ float wredf(float v){
#pragma unroll
  for(int o=32;o;o>>=1) v += __shfl_xor(v,o,64);
  return v;
}
__device__ __forceinline__ double wredd(double v){
#pragma unroll
  for(int o=32;o;o>>=1) v += __shfl_xor(v,o,64);
  return v;
}

__device__ __forceinline__ void gload_lds16(const void* g, void* l){
  __builtin_amdgcn_global_load_lds((void_g*)g, (void_l*)l, 16, 0, 0);
}

#define S_BARRIER   asm volatile("s_barrier" ::: "memory")
#define WAIT_LGKM0  asm volatile("s_waitcnt lgkmcnt(0)" ::: "memory")

template<int N> __device__ __forceinline__ void waitvm(){
  if constexpr (N==0)      asm volatile("s_waitcnt vmcnt(0)" ::: "memory");
  else if constexpr (N==3) asm volatile("s_waitcnt vmcnt(3)" ::: "memory");
  else if constexpr (N==4) asm volatile("s_waitcnt vmcnt(4)" ::: "memory");
  else if constexpr (N==6) asm volatile("s_waitcnt vmcnt(6)" ::: "memory");
  else                     asm volatile("s_waitcnt vmcnt(8)" ::: "memory");
}

// ---------------------------------------------------------------------------
// fp32 -> bf16 bulk convert
// ---------------------------------------------------------------------------
__global__ __launch_bounds__(256) void cvt_bf16(const float* __restrict__ w,
                                                unsigned short* __restrict__ o,
                                                long long n8)
{
  for(long long i = (long long)blockIdx.x*256 + threadIdx.x; i < n8;
      i += (long long)gridDim.x*256){
    f32x4 a = ((const f32x4*)w)[2*i];
    f32x4 b = ((const f32x4*)w)[2*i+1];
    u16x8 v;
#pragma unroll
    for(int j=0;j<4;++j){ v[j] = f2bf(a[j]); v[4+j] = f2bf(b[j]); }
    ((u16x8*)o)[i] = v;
  }
}

// ---------------------------------------------------------------------------
// Row pass 1
// ---------------------------------------------------------------------------
__global__ __launch_bounds__(256) void rowpass1(
    const float* __restrict__ x, const float* __restrict__ nw,
    const float* __restrict__ rw, unsigned short* __restrict__ xn,
    float* __restrict__ act)
{
  const int row = blockIdx.x, tid = threadIdx.x;
  const int lane = tid & 63, wid = tid >> 6;
  const float* xr = x + (size_t)row*D_DIM + tid*8;
  f32x4 v0 = *(const f32x4*)xr;
  f32x4 v1 = *(const f32x4*)(xr+4);
  float ssq = 0.0f;
#pragma unroll
  for(int j=0;j<4;++j) ssq += v0[j]*v0[j] + v1[j]*v1[j];
  __shared__ float red[4];
  float t = wredf(ssq);
  if(lane==0) red[wid] = t;
  __syncthreads();
  const float rs = rsqrtf((red[0]+red[1]+red[2]+red[3])*(1.0f/D_DIM) + 1e-6f);

  f32x4 n0 = *(const f32x4*)(nw + tid*8);
  f32x4 n1 = *(const f32x4*)(nw + tid*8 + 4);
  f32x4 r0 = *(const f32x4*)(rw + tid*8);
  f32x4 r1 = *(const f32x4*)(rw + tid*8 + 4);
  float gp = 0.0f;
  u16x4 o0, o1;
#pragma unroll
  for(int j=0;j<4;++j){
    float a = v0[j]*rs*n0[j];
    float b = v1[j]*rs*n1[j];
    gp += a*r0[j] + b*r1[j];
    o0[j] = f2bf(a);
    o1[j] = f2bf(b);
  }
  unsigned short* xp = xn + (size_t)row*D_DIM + tid*8;
  *(u16x4*)xp = o0;
  *(u16x4*)(xp+4) = o1;

  float gd = wredf(gp);
  __syncthreads();
  if(lane==0) red[wid] = gd;
  __syncthreads();
  if(tid==0){
    float dot = red[0]+red[1]+red[2]+red[3];
    float g = 1.0f/(1.0f+expf(-dot));
    act[row] = (g > 0.35f) ? 1.0f : 0.0f;
  }
}

// ---------------------------------------------------------------------------
// Row pass 2 (ARL fused + next RMSNorm)
// ---------------------------------------------------------------------------
__global__ __launch_bounds__(256) void rowpass2(
    float* __restrict__ x, const float* __restrict__ anw,
    const float* __restrict__ U, const float* __restrict__ Sv,
    const float* __restrict__ V, const float* __restrict__ agam,
    const float* __restrict__ bnw, unsigned short* __restrict__ xn3)
{
  const int row = blockIdx.x, tid = threadIdx.x;
  const int lane = tid & 63, wid = tid >> 6;
  float* xr = x + (size_t)row*D_DIM + tid*8;
  f32x4 v0 = *(const f32x4*)xr;
  f32x4 v1 = *(const f32x4*)(xr+4);
  float ssq = 0.0f;
#pragma unroll
  for(int j=0;j<4;++j) ssq += v0[j]*v0[j] + v1[j]*v1[j];
  __shared__ float red[4];
  float t = wredf(ssq);
  if(lane==0) red[wid] = t;
  __syncthreads();
  const float rs = rsqrtf((red[0]+red[1]+red[2]+red[3])*(1.0f/D_DIM) + 1e-6f);

  f32x4 a0 = *(const f32x4*)(anw + tid*8);
  f32x4 a1 = *(const f32x4*)(anw + tid*8 + 4);
  float xn2[8];
#pragma unroll
  for(int j=0;j<4;++j){ xn2[j] = v0[j]*rs*a0[j]; xn2[4+j] = v1[j]*rs*a1[j]; }

  float pl[16];
#pragma unroll
  for(int r2=0;r2<16;++r2) pl[r2] = 0.0f;
#pragma unroll
  for(int j=0;j<8;++j){
    const int k = tid*8 + j;
    const f32x4* Up = (const f32x4*)(U + (size_t)k*R_DIM);
    f32x4 u0=Up[0], u1=Up[1], u2=Up[2], u3=Up[3];
    const float xv = xn2[j];
#pragma unroll
    for(int q=0;q<4;++q){
      pl[q]    += xv*u0[q];
      pl[4+q]  += xv*u1[q];
      pl[8+q]  += xv*u2[q];
      pl[12+q] += xv*u3[q];
    }
  }
#pragma unroll
  for(int r2=0;r2<16;++r2) pl[r2] = wredf(pl[r2]);
  __shared__ float lred[4][16];
  if(lane==0){
#pragma unroll
    for(int r2=0;r2<16;++r2) lred[wid][r2] = pl[r2];
  }
  __syncthreads();
  __shared__ float lowS[16];
  if(tid==0){
    float sa[16]; float totS = 0.0f;
#pragma unroll
    for(int r2=0;r2<16;++r2){ sa[r2] = fabsf(Sv[r2]); totS += sa[r2]; }
    totS = fmaxf(totS, 1e-8f);
    float c = 0.0f;
#pragma unroll
    for(int r2=0;r2<16;++r2){
      float lraw = lred[0][r2]+lred[1][r2]+lred[2][r2]+lred[3][r2];
      float keep = (r2==0) ? 1.0f : ((c/totS < 0.95f) ? 1.0f : 0.0f);
      c += sa[r2];
      lowS[r2] = lraw * Sv[r2] * keep;
    }
  }
  __syncthreads();

  f32x4 d0 = {0,0,0,0}, d1 = {0,0,0,0};
#pragma unroll
  for(int r2=0;r2<16;++r2){
    const float lr = lowS[r2];
    const f32x4* Vp = (const f32x4*)(V + (size_t)r2*D_DIM + tid*8);
    f32x4 q0 = Vp[0], q1 = Vp[1];
#pragma unroll
    for(int j=0;j<4;++j){ d0[j] += lr*q0[j]; d1[j] += lr*q1[j]; }
  }
  f32x4 g0 = *(const f32x4*)(agam + tid*8);
  f32x4 g1 = *(const f32x4*)(agam + tid*8 + 4);
  f32x4 xo0, xo1;
  float ssq2 = 0.0f;
#pragma unroll
  for(int j=0;j<4;++j){
    xo0[j] = v0[j] + d0[j]*g0[j];
    xo1[j] = v1[j] + d1[j]*g1[j];
    ssq2 += xo0[j]*xo0[j] + xo1[j]*xo1[j];
  }
  __syncthreads();
  float t2 = wredf(ssq2);
  if(lane==0) red[wid] = t2;
  __syncthreads();
  const float rs2 = rsqrtf((red[0]+red[1]+red[2]+red[3])*(1.0f/D_DIM) + 1e-6f);
  f32x4 b0 = *(const f32x4*)(bnw + tid*8);
  f32x4 b1 = *(const f32x4*)(bnw + tid*8 + 4);
  u16x4 o0, o1;
#pragma unroll
  for(int j=0;j<4;++j){
    o0[j] = f2bf(xo0[j]*rs2*b0[j]);
    o1[j] = f2bf(xo1[j]*rs2*b1[j]);
  }
  *(f32x4*)xr = xo0;
  *(f32x4*)(xr+4) = xo1;
  unsigned short* xp = xn3 + (size_t)row*D_DIM + tid*8;
  *(u16x4*)xp = o0;
  *(u16x4*)(xp+4) = o1;
}

// ---------------------------------------------------------------------------
// Ternary quantization
// ---------------------------------------------------------------------------
__global__ __launch_bounds__(256) void abs_part(const float* __restrict__ w,
                                                double* __restrict__ part)
{
  const long long n4 = (long long)H_DIM*D_DIM/4;
  const int tid = threadIdx.x;
  const int lane = tid & 63, wid = tid >> 6;
  float s = 0.0f;
  for(long long i = (long long)blockIdx.x*256 + tid; i < n4;
      i += (long long)gridDim.x*256){
    f32x4 v = ((const f32x4*)w)[i];
    s += fabsf(v[0]) + fabsf(v[1]) + fabsf(v[2]) + fabsf(v[3]);
  }
  double ds = wredd((double)s);
  __shared__ double sred[4];
  if(lane==0) sred[wid] = ds;
  __syncthreads();
  if(tid==0) part[blockIdx.x] = sred[0]+sred[1]+sred[2]+sred[3];
}

__global__ __launch_bounds__(256) void abs_final(const double* __restrict__ part,
                                                 float* __restrict__ scale)
{
  const int tid = threadIdx.x;
  const int lane = tid & 63, wid = tid >> 6;
  double s = 0.0;
  for(int i=tid;i<1024;i+=256) s += part[i];
  s = wredd(s);
  __shared__ double sred[4];
  if(lane==0) sred[wid] = s;
  __syncthreads();
  if(tid==0){
    double m = (sred[0]+sred[1]+sred[2]+sred[3]) / ((double)H_DIM*(double)D_DIM);
    scale[0] = (float)fmax(m, 1e-8);
  }
}

__global__ __launch_bounds__(256) void tquant(const float* __restrict__ w,
                                              const float* __restrict__ scale,
                                              unsigned short* __restrict__ q)
{
  const long long n4 = (long long)H_DIM*D_DIM/4;
  const float s = scale[0];
  for(long long i = (long long)blockIdx.x*256 + threadIdx.x; i < n4;
      i += (long long)gridDim.x*256){
    f32x4 v = ((const f32x4*)w)[i];
    u16x4 o;
#pragma unroll
    for(int j=0;j<4;++j){
      float r = rintf(v[j]/s);
      r = fminf(1.0f, fmaxf(-1.0f, r));
      o[j] = f2bf(r*s);
    }
    ((u16x4*)q)[i] = o;
  }
}

// ---------------------------------------------------------------------------
// 256xBN 8-wave deep-pipelined GEMM (8-phase-style, counted vmcnt).
// C[M=4096, Nout] = A[M,K](bf16) @ B[Nout,K]^T.
// BK=32, 4 LDS tile slots, stage tile T+3 while computing tile T.
// Per tile: 2 phases x {ds_read frags; stage 8KB units; barrier; lgkm0;
//           setprio(1) 16 MFMA setprio(0); barrier}, vmcnt(UPT) once/tile.
// EPI: 0 SwiGLU-combine in place (reads obf as t3, writes h)
//      1 silu -> obf      2 masked residual RMW     3 residual RMW
//      4 raw bf16 -> obf
// ---------------------------------------------------------------------------
template<int EPI, int BN_>
__global__ __launch_bounds__(512, 2) void gemm256(
    const unsigned short* __restrict__ A,
    const unsigned short* __restrict__ B,
    const int Nout, const int K,
    unsigned short* __restrict__ obf,
    float* __restrict__ xacc,
    const float* __restrict__ gamma,
    const float* __restrict__ act)
{
  constexpr int WN     = BN_/4;        // per-wave N (64 or 32)
  constexpr int NFRAG  = WN/16;        // 4 or 2
  constexpr int BUNITS = (BN_*32*2)/8192;  // 2 or 1
  constexpr int UPT    = 2 + BUNITS;   // stage units per tile (4 or 3)
  constexpr int ASLOT  = 8192;         // ushorts per A slot (16 KB)
  constexpr int BSLOT  = BN_*32;       // ushorts per B slot

  __shared__ __align__(16) unsigned short smA[4*ASLOT];
  __shared__ __align__(16) unsigned short smB[4*BSLOT];

  const int tid  = threadIdx.x;
  const int lane = tid & 63;
  const int wid  = tid >> 6;           // 0..7
  const int wr   = wid >> 2;           // 0..1  (2 M-warps)
  const int wc   = wid & 3;            // 0..3  (4 N-warps)
  const int frow = lane & 15;
  const int k16  = lane >> 4;

  // XCD-chunked swizzle; rows fast (B-panel hot in per-XCD L2)
  const int nwg = (int)gridDim.x;
  const int bid = (int)blockIdx.x;
  const int cpx = nwg >> 3;                       // nwg % 8 == 0
  const int swz = (bid & 7)*cpx + (bid >> 3);
  const int rowBase = (swz & 15) << 8;            // M/256 == 16
  const int colBase = (swz >> 4) * BN_;

  // staging thread map: row = tid>>2 (+u*128), chunk XOR-swizzled
  const int trow = tid >> 2;
  const int tchk = (tid & 3) ^ ((tid >> 3) & 3);
  const unsigned short* Abase = A + (size_t)(rowBase + trow)*K + tchk*8;
  const unsigned short* Bbase = B + (size_t)(colBase + trow)*K + tchk*8;

  auto stageA = [&](int T, int u){
    gload_lds16(Abase + (size_t)u*128*K + (size_t)T*32,
                &smA[(T&3)*ASLOT + u*4096 + tid*8]);
  };
  auto stageB = [&](int T, int u){
    gload_lds16(Bbase + (size_t)u*128*K + (size_t)T*32,
                &smB[(T&3)*BSLOT + u*4096 + tid*8]);
  };

  // fragment LDS offsets (ushort units), swizzled chunk
  int aoff[8], boff[NFRAG];
#pragma unroll
  for(int m=0;m<8;++m){
    int row = wr*128 + m*16 + frow;
    int ch  = k16 ^ ((row>>1)&3);
    aoff[m] = row*32 + ch*8;
  }
#pragma unroll
  for(int n=0;n<NFRAG;++n){
    int row = wc*WN + n*16 + frow;
    int ch  = k16 ^ ((row>>1)&3);
    boff[n] = row*32 + ch*8;
  }

  const f32x4 vzero = {0.0f,0.0f,0.0f,0.0f};
  f32x4 acc[8][NFRAG];
#pragma unroll
  for(int m=0;m<8;++m)
#pragma unroll
    for(int n=0;n<NFRAG;++n) acc[m][n] = vzero;

  const int NT = K >> 5;

  // prologue: stage tiles 0,1,2
#pragma unroll
  for(int t=0;t<3;++t){
    stageA(t,0); stageA(t,1);
    stageB(t,0);
    if constexpr (BUNITS==2) stageB(t,1);
  }
  waitvm<2*UPT>();          // tile 0 landed (newest 2*UPT = tiles 1,2)
  S_BARRIER;

  for(int T=0; T<NT; ++T){
    const int sA = (T&3)*ASLOT;
    const int sB = (T&3)*BSLOT;
    const bool pf = (T+3 < NT);

    // ---- phase q0: B frags + A frags m0..3
    bf16x8 bfr[NFRAG], af0[4];
#pragma unroll
    for(int n=0;n<NFRAG;++n) bfr[n] = *(const bf16x8*)&smB[sB + boff[n]];
#pragma unroll
    for(int m=0;m<4;++m)     af0[m] = *(const bf16x8*)&smA[sA + aoff[m]];
    if(pf){ stageA(T+3,0); stageA(T+3,1); }   // slot (T+3)&3 freed at block T-1
    S_BARRIER;
    WAIT_LGKM0;
    __builtin_amdgcn_sched_barrier(0);
    __builtin_amdgcn_s_setprio(1);
#pragma unroll
    for(int m=0;m<4;++m)
#pragma unroll
      for(int n=0;n<NFRAG;++n)
        acc[m][n] = __builtin_amdgcn_mfma_f32_16x16x32_bf16(af0[m], bfr[n], acc[m][n], 0,0,0);
    __builtin_amdgcn_s_setprio(0);
    S_BARRIER;

    // ---- phase q1: A frags m4..7
    bf16x8 af1[4];
#pragma unroll
    for(int m=0;m<4;++m) af1[m] = *(const bf16x8*)&smA[sA + aoff[4+m]];
    if(pf){ stageB(T+3,0); if constexpr (BUNITS==2) stageB(T+3,1); }
    S_BARRIER;
    WAIT_LGKM0;
    __builtin_amdgcn_sched_barrier(0);
    __builtin_amdgcn_s_setprio(1);
#pragma unroll
    for(int m=0;m<4;++m)
#pragma unroll
      for(int n=0;n<NFRAG;++n)
        acc[4+m][n] = __builtin_amdgcn_mfma_f32_16x16x32_bf16(af1[m], bfr[n], acc[4+m][n], 0,0,0);
    __builtin_amdgcn_s_setprio(0);
    if(pf){ waitvm<UPT>(); } else { waitvm<0>(); }   // counted, never 0 in steady state
    S_BARRIER;
  }

  // ---- epilogue. C/D: col = lane&15, row = k16*4 + j
  const int growB = rowBase + wr*128 + (k16<<2);
  const int gcolB = colBase + wc*WN + frow;
#pragma unroll
  for(int m=0;m<8;++m){
#pragma unroll
    for(int n=0;n<NFRAG;++n){
      const int grow0 = growB + m*16;
      const int gcol  = gcolB + n*16;
      f32x4 v = acc[m][n];
      if constexpr (EPI==0){
#pragma unroll
        for(int j=0;j<4;++j){
          const size_t ix = (size_t)(grow0+j)*Nout + gcol;
          float t1 = v[j];
          float s  = t1/(1.0f+expf(-t1));
          float t3 = bf2f(obf[ix]);
          obf[ix] = f2bf(s*t3);
        }
      } else if constexpr (EPI==1){
#pragma unroll
        for(int j=0;j<4;++j){
          float t1 = v[j];
          obf[(size_t)(grow0+j)*Nout + gcol] = f2bf(t1/(1.0f+expf(-t1)));
        }
      } else if constexpr (EPI==2){
        const float g = gamma[gcol];
#pragma unroll
        for(int j=0;j<4;++j){
          if(act[grow0+j] != 0.0f){
            const size_t ix = (size_t)(grow0+j)*Nout + gcol;
            xacc[ix] += v[j]*g;
          }
        }
      } else if constexpr (EPI==3){
        const float g = gamma[gcol];
#pragma unroll
        for(int j=0;j<4;++j){
          const size_t ix = (size_t)(grow0+j)*Nout + gcol;
          xacc[ix] += v[j]*g;
        }
      } else {
#pragma unroll
        for(int j=0;j<4;++j){
          obf[(size_t)(grow0+j)*Nout + gcol] = f2bf(v[j]);
        }
      }
    }
  }
}

// ---------------------------------------------------------------------------
// fallback 128^2 GEMM (round-1 structure) for small ws
// ---------------------------------------------------------------------------
template<int EPI, bool BBF16, bool DUAL>
__global__ __launch_bounds__(256, DUAL?2:3) void gemm128(
    const unsigned short* __restrict__ A,
    const void* __restrict__ B0v,
    const void* __restrict__ B1v,
    const int Nout, const int K,
    unsigned short* __restrict__ obf,
    float* __restrict__ xacc,
    const float* __restrict__ gamma,
    const float* __restrict__ act)
{
  __shared__ __align__(16) unsigned short smA[128*32];
  __shared__ __align__(16) unsigned short smB[128*32];
  __shared__ __align__(16) unsigned short smB2[DUAL?(128*32):8];

  const int tid  = threadIdx.x;
  const int lane = tid & 63;
  const int wid  = tid >> 6;
  const int wr   = wid >> 1;
  const int wc   = wid & 1;
  const int frow = lane & 15;
  const int k16  = lane >> 4;

  const int nwg = (int)gridDim.x;
  const int bid = (int)blockIdx.x;
  const int swz = ((bid & 7) * (nwg >> 3)) + (bid >> 3);
  const int rowBase = (swz & 31) << 7;
  const int colBase = (swz >> 5) << 7;

  int srow[2], schk[2];
#pragma unroll
  for(int r=0;r<2;++r){
    int t = tid + (r<<8);
    srow[r] = t >> 2;
    schk[r] = (t & 3) ^ ((srow[r] >> 1) & 3);
  }

  const f32x4 vzero = {0.0f,0.0f,0.0f,0.0f};
  f32x4 acc[4][4];
  f32x4 acc2[4][4];
#pragma unroll
  for(int m=0;m<4;++m)
#pragma unroll
    for(int n=0;n<4;++n){ acc[m][n] = vzero; acc2[m][n] = vzero; }

  for(int k0=0;k0<K;k0+=32){
#pragma unroll
    for(int r=0;r<2;++r){
      const unsigned short* s = A + (size_t)(rowBase+srow[r])*K + k0 + schk[r]*8;
      gload_lds16(s, &smA[((r<<8)+(wid<<6))*8]);
    }
    if constexpr (BBF16){
      const unsigned short* B0 = (const unsigned short*)B0v;
#pragma unroll
      for(int r=0;r<2;++r){
        const unsigned short* s = B0 + (size_t)(colBase+srow[r])*K + k0 + schk[r]*8;
        gload_lds16(s, &smB[((r<<8)+(wid<<6))*8]);
      }
    } else {
      const float* B0 = (const float*)B0v;
#pragma unroll
      for(int r=0;r<2;++r){
        const float* s = B0 + (size_t)(colBase+srow[r])*K + k0 + schk[r]*8;
        f32x4 f0 = *(const f32x4*)s;
        f32x4 f1 = *(const f32x4*)(s+4);
        u16x8 o;
#pragma unroll
        for(int j=0;j<4;++j){ o[j] = f2bf(f0[j]); o[4+j] = f2bf(f1[j]); }
        *(u16x8*)&smB[(size_t)(tid+(r<<8))*8] = o;
      }
      if constexpr (DUAL){
        const float* B1 = (const float*)B1v;
#pragma unroll
        for(int r=0;r<2;++r){
          const float* s = B1 + (size_t)(colBase+srow[r])*K + k0 + schk[r]*8;
          f32x4 f0 = *(const f32x4*)s;
          f32x4 f1 = *(const f32x4*)(s+4);
          u16x8 o;
#pragma unroll
          for(int j=0;j<4;++j){ o[j] = f2bf(f0[j]); o[4+j] = f2bf(f1[j]); }
          *(u16x8*)&smB2[(size_t)(tid+(r<<8))*8] = o;
        }
      }
    }
    __syncthreads();

    bf16x8 af[4];
#pragma unroll
    for(int m=0;m<4;++m){
      int rr = (wr<<6)+(m<<4)+frow;
      int ch = k16 ^ ((rr>>1)&3);
      af[m] = *(const bf16x8*)&smA[rr*32 + ch*8];
    }
    bf16x8 bfr[4];
    bf16x8 bfr2[4];
#pragma unroll
    for(int n=0;n<4;++n){
      int rr = (wc<<6)+(n<<4)+frow;
      int ch = k16 ^ ((rr>>1)&3);
      bfr[n] = *(const bf16x8*)&smB[rr*32 + ch*8];
      if constexpr (DUAL) bfr2[n] = *(const bf16x8*)&smB2[rr*32 + ch*8];
    }
#pragma unroll
    for(int m=0;m<4;++m)
#pragma unroll
      for(int n=0;n<4;++n){
        acc[m][n] = __builtin_amdgcn_mfma_f32_16x16x32_bf16(af[m], bfr[n], acc[m][n], 0,0,0);
        if constexpr (DUAL)
          acc2[m][n] = __builtin_amdgcn_mfma_f32_16x16x32_bf16(af[m], bfr2[n], acc2[m][n], 0,0,0);
      }
    __syncthreads();
  }

  const int growB = rowBase + (wr<<6) + (k16<<2);
  const int gcolB = colBase + (wc<<6) + frow;
#pragma unroll
  for(int m=0;m<4;++m){
#pragma unroll
    for(int n=0;n<4;++n){
      const int grow0 = growB + (m<<4);
      const int gcol  = gcolB + (n<<4);
      f32x4 v = acc[m][n];
      if constexpr (EPI==0){
        f32x4 v2 = acc2[m][n];
#pragma unroll
        for(int j=0;j<4;++j){
          float t1 = v[j];
          float hv = (t1/(1.0f+expf(-t1))) * v2[j];
          obf[(size_t)(grow0+j)*Nout + gcol] = f2bf(hv);
        }
      } else if constexpr (EPI==1){
#pragma unroll
        for(int j=0;j<4;++j){
          float t1 = v[j];
          obf[(size_t)(grow0+j)*Nout + gcol] = f2bf(t1/(1.0f+expf(-t1)));
        }
      } else if constexpr (EPI==2){
        const float g = gamma[gcol];
#pragma unroll
        for(int j=0;j<4;++j){
          if(act[grow0+j] != 0.0f){
            const size_t ix = (size_t)(grow0+j)*Nout + gcol;
            xacc[ix] += v[j]*g;
          }
        }
      } else {
        const float g = gamma[gcol];
#pragma unroll
        for(int j=0;j<4;++j){
          const size_t ix = (size_t)(grow0+j)*Nout + gcol;
          xacc[ix] += v[j]*g;
        }
      }
    }
  }
}

// ---------------------------------------------------------------------------
extern "C" void kernel_launch(void* const* d_in, const int* in_sizes, int n_in,
                              void* d_out, int out_size, void* d_ws, size_t ws_size,
                              hipStream_t stream)
{
  (void)in_sizes; (void)n_in; (void)out_size;
  const float* x_in  = (const float*)d_in[0];
  const float* acbnw = (const float*)d_in[1];
  const float* routw = (const float*)d_in[2];
  const float* w1    = (const float*)d_in[3];
  const float* w2    = (const float*)d_in[4];
  const float* w3    = (const float*)d_in[5];
  const float* acbg  = (const float*)d_in[6];
  const float* arlnw = (const float*)d_in[7];
  const float* U     = (const float*)d_in[8];
  const float* Sv    = (const float*)d_in[9];
  const float* V     = (const float*)d_in[10];
  const float* arlg  = (const float*)d_in[11];
  const float* bitnw = (const float*)d_in[12];
  const float* wup   = (const float*)d_in[13];
  const float* wdn   = (const float*)d_in[14];
  const float* bitg  = (const float*)d_in[15];

  float* xs = (float*)d_out;           // x state lives in d_out (fp32 [N,D])
  char* ws = (char*)d_ws;

  const bool big = (ws_size >= (size_t)185000000);

  hipMemcpyAsync(xs, x_in, (size_t)NTOK*D_DIM*sizeof(float),
                 hipMemcpyDeviceToDevice, stream);

  const long long n8w = (long long)H_DIM*D_DIM/8;

  if (big) {
    unsigned short* xn  = (unsigned short*)(ws);                  // 16 MiB
    unsigned short* hb  = (unsigned short*)(ws + 16777216);       // 64 MiB
    unsigned short* wb1 = (unsigned short*)(ws + 83886080);       // 32 MiB
    unsigned short* wb3 = (unsigned short*)(ws + 117440512);      // 32 MiB
    unsigned short* wb2 = (unsigned short*)(ws + 150994944);      // 32 MiB
    float*  act   = (float*)(ws + 184549376);
    double* parts = (double*)(ws + 184565760);
    float*  scal  = (float*)(ws + 184573952);

    const int gH = (NTOK/256)*(H_DIM/256);   // 512
    const int gD = (NTOK/256)*(D_DIM/128);   // 256

    for(int d=0; d<DEPTH; ++d){
      const size_t oD  = (size_t)d*D_DIM;
      const size_t oHD = (size_t)d*H_DIM*D_DIM;
      const size_t oR  = (size_t)d*R_DIM;
      const size_t oDR = (size_t)d*D_DIM*R_DIM;

      cvt_bf16<<<4096,256,0,stream>>>(w1+oHD, wb1, n8w);
      cvt_bf16<<<4096,256,0,stream>>>(w3+oHD, wb3, n8w);
      cvt_bf16<<<4096,256,0,stream>>>(w2+oHD, wb2, n8w);

      // ---- AdaptiveComputeBlock
      rowpass1<<<NTOK,256,0,stream>>>(xs, acbnw+oD, routw+oD, xn, act);
      gemm256<4,256><<<gH,512,0,stream>>>(          // t3 raw -> hb
          xn, wb3, H_DIM, D_DIM, hb, nullptr, nullptr, nullptr);
      gemm256<0,256><<<gH,512,0,stream>>>(          // h = silu(xn@w1^T)*t3 (in place)
          xn, wb1, H_DIM, D_DIM, hb, nullptr, nullptr, nullptr);
      gemm256<2,128><<<gD,512,0,stream>>>(          // x += masked ffn*gamma
          hb, wb2, D_DIM, H_DIM, nullptr, xs, acbg+oD, act);

      // ---- AdaptiveRankLinear + BitLinear input norm
      rowpass2<<<NTOK,256,0,stream>>>(xs, arlnw+oD, U+oDR, Sv+oR, V+oDR,
                                      arlg+oD, bitnw+oD, xn);

      // ---- BitLinear
      abs_part<<<1024,256,0,stream>>>(wup+oHD, parts);
      abs_final<<<1,256,0,stream>>>(parts, scal);
      tquant<<<2048,256,0,stream>>>(wup+oHD, scal, wb1);
      gemm256<1,256><<<gH,512,0,stream>>>(
          xn, wb1, H_DIM, D_DIM, hb, nullptr, nullptr, nullptr);

      abs_part<<<1024,256,0,stream>>>(wdn+oHD, parts);
      abs_final<<<1,256,0,stream>>>(parts, scal);
      tquant<<<2048,256,0,stream>>>(wdn+oHD, scal, wb2);
      gemm256<3,128><<<gD,512,0,stream>>>(
          hb, wb2, D_DIM, H_DIM, nullptr, xs, bitg+oD, nullptr);
    }
  } else {
    // fallback: round-1 layout (fp32 B reg-staged for w1/w3/w2)
    unsigned short* xn = (unsigned short*)(ws);                 // 16 MiB
    unsigned short* hb = (unsigned short*)(ws + 16777216);      // 64 MiB
    unsigned short* qb = (unsigned short*)(ws + 83886080);      // 32 MiB
    float*  act   = (float*)(ws + 117440512);
    double* parts = (double*)(ws + 117456896);
    float*  scal  = (float*)(ws + 117465088);

    const int gH = (NTOK/128)*(H_DIM/128);   // 2048
    const int gD = (NTOK/128)*(D_DIM/128);   // 512

    for(int d=0; d<DEPTH; ++d){
      const size_t oD  = (size_t)d*D_DIM;
      const size_t oHD = (size_t)d*H_DIM*D_DIM;
      const size_t oR  = (size_t)d*R_DIM;
      const size_t oDR = (size_t)d*D_DIM*R_DIM;

      rowpass1<<<NTOK,256,0,stream>>>(xs, acbnw+oD, routw+oD, xn, act);
      gemm128<0,false,true><<<gH,256,0,stream>>>(
          xn, w1+oHD, w3+oHD, H_DIM, D_DIM, hb, nullptr, nullptr, nullptr);
      gemm128<2,false,false><<<gD,256,0,stream>>>(
          hb, w2+oHD, nullptr, D_DIM, H_DIM, nullptr, xs, acbg+oD, act);

      rowpass2<<<NTOK,256,0,stream>>>(xs, arlnw+oD, U+oDR, Sv+oR, V+oDR,
                                      arlg+oD, bitnw+oD, xn);

      abs_part<<<1024,256,0,stream>>>(wup+oHD, parts);
      abs_final<<<1,256,0,stream>>>(parts, scal);
      tquant<<<2048,256,0,stream>>>(wup+oHD, scal, qb);
      gemm128<1,true,false><<<gH,256,0,stream>>>(
          xn, qb, nullptr, H_DIM, D_DIM, hb, nullptr, nullptr, nullptr);

      abs_part<<<1024,256,0,stream>>>(wdn+oHD, parts);
      abs_final<<<1,256,0,stream>>>(parts, scal);
      tquant<<<2048,256,0,stream>>>(wdn+oHD, scal, qb);
      gemm128<3,true,false><<<gD,256,0,stream>>>(
          hb, qb, nullptr, D_DIM, H_DIM, nullptr, xs, bitg+oD, nullptr);
    }
  }
}

// Round 4
// 2242.542 us; speedup vs baseline: 1.2954x; 1.0204x over previous
//
#include <hip/hip_runtime.h>

#define D_DIM 2048
#define H_DIM 8192
#define NTOK  4096
#define R_DIM 16
#define DEPTH 2

typedef float f32x4 __attribute__((ext_vector_type(4)));
typedef __bf16 bf16x8 __attribute__((ext_vector_type(8)));
typedef unsigned short u16x4 __attribute__((ext_vector_type(4)));
typedef unsigned short u16x8 __attribute__((ext_vector_type(8)));

typedef __attribute__((address_space(1))) void void_g;
typedef __attribute__((address_space(3))) void void_l;

__device__ __forceinline__ unsigned short f2bf(float f){
  __bf16 b = (__bf16)f;
  return __builtin_bit_cast(unsigned short, b);
}
__device__ __forceinline__ float bf2f(unsigned short u){
  unsigned int x = ((unsigned int)u) << 16;
  return __builtin_bit_cast(float, x);
}

__device__ __forceinline__ float wredf(float v){
#pragma unroll
  for(int o=32;o;o>>=1) v += __shfl_xor(v,o,64);
  return v;
}
__device__ __forceinline__ double wredd(double v){
#pragma unroll
  for(int o=32;o;o>>=1) v += __shfl_xor(v,o,64);
  return v;
}

__device__ __forceinline__ void gload_lds16(const void* g, void* l){
  __builtin_amdgcn_global_load_lds((void_g*)g, (void_l*)l, 16, 0, 0);
}

#define S_BARRIER   asm volatile("s_barrier" ::: "memory")

template<int N> __device__ __forceinline__ void waitvm(){
  if constexpr (N==0)      asm volatile("s_waitcnt vmcnt(0)" ::: "memory");
  else if constexpr (N==3) asm volatile("s_waitcnt vmcnt(3)" ::: "memory");
  else if constexpr (N==4) asm volatile("s_waitcnt vmcnt(4)" ::: "memory");
  else if constexpr (N==6) asm volatile("s_waitcnt vmcnt(6)" ::: "memory");
  else                     asm volatile("s_waitcnt vmcnt(8)" ::: "memory");
}

// ---------------------------------------------------------------------------
// fp32 -> bf16 bulk convert
// ---------------------------------------------------------------------------
__global__ __launch_bounds__(256) void cvt_bf16(const float* __restrict__ w,
                                                unsigned short* __restrict__ o,
                                                long long n8)
{
  for(long long i = (long long)blockIdx.x*256 + threadIdx.x; i < n8;
      i += (long long)gridDim.x*256){
    f32x4 a = ((const f32x4*)w)[2*i];
    f32x4 b = ((const f32x4*)w)[2*i+1];
    u16x8 v;
#pragma unroll
    for(int j=0;j<4;++j){ v[j] = f2bf(a[j]); v[4+j] = f2bf(b[j]); }
    ((u16x8*)o)[i] = v;
  }
}

// ---------------------------------------------------------------------------
// Row pass 1
// ---------------------------------------------------------------------------
__global__ __launch_bounds__(256) void rowpass1(
    const float* __restrict__ x, const float* __restrict__ nw,
    const float* __restrict__ rw, unsigned short* __restrict__ xn,
    float* __restrict__ act)
{
  const int row = blockIdx.x, tid = threadIdx.x;
  const int lane = tid & 63, wid = tid >> 6;
  const float* xr = x + (size_t)row*D_DIM + tid*8;
  f32x4 v0 = *(const f32x4*)xr;
  f32x4 v1 = *(const f32x4*)(xr+4);
  float ssq = 0.0f;
#pragma unroll
  for(int j=0;j<4;++j) ssq += v0[j]*v0[j] + v1[j]*v1[j];
  __shared__ float red[4];
  float t = wredf(ssq);
  if(lane==0) red[wid] = t;
  __syncthreads();
  const float rs = rsqrtf((red[0]+red[1]+red[2]+red[3])*(1.0f/D_DIM) + 1e-6f);

  f32x4 n0 = *(const f32x4*)(nw + tid*8);
  f32x4 n1 = *(const f32x4*)(nw + tid*8 + 4);
  f32x4 r0 = *(const f32x4*)(rw + tid*8);
  f32x4 r1 = *(const f32x4*)(rw + tid*8 + 4);
  float gp = 0.0f;
  u16x4 o0, o1;
#pragma unroll
  for(int j=0;j<4;++j){
    float a = v0[j]*rs*n0[j];
    float b = v1[j]*rs*n1[j];
    gp += a*r0[j] + b*r1[j];
    o0[j] = f2bf(a);
    o1[j] = f2bf(b);
  }
  unsigned short* xp = xn + (size_t)row*D_DIM + tid*8;
  *(u16x4*)xp = o0;
  *(u16x4*)(xp+4) = o1;

  float gd = wredf(gp);
  __syncthreads();
  if(lane==0) red[wid] = gd;
  __syncthreads();
  if(tid==0){
    float dot = red[0]+red[1]+red[2]+red[3];
    float g = 1.0f/(1.0f+expf(-dot));
    act[row] = (g > 0.35f) ? 1.0f : 0.0f;
  }
}

// ---------------------------------------------------------------------------
// Row pass 2 (ARL fused + next RMSNorm)
// ---------------------------------------------------------------------------
__global__ __launch_bounds__(256) void rowpass2(
    float* __restrict__ x, const float* __restrict__ anw,
    const float* __restrict__ U, const float* __restrict__ Sv,
    const float* __restrict__ V, const float* __restrict__ agam,
    const float* __restrict__ bnw, unsigned short* __restrict__ xn3)
{
  const int row = blockIdx.x, tid = threadIdx.x;
  const int lane = tid & 63, wid = tid >> 6;
  float* xr = x + (size_t)row*D_DIM + tid*8;
  f32x4 v0 = *(const f32x4*)xr;
  f32x4 v1 = *(const f32x4*)(xr+4);
  float ssq = 0.0f;
#pragma unroll
  for(int j=0;j<4;++j) ssq += v0[j]*v0[j] + v1[j]*v1[j];
  __shared__ float red[4];
  float t = wredf(ssq);
  if(lane==0) red[wid] = t;
  __syncthreads();
  const float rs = rsqrtf((red[0]+red[1]+red[2]+red[3])*(1.0f/D_DIM) + 1e-6f);

  f32x4 a0 = *(const f32x4*)(anw + tid*8);
  f32x4 a1 = *(const f32x4*)(anw + tid*8 + 4);
  float xn2[8];
#pragma unroll
  for(int j=0;j<4;++j){ xn2[j] = v0[j]*rs*a0[j]; xn2[4+j] = v1[j]*rs*a1[j]; }

  float pl[16];
#pragma unroll
  for(int r2=0;r2<16;++r2) pl[r2] = 0.0f;
#pragma unroll
  for(int j=0;j<8;++j){
    const int k = tid*8 + j;
    const f32x4* Up = (const f32x4*)(U + (size_t)k*R_DIM);
    f32x4 u0=Up[0], u1=Up[1], u2=Up[2], u3=Up[3];
    const float xv = xn2[j];
#pragma unroll
    for(int q=0;q<4;++q){
      pl[q]    += xv*u0[q];
      pl[4+q]  += xv*u1[q];
      pl[8+q]  += xv*u2[q];
      pl[12+q] += xv*u3[q];
    }
  }
#pragma unroll
  for(int r2=0;r2<16;++r2) pl[r2] = wredf(pl[r2]);
  __shared__ float lred[4][16];
  if(lane==0){
#pragma unroll
    for(int r2=0;r2<16;++r2) lred[wid][r2] = pl[r2];
  }
  __syncthreads();
  __shared__ float lowS[16];
  if(tid==0){
    float sa[16]; float totS = 0.0f;
#pragma unroll
    for(int r2=0;r2<16;++r2){ sa[r2] = fabsf(Sv[r2]); totS += sa[r2]; }
    totS = fmaxf(totS, 1e-8f);
    float c = 0.0f;
#pragma unroll
    for(int r2=0;r2<16;++r2){
      float lraw = lred[0][r2]+lred[1][r2]+lred[2][r2]+lred[3][r2];
      float keep = (r2==0) ? 1.0f : ((c/totS < 0.95f) ? 1.0f : 0.0f);
      c += sa[r2];
      lowS[r2] = lraw * Sv[r2] * keep;
    }
  }
  __syncthreads();

  f32x4 d0 = {0,0,0,0}, d1 = {0,0,0,0};
#pragma unroll
  for(int r2=0;r2<16;++r2){
    const float lr = lowS[r2];
    const f32x4* Vp = (const f32x4*)(V + (size_t)r2*D_DIM + tid*8);
    f32x4 q0 = Vp[0], q1 = Vp[1];
#pragma unroll
    for(int j=0;j<4;++j){ d0[j] += lr*q0[j]; d1[j] += lr*q1[j]; }
  }
  f32x4 g0 = *(const f32x4*)(agam + tid*8);
  f32x4 g1 = *(const f32x4*)(agam + tid*8 + 4);
  f32x4 xo0, xo1;
  float ssq2 = 0.0f;
#pragma unroll
  for(int j=0;j<4;++j){
    xo0[j] = v0[j] + d0[j]*g0[j];
    xo1[j] = v1[j] + d1[j]*g1[j];
    ssq2 += xo0[j]*xo0[j] + xo1[j]*xo1[j];
  }
  __syncthreads();
  float t2 = wredf(ssq2);
  if(lane==0) red[wid] = t2;
  __syncthreads();
  const float rs2 = rsqrtf((red[0]+red[1]+red[2]+red[3])*(1.0f/D_DIM) + 1e-6f);
  f32x4 b0 = *(const f32x4*)(bnw + tid*8);
  f32x4 b1 = *(const f32x4*)(bnw + tid*8 + 4);
  u16x4 o0, o1;
#pragma unroll
  for(int j=0;j<4;++j){
    o0[j] = f2bf(xo0[j]*rs2*b0[j]);
    o1[j] = f2bf(xo1[j]*rs2*b1[j]);
  }
  *(f32x4*)xr = xo0;
  *(f32x4*)(xr+4) = xo1;
  unsigned short* xp = xn3 + (size_t)row*D_DIM + tid*8;
  *(u16x4*)xp = o0;
  *(u16x4*)(xp+4) = o1;
}

// ---------------------------------------------------------------------------
// Ternary quantization
// ---------------------------------------------------------------------------
__global__ __launch_bounds__(256) void abs_part(const float* __restrict__ w,
                                                double* __restrict__ part)
{
  const long long n4 = (long long)H_DIM*D_DIM/4;
  const int tid = threadIdx.x;
  const int lane = tid & 63, wid = tid >> 6;
  float s = 0.0f;
  for(long long i = (long long)blockIdx.x*256 + tid; i < n4;
      i += (long long)gridDim.x*256){
    f32x4 v = ((const f32x4*)w)[i];
    s += fabsf(v[0]) + fabsf(v[1]) + fabsf(v[2]) + fabsf(v[3]);
  }
  double ds = wredd((double)s);
  __shared__ double sred[4];
  if(lane==0) sred[wid] = ds;
  __syncthreads();
  if(tid==0) part[blockIdx.x] = sred[0]+sred[1]+sred[2]+sred[3];
}

__global__ __launch_bounds__(256) void abs_final(const double* __restrict__ part,
                                                 float* __restrict__ scale)
{
  const int tid = threadIdx.x;
  const int lane = tid & 63, wid = tid >> 6;
  double s = 0.0;
  for(int i=tid;i<1024;i+=256) s += part[i];
  s = wredd(s);
  __shared__ double sred[4];
  if(lane==0) sred[wid] = s;
  __syncthreads();
  if(tid==0){
    double m = (sred[0]+sred[1]+sred[2]+sred[3]) / ((double)H_DIM*(double)D_DIM);
    scale[0] = (float)fmax(m, 1e-8);
  }
}

__global__ __launch_bounds__(256) void tquant(const float* __restrict__ w,
                                              const float* __restrict__ scale,
                                              unsigned short* __restrict__ q)
{
  const long long n4 = (long long)H_DIM*D_DIM/4;
  const float s = scale[0];
  for(long long i = (long long)blockIdx.x*256 + threadIdx.x; i < n4;
      i += (long long)gridDim.x*256){
    f32x4 v = ((const f32x4*)w)[i];
    u16x4 o;
#pragma unroll
    for(int j=0;j<4;++j){
      float r = rintf(v[j]/s);
      r = fminf(1.0f, fmaxf(-1.0f, r));
      o[j] = f2bf(r*s);
    }
    ((u16x4*)q)[i] = o;
  }
}

// ---------------------------------------------------------------------------
// 256xBN 8-wave deep-pipelined GEMM with READ-AHEAD-1 fragment pipeline.
// C[M=4096, Nout] = A[M,K](bf16) @ B[Nout,K]^T.  BK=32, 4 LDS tile slots,
// stage tile T+3 while computing T; frags for phase P+1 read during phase P
// (counted lgkm waits inserted by the compiler).  vmcnt(UPT) once per tile.
// EPI: 0 SwiGLU-combine in place   1 silu->obf   2 masked residual RMW
//      3 residual RMW              4 raw bf16 -> obf
// ---------------------------------------------------------------------------
template<int EPI, int BN_>
__global__ __launch_bounds__(512, 2) void gemm256(
    const unsigned short* __restrict__ A,
    const unsigned short* __restrict__ B,
    const int Nout, const int K,
    unsigned short* __restrict__ obf,
    float* __restrict__ xacc,
    const float* __restrict__ gamma,
    const float* __restrict__ act)
{
  constexpr int WN     = BN_/4;        // per-wave N (64 or 32)
  constexpr int NFRAG  = WN/16;        // 4 or 2
  constexpr int BUNITS = (BN_*32*2)/8192;  // 2 or 1
  constexpr int UPT    = 2 + BUNITS;   // stage units per tile (4 or 3)
  constexpr int ASLOT  = 8192;         // ushorts per A slot (16 KB)
  constexpr int BSLOT  = BN_*32;       // ushorts per B slot

  __shared__ __align__(16) unsigned short smA[4*ASLOT];
  __shared__ __align__(16) unsigned short smB[4*BSLOT];

  const int tid  = threadIdx.x;
  const int lane = tid & 63;
  const int wid  = tid >> 6;           // 0..7
  const int wr   = wid >> 2;           // 0..1  (2 M-warps)
  const int wc   = wid & 3;            // 0..3  (4 N-warps)
  const int frow = lane & 15;
  const int k16  = lane >> 4;

  // XCD-chunked swizzle; rows fast (B-panel hot in per-XCD L2)
  const int nwg = (int)gridDim.x;
  const int bid = (int)blockIdx.x;
  const int cpx = nwg >> 3;                       // nwg % 8 == 0
  const int swz = (bid & 7)*cpx + (bid >> 3);
  const int rowBase = (swz & 15) << 8;            // M/256 == 16
  const int colBase = (swz >> 4) * BN_;

  // staging thread map: row = tid>>2 (+u*128), chunk XOR-swizzled
  const int trow = tid >> 2;
  const int tchk = (tid & 3) ^ ((tid >> 3) & 3);
  const unsigned short* Abase = A + (size_t)(rowBase + trow)*K + tchk*8;
  const unsigned short* Bbase = B + (size_t)(colBase + trow)*K + tchk*8;

  auto stageA = [&](int T, int u){
    gload_lds16(Abase + (size_t)u*128*K + (size_t)T*32,
                &smA[(T&3)*ASLOT + u*4096 + tid*8]);
  };
  auto stageB = [&](int T, int u){
    gload_lds16(Bbase + (size_t)u*128*K + (size_t)T*32,
                &smB[(T&3)*BSLOT + u*4096 + tid*8]);
  };

  // fragment LDS offsets (ushort units), swizzled chunk
  int aoff[8], boff[NFRAG];
#pragma unroll
  for(int m=0;m<8;++m){
    int row = wr*128 + m*16 + frow;
    int ch  = k16 ^ ((row>>1)&3);
    aoff[m] = row*32 + ch*8;
  }
#pragma unroll
  for(int n=0;n<NFRAG;++n){
    int row = wc*WN + n*16 + frow;
    int ch  = k16 ^ ((row>>1)&3);
    boff[n] = row*32 + ch*8;
  }

  const f32x4 vzero = {0.0f,0.0f,0.0f,0.0f};
  f32x4 acc[8][NFRAG];
#pragma unroll
  for(int m=0;m<8;++m)
#pragma unroll
    for(int n=0;n<NFRAG;++n) acc[m][n] = vzero;

  const int NT = K >> 5;

  // prologue: stage tiles 0,1,2
#pragma unroll
  for(int t=0;t<3;++t){
    stageA(t,0); stageA(t,1);
    stageB(t,0);
    if constexpr (BUNITS==2) stageB(t,1);
  }
  waitvm<2*UPT>();          // own tile-0 units landed (newest 2*UPT = t1,t2)
  S_BARRIER;                // => ALL waves' tile-0 stages landed

  // pre-read tile-0 phase-q0 operands
  bf16x8 aE[4], aO[4], bb0[NFRAG], bb1[NFRAG];
#pragma unroll
  for(int n=0;n<NFRAG;++n) bb0[n] = *(const bf16x8*)&smB[boff[n]];
#pragma unroll
  for(int m=0;m<4;++m)     aE[m]  = *(const bf16x8*)&smA[aoff[m]];

  auto iterBody = [&](int T, bf16x8 (&bCur)[NFRAG], bf16x8 (&bNew)[NFRAG]){
    const int sT  = (T&3)*ASLOT;
    const int sBT1 = ((T+1)&3)*BSLOT;
    const int sAT1 = ((T+1)&3)*ASLOT;
    const bool pf = (T+3 < NT);
    // ---- q0: read af1_T (next-phase A); MFMA acc0..3 with (aE=af0_T, bCur)
#pragma unroll
    for(int m=0;m<4;++m) aO[m] = *(const bf16x8*)&smA[sT + aoff[4+m]];
    if(pf){ stageA(T+3,0); stageA(T+3,1); }
    S_BARRIER;
    __builtin_amdgcn_s_setprio(1);
#pragma unroll
    for(int m=0;m<4;++m)
#pragma unroll
      for(int n=0;n<NFRAG;++n)
        acc[m][n] = __builtin_amdgcn_mfma_f32_16x16x32_bf16(aE[m], bCur[n], acc[m][n], 0,0,0);
    __builtin_amdgcn_s_setprio(0);
    S_BARRIER;
    // ---- q1: read b_{T+1} + af0_{T+1} (next-tile, landed per prev iter's
    //          vmcnt+barrier); MFMA acc4..7 with (aO=af1_T, bCur)
#pragma unroll
    for(int n=0;n<NFRAG;++n) bNew[n] = *(const bf16x8*)&smB[sBT1 + boff[n]];
#pragma unroll
    for(int m=0;m<4;++m)     aE[m]   = *(const bf16x8*)&smA[sAT1 + aoff[m]];
    if(pf){ stageB(T+3,0); if constexpr (BUNITS==2) stageB(T+3,1); }
    S_BARRIER;
    __builtin_amdgcn_s_setprio(1);
#pragma unroll
    for(int m=0;m<4;++m)
#pragma unroll
      for(int n=0;n<NFRAG;++n)
        acc[4+m][n] = __builtin_amdgcn_mfma_f32_16x16x32_bf16(aO[m], bCur[n], acc[4+m][n], 0,0,0);
    __builtin_amdgcn_s_setprio(0);
    if(pf) waitvm<UPT>(); else waitvm<0>();   // own next-tile stages landed
    S_BARRIER;                                 // => all waves'
  };

  for(int T=0; T<NT; T+=2){
    iterBody(T,   bb0, bb1);
    iterBody(T+1, bb1, bb0);
  }

  // ---- epilogue. C/D: col = lane&15, row = k16*4 + j
  const int growB = rowBase + wr*128 + (k16<<2);
  const int gcolB = colBase + wc*WN + frow;
#pragma unroll
  for(int m=0;m<8;++m){
#pragma unroll
    for(int n=0;n<NFRAG;++n){
      const int grow0 = growB + m*16;
      const int gcol  = gcolB + n*16;
      f32x4 v = acc[m][n];
      if constexpr (EPI==0){
#pragma unroll
        for(int j=0;j<4;++j){
          const size_t ix = (size_t)(grow0+j)*Nout + gcol;
          float t1 = v[j];
          float s  = t1/(1.0f+expf(-t1));
          float t3 = bf2f(obf[ix]);
          obf[ix] = f2bf(s*t3);
        }
      } else if constexpr (EPI==1){
#pragma unroll
        for(int j=0;j<4;++j){
          float t1 = v[j];
          obf[(size_t)(grow0+j)*Nout + gcol] = f2bf(t1/(1.0f+expf(-t1)));
        }
      } else if constexpr (EPI==2){
        const float g = gamma[gcol];
#pragma unroll
        for(int j=0;j<4;++j){
          if(act[grow0+j] != 0.0f){
            const size_t ix = (size_t)(grow0+j)*Nout + gcol;
            xacc[ix] += v[j]*g;
          }
        }
      } else if constexpr (EPI==3){
        const float g = gamma[gcol];
#pragma unroll
        for(int j=0;j<4;++j){
          const size_t ix = (size_t)(grow0+j)*Nout + gcol;
          xacc[ix] += v[j]*g;
        }
      } else {
#pragma unroll
        for(int j=0;j<4;++j){
          obf[(size_t)(grow0+j)*Nout + gcol] = f2bf(v[j]);
        }
      }
    }
  }
}

// ---------------------------------------------------------------------------
// fallback 128^2 GEMM (round-1 structure) for small ws
// ---------------------------------------------------------------------------
template<int EPI, bool BBF16, bool DUAL>
__global__ __launch_bounds__(256, DUAL?2:3) void gemm128(
    const unsigned short* __restrict__ A,
    const void* __restrict__ B0v,
    const void* __restrict__ B1v,
    const int Nout, const int K,
    unsigned short* __restrict__ obf,
    float* __restrict__ xacc,
    const float* __restrict__ gamma,
    const float* __restrict__ act)
{
  __shared__ __align__(16) unsigned short smA[128*32];
  __shared__ __align__(16) unsigned short smB[128*32];
  __shared__ __align__(16) unsigned short smB2[DUAL?(128*32):8];

  const int tid  = threadIdx.x;
  const int lane = tid & 63;
  const int wid  = tid >> 6;
  const int wr   = wid >> 1;
  const int wc   = wid & 1;
  const int frow = lane & 15;
  const int k16  = lane >> 4;

  const int nwg = (int)gridDim.x;
  const int bid = (int)blockIdx.x;
  const int swz = ((bid & 7) * (nwg >> 3)) + (bid >> 3);
  const int rowBase = (swz & 31) << 7;
  const int colBase = (swz >> 5) << 7;

  int srow[2], schk[2];
#pragma unroll
  for(int r=0;r<2;++r){
    int t = tid + (r<<8);
    srow[r] = t >> 2;
    schk[r] = (t & 3) ^ ((srow[r] >> 1) & 3);
  }

  const f32x4 vzero = {0.0f,0.0f,0.0f,0.0f};
  f32x4 acc[4][4];
  f32x4 acc2[4][4];
#pragma unroll
  for(int m=0;m<4;++m)
#pragma unroll
    for(int n=0;n<4;++n){ acc[m][n] = vzero; acc2[m][n] = vzero; }

  for(int k0=0;k0<K;k0+=32){
#pragma unroll
    for(int r=0;r<2;++r){
      const unsigned short* s = A + (size_t)(rowBase+srow[r])*K + k0 + schk[r]*8;
      gload_lds16(s, &smA[((r<<8)+(wid<<6))*8]);
    }
    if constexpr (BBF16){
      const unsigned short* B0 = (const unsigned short*)B0v;
#pragma unroll
      for(int r=0;r<2;++r){
        const unsigned short* s = B0 + (size_t)(colBase+srow[r])*K + k0 + schk[r]*8;
        gload_lds16(s, &smB[((r<<8)+(wid<<6))*8]);
      }
    } else {
      const float* B0 = (const float*)B0v;
#pragma unroll
      for(int r=0;r<2;++r){
        const float* s = B0 + (size_t)(colBase+srow[r])*K + k0 + schk[r]*8;
        f32x4 f0 = *(const f32x4*)s;
        f32x4 f1 = *(const f32x4*)(s+4);
        u16x8 o;
#pragma unroll
        for(int j=0;j<4;++j){ o[j] = f2bf(f0[j]); o[4+j] = f2bf(f1[j]); }
        *(u16x8*)&smB[(size_t)(tid+(r<<8))*8] = o;
      }
      if constexpr (DUAL){
        const float* B1 = (const float*)B1v;
#pragma unroll
        for(int r=0;r<2;++r){
          const float* s = B1 + (size_t)(colBase+srow[r])*K + k0 + schk[r]*8;
          f32x4 f0 = *(const f32x4*)s;
          f32x4 f1 = *(const f32x4*)(s+4);
          u16x8 o;
#pragma unroll
          for(int j=0;j<4;++j){ o[j] = f2bf(f0[j]); o[4+j] = f2bf(f1[j]); }
          *(u16x8*)&smB2[(size_t)(tid+(r<<8))*8] = o;
        }
      }
    }
    __syncthreads();

    bf16x8 af[4];
#pragma unroll
    for(int m=0;m<4;++m){
      int rr = (wr<<6)+(m<<4)+frow;
      int ch = k16 ^ ((rr>>1)&3);
      af[m] = *(const bf16x8*)&smA[rr*32 + ch*8];
    }
    bf16x8 bfr[4];
    bf16x8 bfr2[4];
#pragma unroll
    for(int n=0;n<4;++n){
      int rr = (wc<<6)+(n<<4)+frow;
      int ch = k16 ^ ((rr>>1)&3);
      bfr[n] = *(const bf16x8*)&smB[rr*32 + ch*8];
      if constexpr (DUAL) bfr2[n] = *(const bf16x8*)&smB2[rr*32 + ch*8];
    }
#pragma unroll
    for(int m=0;m<4;++m)
#pragma unroll
      for(int n=0;n<4;++n){
        acc[m][n] = __builtin_amdgcn_mfma_f32_16x16x32_bf16(af[m], bfr[n], acc[m][n], 0,0,0);
        if constexpr (DUAL)
          acc2[m][n] = __builtin_amdgcn_mfma_f32_16x16x32_bf16(af[m], bfr2[n], acc2[m][n], 0,0,0);
      }
    __syncthreads();
  }

  const int growB = rowBase + (wr<<6) + (k16<<2);
  const int gcolB = colBase + (wc<<6) + frow;
#pragma unroll
  for(int m=0;m<4;++m){
#pragma unroll
    for(int n=0;n<4;++n){
      const int grow0 = growB + (m<<4);
      const int gcol  = gcolB + (n<<4);
      f32x4 v = acc[m][n];
      if constexpr (EPI==0){
        f32x4 v2 = acc2[m][n];
#pragma unroll
        for(int j=0;j<4;++j){
          float t1 = v[j];
          float hv = (t1/(1.0f+expf(-t1))) * v2[j];
          obf[(size_t)(grow0+j)*Nout + gcol] = f2bf(hv);
        }
      } else if constexpr (EPI==1){
#pragma unroll
        for(int j=0;j<4;++j){
          float t1 = v[j];
          obf[(size_t)(grow0+j)*Nout + gcol] = f2bf(t1/(1.0f+expf(-t1)));
        }
      } else if constexpr (EPI==2){
        const float g = gamma[gcol];
#pragma unroll
        for(int j=0;j<4;++j){
          if(act[grow0+j] != 0.0f){
            const size_t ix = (size_t)(grow0+j)*Nout + gcol;
            xacc[ix] += v[j]*g;
          }
        }
      } else {
        const float g = gamma[gcol];
#pragma unroll
        for(int j=0;j<4;++j){
          const size_t ix = (size_t)(grow0+j)*Nout + gcol;
          xacc[ix] += v[j]*g;
        }
      }
    }
  }
}

// ---------------------------------------------------------------------------
extern "C" void kernel_launch(void* const* d_in, const int* in_sizes, int n_in,
                              void* d_out, int out_size, void* d_ws, size_t ws_size,
                              hipStream_t stream)
{
  (void)in_sizes; (void)n_in; (void)out_size;
  const float* x_in  = (const float*)d_in[0];
  const float* acbnw = (const float*)d_in[1];
  const float* routw = (const float*)d_in[2];
  const float* w1    = (const float*)d_in[3];
  const float* w2    = (const float*)d_in[4];
  const float* w3    = (const float*)d_in[5];
  const float* acbg  = (const float*)d_in[6];
  const float* arlnw = (const float*)d_in[7];
  const float* U     = (const float*)d_in[8];
  const float* Sv    = (const float*)d_in[9];
  const float* V     = (const float*)d_in[10];
  const float* arlg  = (const float*)d_in[11];
  const float* bitnw = (const float*)d_in[12];
  const float* wup   = (const float*)d_in[13];
  const float* wdn   = (const float*)d_in[14];
  const float* bitg  = (const float*)d_in[15];

  float* xs = (float*)d_out;           // x state lives in d_out (fp32 [N,D])
  char* ws = (char*)d_ws;

  const bool big = (ws_size >= (size_t)185000000);

  hipMemcpyAsync(xs, x_in, (size_t)NTOK*D_DIM*sizeof(float),
                 hipMemcpyDeviceToDevice, stream);

  const long long n8w = (long long)H_DIM*D_DIM/8;

  if (big) {
    unsigned short* xn  = (unsigned short*)(ws);                  // 16 MiB
    unsigned short* hb  = (unsigned short*)(ws + 16777216);       // 64 MiB
    unsigned short* wb1 = (unsigned short*)(ws + 83886080);       // 32 MiB
    unsigned short* wb3 = (unsigned short*)(ws + 117440512);      // 32 MiB
    unsigned short* wb2 = (unsigned short*)(ws + 150994944);      // 32 MiB
    float*  act   = (float*)(ws + 184549376);
    double* parts = (double*)(ws + 184565760);
    float*  scal  = (float*)(ws + 184573952);

    const int gH = (NTOK/256)*(H_DIM/256);   // 512
    const int gD = (NTOK/256)*(D_DIM/128);   // 256

    for(int d=0; d<DEPTH; ++d){
      const size_t oD  = (size_t)d*D_DIM;
      const size_t oHD = (size_t)d*H_DIM*D_DIM;
      const size_t oR  = (size_t)d*R_DIM;
      const size_t oDR = (size_t)d*D_DIM*R_DIM;

      cvt_bf16<<<4096,256,0,stream>>>(w1+oHD, wb1, n8w);
      cvt_bf16<<<4096,256,0,stream>>>(w3+oHD, wb3, n8w);
      cvt_bf16<<<4096,256,0,stream>>>(w2+oHD, wb2, n8w);

      // ---- AdaptiveComputeBlock
      rowpass1<<<NTOK,256,0,stream>>>(xs, acbnw+oD, routw+oD, xn, act);
      gemm256<4,256><<<gH,512,0,stream>>>(          // t3 raw -> hb
          xn, wb3, H_DIM, D_DIM, hb, nullptr, nullptr, nullptr);
      gemm256<0,256><<<gH,512,0,stream>>>(          // h = silu(xn@w1^T)*t3 (in place)
          xn, wb1, H_DIM, D_DIM, hb, nullptr, nullptr, nullptr);
      gemm256<2,128><<<gD,512,0,stream>>>(          // x += masked ffn*gamma
          hb, wb2, D_DIM, H_DIM, nullptr, xs, acbg+oD, act);

      // ---- AdaptiveRankLinear + BitLinear input norm
      rowpass2<<<NTOK,256,0,stream>>>(xs, arlnw+oD, U+oDR, Sv+oR, V+oDR,
                                      arlg+oD, bitnw+oD, xn);

      // ---- BitLinear
      abs_part<<<1024,256,0,stream>>>(wup+oHD, parts);
      abs_final<<<1,256,0,stream>>>(parts, scal);
      tquant<<<2048,256,0,stream>>>(wup+oHD, scal, wb1);
      gemm256<1,256><<<gH,512,0,stream>>>(
          xn, wb1, H_DIM, D_DIM, hb, nullptr, nullptr, nullptr);

      abs_part<<<1024,256,0,stream>>>(wdn+oHD, parts);
      abs_final<<<1,256,0,stream>>>(parts, scal);
      tquant<<<2048,256,0,stream>>>(wdn+oHD, scal, wb2);
      gemm256<3,128><<<gD,512,0,stream>>>(
          hb, wb2, D_DIM, H_DIM, nullptr, xs, bitg+oD, nullptr);
    }
  } else {
    // fallback: round-1 layout (fp32 B reg-staged for w1/w3/w2)
    unsigned short* xn = (unsigned short*)(ws);                 // 16 MiB
    unsigned short* hb = (unsigned short*)(ws + 16777216);      // 64 MiB
    unsigned short* qb = (unsigned short*)(ws + 83886080);      // 32 MiB
    float*  act   = (float*)(ws + 117440512);
    double* parts = (double*)(ws + 117456896);
    float*  scal  = (float*)(ws + 117465088);

    const int gH = (NTOK/128)*(H_DIM/128);   // 2048
    const int gD = (NTOK/128)*(D_DIM/128);   // 512

    for(int d=0; d<DEPTH; ++d){
      const size_t oD  = (size_t)d*D_DIM;
      const size_t oHD = (size_t)d*H_DIM*D_DIM;
      const size_t oR  = (size_t)d*R_DIM;
      const size_t oDR = (size_t)d*D_DIM*R_DIM;

      rowpass1<<<NTOK,256,0,stream>>>(xs, acbnw+oD, routw+oD, xn, act);
      gemm128<0,false,true><<<gH,256,0,stream>>>(
          xn, w1+oHD, w3+oHD, H_DIM, D_DIM, hb, nullptr, nullptr, nullptr);
      gemm128<2,false,false><<<gD,256,0,stream>>>(
          hb, w2+oHD, nullptr, D_DIM, H_DIM, nullptr, xs, acbg+oD, act);

      rowpass2<<<NTOK,256,0,stream>>>(xs, arlnw+oD, U+oDR, Sv+oR, V+oDR,
                                      arlg+oD, bitnw+oD, xn);

      abs_part<<<1024,256,0,stream>>>(wup+oHD, parts);
      abs_final<<<1,256,0,stream>>>(parts, scal);
      tquant<<<2048,256,0,stream>>>(wup+oHD, scal, qb);
      gemm128<1,true,false><<<gH,256,0,stream>>>(
          xn, qb, nullptr, H_DIM, D_DIM, hb, nullptr, nullptr, nullptr);

      abs_part<<<1024,256,0,stream>>>(wdn+oHD, parts);
      abs_final<<<1,256,0,stream>>>(parts, scal);
      tquant<<<2048,256,0,stream>>>(wdn+oHD, scal, qb);
      gemm128<3,true,false><<<gD,256,0,stream>>>(
          hb, qb, nullptr, D_DIM, H_DIM, nullptr, xs, bitg+oD, nullptr);
    }
  }
}

// Round 5
// 1674.673 us; speedup vs baseline: 1.7346x; 1.3391x over previous
//
#include <hip/hip_runtime.h>

#define D_DIM 2048
#define H_DIM 8192
#define NTOK  4096
#define R_DIM 16
#define DEPTH 2

typedef float f32x4 __attribute__((ext_vector_type(4)));
typedef __bf16 bf16x8 __attribute__((ext_vector_type(8)));
typedef unsigned short u16x4 __attribute__((ext_vector_type(4)));
typedef unsigned short u16x8 __attribute__((ext_vector_type(8)));
typedef int i32x4 __attribute__((ext_vector_type(4)));
typedef int i32x2 __attribute__((ext_vector_type(2)));

typedef __attribute__((address_space(1))) void void_g;
typedef __attribute__((address_space(3))) void void_l;

__device__ __forceinline__ unsigned short f2bf(float f){
  __bf16 b = (__bf16)f;
  return __builtin_bit_cast(unsigned short, b);
}
__device__ __forceinline__ float bf2f(unsigned short u){
  unsigned int x = ((unsigned int)u) << 16;
  return __builtin_bit_cast(float, x);
}

__device__ __forceinline__ float wredf(float v){
#pragma unroll
  for(int o=32;o;o>>=1) v += __shfl_xor(v,o,64);
  return v;
}
__device__ __forceinline__ float wredmax(float v){
#pragma unroll
  for(int o=32;o;o>>=1) v = fmaxf(v, __shfl_xor(v,o,64));
  return v;
}
__device__ __forceinline__ double wredd(double v){
#pragma unroll
  for(int o=32;o;o>>=1) v += __shfl_xor(v,o,64);
  return v;
}

__device__ __forceinline__ void gload_lds16(const void* g, void* l){
  __builtin_amdgcn_global_load_lds((void_g*)g, (void_l*)l, 16, 0, 0);
}

__device__ __forceinline__ int clampi(int v, int lim){
  return v > lim ? lim : (v < -lim ? -lim : v);
}
__device__ __forceinline__ int pack4q(float a, float b, float c, float d,
                                      float inv, int lim){
  int qa = clampi((int)rintf(a*inv), lim);
  int qb = clampi((int)rintf(b*inv), lim);
  int qc = clampi((int)rintf(c*inv), lim);
  int qd = clampi((int)rintf(d*inv), lim);
  return (qa&255) | ((qb&255)<<8) | ((qc&255)<<16) | ((qd&255)<<24);
}

// ---------------------------------------------------------------------------
// Row pass 1 (i8): xn=rms_norm -> per-row i8 quant; gate -> act mask (fp32)
// ---------------------------------------------------------------------------
__global__ __launch_bounds__(256) void rowpass1_i8(
    const float* __restrict__ x, const float* __restrict__ nw,
    const float* __restrict__ rw, signed char* __restrict__ xq,
    float* __restrict__ sxn, float* __restrict__ act)
{
  const int row = blockIdx.x, tid = threadIdx.x;
  const int lane = tid & 63, wid = tid >> 6;
  const float* xr = x + (size_t)row*D_DIM + tid*8;
  f32x4 v0 = *(const f32x4*)xr;
  f32x4 v1 = *(const f32x4*)(xr+4);
  float ssq = 0.0f;
#pragma unroll
  for(int j=0;j<4;++j) ssq += v0[j]*v0[j] + v1[j]*v1[j];
  __shared__ float red[4];
  float t = wredf(ssq);
  if(lane==0) red[wid] = t;
  __syncthreads();
  const float rs = rsqrtf((red[0]+red[1]+red[2]+red[3])*(1.0f/D_DIM) + 1e-6f);

  f32x4 n0 = *(const f32x4*)(nw + tid*8);
  f32x4 n1 = *(const f32x4*)(nw + tid*8 + 4);
  f32x4 r0 = *(const f32x4*)(rw + tid*8);
  f32x4 r1 = *(const f32x4*)(rw + tid*8 + 4);
  float a[8];
  float gp = 0.0f, am = 0.0f;
#pragma unroll
  for(int j=0;j<4;++j){
    a[j]   = v0[j]*rs*n0[j];
    a[4+j] = v1[j]*rs*n1[j];
    gp += a[j]*r0[j] + a[4+j]*r1[j];
    am = fmaxf(am, fmaxf(fabsf(a[j]), fabsf(a[4+j])));
  }
  // row absmax
  float wm = wredmax(am);
  __syncthreads();
  if(lane==0) red[wid] = wm;
  __syncthreads();
  const float rowmax = fmaxf(fmaxf(red[0],red[1]), fmaxf(red[2],red[3]));
  const float guard = fmaxf(rowmax, 1e-12f);
  const float inv = 127.0f/guard;
  i32x2 q;
  q[0] = pack4q(a[0],a[1],a[2],a[3], inv, 127);
  q[1] = pack4q(a[4],a[5],a[6],a[7], inv, 127);
  *(i32x2*)(xq + (size_t)row*D_DIM + tid*8) = q;

  float gd = wredf(gp);
  __syncthreads();
  if(lane==0) red[wid] = gd;
  __syncthreads();
  if(tid==0){
    sxn[row] = guard/127.0f;
    float dot = red[0]+red[1]+red[2]+red[3];
    float g = 1.0f/(1.0f+expf(-dot));
    act[row] = (g > 0.35f) ? 1.0f : 0.0f;
  }
}

// ---------------------------------------------------------------------------
// Row pass 2 (i8): ARL fp32 fused + next RMSNorm -> per-row i8 quant
// ---------------------------------------------------------------------------
__global__ __launch_bounds__(256) void rowpass2_i8(
    float* __restrict__ x, const float* __restrict__ anw,
    const float* __restrict__ U, const float* __restrict__ Sv,
    const float* __restrict__ V, const float* __restrict__ agam,
    const float* __restrict__ bnw, signed char* __restrict__ xq,
    float* __restrict__ sxn)
{
  const int row = blockIdx.x, tid = threadIdx.x;
  const int lane = tid & 63, wid = tid >> 6;
  float* xr = x + (size_t)row*D_DIM + tid*8;
  f32x4 v0 = *(const f32x4*)xr;
  f32x4 v1 = *(const f32x4*)(xr+4);
  float ssq = 0.0f;
#pragma unroll
  for(int j=0;j<4;++j) ssq += v0[j]*v0[j] + v1[j]*v1[j];
  __shared__ float red[4];
  float t = wredf(ssq);
  if(lane==0) red[wid] = t;
  __syncthreads();
  const float rs = rsqrtf((red[0]+red[1]+red[2]+red[3])*(1.0f/D_DIM) + 1e-6f);

  f32x4 a0 = *(const f32x4*)(anw + tid*8);
  f32x4 a1 = *(const f32x4*)(anw + tid*8 + 4);
  float xn2[8];
#pragma unroll
  for(int j=0;j<4;++j){ xn2[j] = v0[j]*rs*a0[j]; xn2[4+j] = v1[j]*rs*a1[j]; }

  float pl[16];
#pragma unroll
  for(int r2=0;r2<16;++r2) pl[r2] = 0.0f;
#pragma unroll
  for(int j=0;j<8;++j){
    const int k = tid*8 + j;
    const f32x4* Up = (const f32x4*)(U + (size_t)k*R_DIM);
    f32x4 u0=Up[0], u1=Up[1], u2=Up[2], u3=Up[3];
    const float xv = xn2[j];
#pragma unroll
    for(int q=0;q<4;++q){
      pl[q]    += xv*u0[q];
      pl[4+q]  += xv*u1[q];
      pl[8+q]  += xv*u2[q];
      pl[12+q] += xv*u3[q];
    }
  }
#pragma unroll
  for(int r2=0;r2<16;++r2) pl[r2] = wredf(pl[r2]);
  __shared__ float lred[4][16];
  if(lane==0){
#pragma unroll
    for(int r2=0;r2<16;++r2) lred[wid][r2] = pl[r2];
  }
  __syncthreads();
  __shared__ float lowS[16];
  if(tid==0){
    float sa[16]; float totS = 0.0f;
#pragma unroll
    for(int r2=0;r2<16;++r2){ sa[r2] = fabsf(Sv[r2]); totS += sa[r2]; }
    totS = fmaxf(totS, 1e-8f);
    float c = 0.0f;
#pragma unroll
    for(int r2=0;r2<16;++r2){
      float lraw = lred[0][r2]+lred[1][r2]+lred[2][r2]+lred[3][r2];
      float keep = (r2==0) ? 1.0f : ((c/totS < 0.95f) ? 1.0f : 0.0f);
      c += sa[r2];
      lowS[r2] = lraw * Sv[r2] * keep;
    }
  }
  __syncthreads();

  f32x4 d0 = {0,0,0,0}, d1 = {0,0,0,0};
#pragma unroll
  for(int r2=0;r2<16;++r2){
    const float lr = lowS[r2];
    const f32x4* Vp = (const f32x4*)(V + (size_t)r2*D_DIM + tid*8);
    f32x4 q0 = Vp[0], q1 = Vp[1];
#pragma unroll
    for(int j=0;j<4;++j){ d0[j] += lr*q0[j]; d1[j] += lr*q1[j]; }
  }
  f32x4 g0 = *(const f32x4*)(agam + tid*8);
  f32x4 g1 = *(const f32x4*)(agam + tid*8 + 4);
  f32x4 xo0, xo1;
  float ssq2 = 0.0f;
#pragma unroll
  for(int j=0;j<4;++j){
    xo0[j] = v0[j] + d0[j]*g0[j];
    xo1[j] = v1[j] + d1[j]*g1[j];
    ssq2 += xo0[j]*xo0[j] + xo1[j]*xo1[j];
  }
  __syncthreads();
  float t2 = wredf(ssq2);
  if(lane==0) red[wid] = t2;
  __syncthreads();
  const float rs2 = rsqrtf((red[0]+red[1]+red[2]+red[3])*(1.0f/D_DIM) + 1e-6f);
  f32x4 b0 = *(const f32x4*)(bnw + tid*8);
  f32x4 b1 = *(const f32x4*)(bnw + tid*8 + 4);
  float a[8]; float am = 0.0f;
#pragma unroll
  for(int j=0;j<4;++j){
    a[j]   = xo0[j]*rs2*b0[j];
    a[4+j] = xo1[j]*rs2*b1[j];
    am = fmaxf(am, fmaxf(fabsf(a[j]), fabsf(a[4+j])));
  }
  *(f32x4*)xr = xo0;
  *(f32x4*)(xr+4) = xo1;

  float wm = wredmax(am);
  __syncthreads();
  if(lane==0) red[wid] = wm;
  __syncthreads();
  const float rowmax = fmaxf(fmaxf(red[0],red[1]), fmaxf(red[2],red[3]));
  const float guard = fmaxf(rowmax, 1e-12f);
  const float inv = 127.0f/guard;
  i32x2 q;
  q[0] = pack4q(a[0],a[1],a[2],a[3], inv, 127);
  q[1] = pack4q(a[4],a[5],a[6],a[7], inv, 127);
  *(i32x2*)(xq + (size_t)row*D_DIM + tid*8) = q;
  if(tid==0) sxn[row] = guard/127.0f;
}

// ---------------------------------------------------------------------------
// h (bf16 [4096 x 8192]) -> per-row i8 + scale
// ---------------------------------------------------------------------------
__global__ __launch_bounds__(256) void hquant(
    const unsigned short* __restrict__ h, signed char* __restrict__ q,
    float* __restrict__ sh)
{
  const int row = blockIdx.x, tid = threadIdx.x;
  const int lane = tid & 63, wid = tid >> 6;
  const unsigned short* hr = h + (size_t)row*H_DIM + tid*32;
  float v[32]; float am = 0.0f;
#pragma unroll
  for(int c=0;c<4;++c){
    u16x8 u = *(const u16x8*)(hr + c*8);
#pragma unroll
    for(int j=0;j<8;++j){
      float f = bf2f(u[j]);
      v[c*8+j] = f;
      am = fmaxf(am, fabsf(f));
    }
  }
  __shared__ float red[4];
  float wm = wredmax(am);
  if(lane==0) red[wid] = wm;
  __syncthreads();
  const float rowmax = fmaxf(fmaxf(red[0],red[1]), fmaxf(red[2],red[3]));
  const float guard = fmaxf(rowmax, 1e-12f);
  const float inv = 127.0f/guard;
  i32x4 o0, o1;
#pragma unroll
  for(int c=0;c<4;++c){
    int p = pack4q(v[c*4],v[c*4+1],v[c*4+2],v[c*4+3], inv, 127);
    o0[c] = p;
  }
#pragma unroll
  for(int c=0;c<4;++c){
    int p = pack4q(v[16+c*4],v[16+c*4+1],v[16+c*4+2],v[16+c*4+3], inv, 127);
    o1[c] = p;
  }
  signed char* qp = q + (size_t)row*H_DIM + tid*32;
  *(i32x4*)qp = o0;
  *(i32x4*)(qp+16) = o1;
  if(tid==0) sh[row] = guard/127.0f;
}

// ---------------------------------------------------------------------------
// Weight absmax (two-stage, exact) -> scale = absmax/127 ; then quant to i8
// ---------------------------------------------------------------------------
__global__ __launch_bounds__(256) void wmax_part(const float* __restrict__ w,
                                                 float* __restrict__ part)
{
  const long long n4 = (long long)H_DIM*D_DIM/4;
  const int tid = threadIdx.x;
  const int lane = tid & 63, wid = tid >> 6;
  float m = 0.0f;
  for(long long i = (long long)blockIdx.x*256 + tid; i < n4;
      i += (long long)gridDim.x*256){
    f32x4 v = ((const f32x4*)w)[i];
    m = fmaxf(m, fmaxf(fmaxf(fabsf(v[0]),fabsf(v[1])),
                       fmaxf(fabsf(v[2]),fabsf(v[3]))));
  }
  float wm = wredmax(m);
  __shared__ float red[4];
  if(lane==0) red[wid] = wm;
  __syncthreads();
  if(tid==0) part[blockIdx.x] = fmaxf(fmaxf(red[0],red[1]),
                                      fmaxf(red[2],red[3]));
}

__global__ __launch_bounds__(256) void wmax_final(const float* __restrict__ part,
                                                  float* __restrict__ scale)
{
  const int tid = threadIdx.x;
  const int lane = tid & 63, wid = tid >> 6;
  float m = 0.0f;
  for(int i=tid;i<1024;i+=256) m = fmaxf(m, part[i]);
  m = wredmax(m);
  __shared__ float red[4];
  if(lane==0) red[wid] = m;
  __syncthreads();
  if(tid==0){
    float mm = fmaxf(fmaxf(red[0],red[1]), fmaxf(red[2],red[3]));
    scale[0] = fmaxf(mm, 1e-12f)/127.0f;
  }
}

__global__ __launch_bounds__(256) void wquant_i8(const float* __restrict__ w,
                                                 const float* __restrict__ scale,
                                                 signed char* __restrict__ q)
{
  const long long n8 = (long long)H_DIM*D_DIM/8;
  const float inv = 1.0f/scale[0];
  for(long long i = (long long)blockIdx.x*256 + threadIdx.x; i < n8;
      i += (long long)gridDim.x*256){
    f32x4 a = ((const f32x4*)w)[2*i];
    f32x4 b = ((const f32x4*)w)[2*i+1];
    i32x2 o;
    o[0] = pack4q(a[0],a[1],a[2],a[3], inv, 127);
    o[1] = pack4q(b[0],b[1],b[2],b[3], inv, 127);
    ((i32x2*)q)[i] = o;
  }
}

// ---------------------------------------------------------------------------
// Ternary absmean (two-stage, deterministic) + ternary quant to i8 {-1,0,1}
// ---------------------------------------------------------------------------
__global__ __launch_bounds__(256) void abs_part(const float* __restrict__ w,
                                                double* __restrict__ part)
{
  const long long n4 = (long long)H_DIM*D_DIM/4;
  const int tid = threadIdx.x;
  const int lane = tid & 63, wid = tid >> 6;
  float s = 0.0f;
  for(long long i = (long long)blockIdx.x*256 + tid; i < n4;
      i += (long long)gridDim.x*256){
    f32x4 v = ((const f32x4*)w)[i];
    s += fabsf(v[0]) + fabsf(v[1]) + fabsf(v[2]) + fabsf(v[3]);
  }
  double ds = wredd((double)s);
  __shared__ double sred[4];
  if(lane==0) sred[wid] = ds;
  __syncthreads();
  if(tid==0) part[blockIdx.x] = sred[0]+sred[1]+sred[2]+sred[3];
}

__global__ __launch_bounds__(256) void abs_final(const double* __restrict__ part,
                                                 float* __restrict__ scale)
{
  const int tid = threadIdx.x;
  const int lane = tid & 63, wid = tid >> 6;
  double s = 0.0;
  for(int i=tid;i<1024;i+=256) s += part[i];
  s = wredd(s);
  __shared__ double sred[4];
  if(lane==0) sred[wid] = s;
  __syncthreads();
  if(tid==0){
    double m = (sred[0]+sred[1]+sred[2]+sred[3]) / ((double)H_DIM*(double)D_DIM);
    scale[0] = (float)fmax(m, 1e-8);
  }
}

__global__ __launch_bounds__(256) void tquant_i8(const float* __restrict__ w,
                                                 const float* __restrict__ scale,
                                                 signed char* __restrict__ q)
{
  const long long n8 = (long long)H_DIM*D_DIM/8;
  const float inv = 1.0f/scale[0];
  for(long long i = (long long)blockIdx.x*256 + threadIdx.x; i < n8;
      i += (long long)gridDim.x*256){
    f32x4 a = ((const f32x4*)w)[2*i];
    f32x4 b = ((const f32x4*)w)[2*i+1];
    i32x2 o;
    o[0] = pack4q(a[0],a[1],a[2],a[3], inv, 1);
    o[1] = pack4q(b[0],b[1],b[2],b[3], inv, 1);
    ((i32x2*)q)[i] = o;
  }
}

// ---------------------------------------------------------------------------
// i8 GEMM: C[M,Nout] = A[M,K](i8) @ B[Nout,K](i8)^T, 128x128 tile, BK=64,
// 4 waves (2x2), mfma_i32_16x16x64_i8.  Dequant: f = acc * sA[row] * sW.
// Byte-level staging/swizzle identical to the proven bf16 kernel.
//  EPI 0 (DUAL): h = silu(f0)*f1 -> bf16 obf     (SwiGLU)
//  EPI 1: silu(f) -> bf16 obf                    (BitLinear up)
//  EPI 2: xacc += act[row] ? f*gamma[col] : 0    (ACB residual)
//  EPI 3: xacc += f*gamma[col]                   (BitLinear residual)
// ---------------------------------------------------------------------------
template<int EPI, bool DUAL>
__global__ __launch_bounds__(256, DUAL?2:3) void gemm128q(
    const signed char* __restrict__ A,
    const signed char* __restrict__ B0,
    const signed char* __restrict__ B1,
    const int Nout, const int K,
    const float* __restrict__ sArow,
    const float* __restrict__ sW0p,
    const float* __restrict__ sW1p,
    unsigned short* __restrict__ obf,
    float* __restrict__ xacc,
    const float* __restrict__ gamma,
    const float* __restrict__ act)
{
  __shared__ __align__(16) signed char smA[128*64];
  __shared__ __align__(16) signed char smB[128*64];
  __shared__ __align__(16) signed char smB2[DUAL?(128*64):16];

  const int tid  = threadIdx.x;
  const int lane = tid & 63;
  const int wid  = tid >> 6;
  const int wr   = wid >> 1;
  const int wc   = wid & 1;
  const int frow = lane & 15;
  const int k16  = lane >> 4;

  const int nwg = (int)gridDim.x;
  const int bid = (int)blockIdx.x;
  const int swz = ((bid & 7) * (nwg >> 3)) + (bid >> 3);
  const int rowBase = (swz & 31) << 7;       // M/128 == 32, rows fast in chunk
  const int colBase = (swz >> 5) << 7;

  int srow[2], schk[2];
#pragma unroll
  for(int r=0;r<2;++r){
    int t = tid + (r<<8);
    srow[r] = t >> 2;
    schk[r] = (t & 3) ^ ((srow[r] >> 1) & 3);   // XOR swizzle, 16B chunks
  }

  const i32x4 izero = {0,0,0,0};
  i32x4 acc[4][4];
  i32x4 acc2[4][4];
#pragma unroll
  for(int m=0;m<4;++m)
#pragma unroll
    for(int n=0;n<4;++n){ acc[m][n] = izero; acc2[m][n] = izero; }

  for(int k0=0;k0<K;k0+=64){
#pragma unroll
    for(int r=0;r<2;++r){
      const signed char* s = A + (size_t)(rowBase+srow[r])*K + k0 + schk[r]*16;
      gload_lds16(s, &smA[((r<<8)+(wid<<6))*16]);
    }
#pragma unroll
    for(int r=0;r<2;++r){
      const signed char* s = B0 + (size_t)(colBase+srow[r])*K + k0 + schk[r]*16;
      gload_lds16(s, &smB[((r<<8)+(wid<<6))*16]);
    }
    if constexpr (DUAL){
#pragma unroll
      for(int r=0;r<2;++r){
        const signed char* s = B1 + (size_t)(colBase+srow[r])*K + k0 + schk[r]*16;
        gload_lds16(s, &smB2[((r<<8)+(wid<<6))*16]);
      }
    }
    __syncthreads();

    i32x4 af[4];
#pragma unroll
    for(int m=0;m<4;++m){
      int rr = (wr<<6)+(m<<4)+frow;
      int ch = k16 ^ ((rr>>1)&3);
      af[m] = *(const i32x4*)&smA[rr*64 + ch*16];
    }
    i32x4 bfr[4];
    i32x4 bfr2[4];
#pragma unroll
    for(int n=0;n<4;++n){
      int rr = (wc<<6)+(n<<4)+frow;
      int ch = k16 ^ ((rr>>1)&3);
      bfr[n] = *(const i32x4*)&smB[rr*64 + ch*16];
      if constexpr (DUAL) bfr2[n] = *(const i32x4*)&smB2[rr*64 + ch*16];
    }
#pragma unroll
    for(int m=0;m<4;++m)
#pragma unroll
      for(int n=0;n<4;++n){
        acc[m][n] = __builtin_amdgcn_mfma_i32_16x16x64_i8(af[m], bfr[n], acc[m][n], 0,0,0);
        if constexpr (DUAL)
          acc2[m][n] = __builtin_amdgcn_mfma_i32_16x16x64_i8(af[m], bfr2[n], acc2[m][n], 0,0,0);
      }
    __syncthreads();
  }

  // ---- epilogue.  C/D layout: col = lane&15, row = (lane>>4)*4 + j
  const float fsW0 = sW0p[0];
  const float fsW1 = DUAL ? sW1p[0] : 0.0f;
  const int growB = rowBase + (wr<<6) + (k16<<2);
  const int gcolB = colBase + (wc<<6) + frow;
#pragma unroll
  for(int m=0;m<4;++m){
#pragma unroll
    for(int n=0;n<4;++n){
      const int grow0 = growB + (m<<4);
      const int gcol  = gcolB + (n<<4);
      i32x4 v = acc[m][n];
      if constexpr (EPI==0){
        i32x4 v2 = acc2[m][n];
#pragma unroll
        for(int j=0;j<4;++j){
          const float sa = sArow[grow0+j];
          float f1 = (float)v[j]  * sa * fsW0;
          float f3 = (float)v2[j] * sa * fsW1;
          float hv = (f1/(1.0f+expf(-f1))) * f3;
          obf[(size_t)(grow0+j)*Nout + gcol] = f2bf(hv);
        }
      } else if constexpr (EPI==1){
#pragma unroll
        for(int j=0;j<4;++j){
          const float sa = sArow[grow0+j];
          float f = (float)v[j] * sa * fsW0;
          obf[(size_t)(grow0+j)*Nout + gcol] = f2bf(f/(1.0f+expf(-f)));
        }
      } else if constexpr (EPI==2){
        const float g = gamma[gcol];
#pragma unroll
        for(int j=0;j<4;++j){
          if(act[grow0+j] != 0.0f){
            const float sa = sArow[grow0+j];
            const size_t ix = (size_t)(grow0+j)*Nout + gcol;
            xacc[ix] += (float)v[j] * sa * fsW0 * g;
          }
        }
      } else {
        const float g = gamma[gcol];
#pragma unroll
        for(int j=0;j<4;++j){
          const float sa = sArow[grow0+j];
          const size_t ix = (size_t)(grow0+j)*Nout + gcol;
          xacc[ix] += (float)v[j] * sa * fsW0 * g;
        }
      }
    }
  }
}

// ===========================================================================
// Fallback path kernels (round-1 proven): bf16 GEMM, bf16 rowpasses, bf16 tquant
// ===========================================================================
__global__ __launch_bounds__(256) void rowpass1(
    const float* __restrict__ x, const float* __restrict__ nw,
    const float* __restrict__ rw, unsigned short* __restrict__ xn,
    float* __restrict__ act)
{
  const int row = blockIdx.x, tid = threadIdx.x;
  const int lane = tid & 63, wid = tid >> 6;
  const float* xr = x + (size_t)row*D_DIM + tid*8;
  f32x4 v0 = *(const f32x4*)xr;
  f32x4 v1 = *(const f32x4*)(xr+4);
  float ssq = 0.0f;
#pragma unroll
  for(int j=0;j<4;++j) ssq += v0[j]*v0[j] + v1[j]*v1[j];
  __shared__ float red[4];
  float t = wredf(ssq);
  if(lane==0) red[wid] = t;
  __syncthreads();
  const float rs = rsqrtf((red[0]+red[1]+red[2]+red[3])*(1.0f/D_DIM) + 1e-6f);
  f32x4 n0 = *(const f32x4*)(nw + tid*8);
  f32x4 n1 = *(const f32x4*)(nw + tid*8 + 4);
  f32x4 r0 = *(const f32x4*)(rw + tid*8);
  f32x4 r1 = *(const f32x4*)(rw + tid*8 + 4);
  float gp = 0.0f;
  u16x4 o0, o1;
#pragma unroll
  for(int j=0;j<4;++j){
    float a = v0[j]*rs*n0[j];
    float b = v1[j]*rs*n1[j];
    gp += a*r0[j] + b*r1[j];
    o0[j] = f2bf(a);
    o1[j] = f2bf(b);
  }
  unsigned short* xp = xn + (size_t)row*D_DIM + tid*8;
  *(u16x4*)xp = o0;
  *(u16x4*)(xp+4) = o1;
  float gd = wredf(gp);
  __syncthreads();
  if(lane==0) red[wid] = gd;
  __syncthreads();
  if(tid==0){
    float dot = red[0]+red[1]+red[2]+red[3];
    float g = 1.0f/(1.0f+expf(-dot));
    act[row] = (g > 0.35f) ? 1.0f : 0.0f;
  }
}

__global__ __launch_bounds__(256) void rowpass2(
    float* __restrict__ x, const float* __restrict__ anw,
    const float* __restrict__ U, const float* __restrict__ Sv,
    const float* __restrict__ V, const float* __restrict__ agam,
    const float* __restrict__ bnw, unsigned short* __restrict__ xn3)
{
  const int row = blockIdx.x, tid = threadIdx.x;
  const int lane = tid & 63, wid = tid >> 6;
  float* xr = x + (size_t)row*D_DIM + tid*8;
  f32x4 v0 = *(const f32x4*)xr;
  f32x4 v1 = *(const f32x4*)(xr+4);
  float ssq = 0.0f;
#pragma unroll
  for(int j=0;j<4;++j) ssq += v0[j]*v0[j] + v1[j]*v1[j];
  __shared__ float red[4];
  float t = wredf(ssq);
  if(lane==0) red[wid] = t;
  __syncthreads();
  const float rs = rsqrtf((red[0]+red[1]+red[2]+red[3])*(1.0f/D_DIM) + 1e-6f);
  f32x4 a0 = *(const f32x4*)(anw + tid*8);
  f32x4 a1 = *(const f32x4*)(anw + tid*8 + 4);
  float xn2[8];
#pragma unroll
  for(int j=0;j<4;++j){ xn2[j] = v0[j]*rs*a0[j]; xn2[4+j] = v1[j]*rs*a1[j]; }
  float pl[16];
#pragma unroll
  for(int r2=0;r2<16;++r2) pl[r2] = 0.0f;
#pragma unroll
  for(int j=0;j<8;++j){
    const int k = tid*8 + j;
    const f32x4* Up = (const f32x4*)(U + (size_t)k*R_DIM);
    f32x4 u0=Up[0], u1=Up[1], u2=Up[2], u3=Up[3];
    const float xv = xn2[j];
#pragma unroll
    for(int q=0;q<4;++q){
      pl[q] += xv*u0[q]; pl[4+q] += xv*u1[q];
      pl[8+q] += xv*u2[q]; pl[12+q] += xv*u3[q];
    }
  }
#pragma unroll
  for(int r2=0;r2<16;++r2) pl[r2] = wredf(pl[r2]);
  __shared__ float lred[4][16];
  if(lane==0){
#pragma unroll
    for(int r2=0;r2<16;++r2) lred[wid][r2] = pl[r2];
  }
  __syncthreads();
  __shared__ float lowS[16];
  if(tid==0){
    float sa[16]; float totS = 0.0f;
#pragma unroll
    for(int r2=0;r2<16;++r2){ sa[r2] = fabsf(Sv[r2]); totS += sa[r2]; }
    totS = fmaxf(totS, 1e-8f);
    float c = 0.0f;
#pragma unroll
    for(int r2=0;r2<16;++r2){
      float lraw = lred[0][r2]+lred[1][r2]+lred[2][r2]+lred[3][r2];
      float keep = (r2==0) ? 1.0f : ((c/totS < 0.95f) ? 1.0f : 0.0f);
      c += sa[r2];
      lowS[r2] = lraw * Sv[r2] * keep;
    }
  }
  __syncthreads();
  f32x4 d0 = {0,0,0,0}, d1 = {0,0,0,0};
#pragma unroll
  for(int r2=0;r2<16;++r2){
    const float lr = lowS[r2];
    const f32x4* Vp = (const f32x4*)(V + (size_t)r2*D_DIM + tid*8);
    f32x4 q0 = Vp[0], q1 = Vp[1];
#pragma unroll
    for(int j=0;j<4;++j){ d0[j] += lr*q0[j]; d1[j] += lr*q1[j]; }
  }
  f32x4 g0 = *(const f32x4*)(agam + tid*8);
  f32x4 g1 = *(const f32x4*)(agam + tid*8 + 4);
  f32x4 xo0, xo1;
  float ssq2 = 0.0f;
#pragma unroll
  for(int j=0;j<4;++j){
    xo0[j] = v0[j] + d0[j]*g0[j];
    xo1[j] = v1[j] + d1[j]*g1[j];
    ssq2 += xo0[j]*xo0[j] + xo1[j]*xo1[j];
  }
  __syncthreads();
  float t2 = wredf(ssq2);
  if(lane==0) red[wid] = t2;
  __syncthreads();
  const float rs2 = rsqrtf((red[0]+red[1]+red[2]+red[3])*(1.0f/D_DIM) + 1e-6f);
  f32x4 b0 = *(const f32x4*)(bnw + tid*8);
  f32x4 b1 = *(const f32x4*)(bnw + tid*8 + 4);
  u16x4 o0, o1;
#pragma unroll
  for(int j=0;j<4;++j){
    o0[j] = f2bf(xo0[j]*rs2*b0[j]);
    o1[j] = f2bf(xo1[j]*rs2*b1[j]);
  }
  *(f32x4*)xr = xo0;
  *(f32x4*)(xr+4) = xo1;
  unsigned short* xp = xn3 + (size_t)row*D_DIM + tid*8;
  *(u16x4*)xp = o0;
  *(u16x4*)(xp+4) = o1;
}

__global__ __launch_bounds__(256) void tquant(const float* __restrict__ w,
                                              const float* __restrict__ scale,
                                              unsigned short* __restrict__ q)
{
  const long long n4 = (long long)H_DIM*D_DIM/4;
  const float s = scale[0];
  for(long long i = (long long)blockIdx.x*256 + threadIdx.x; i < n4;
      i += (long long)gridDim.x*256){
    f32x4 v = ((const f32x4*)w)[i];
    u16x4 o;
#pragma unroll
    for(int j=0;j<4;++j){
      float r = rintf(v[j]/s);
      r = fminf(1.0f, fmaxf(-1.0f, r));
      o[j] = f2bf(r*s);
    }
    ((u16x4*)q)[i] = o;
  }
}

template<int EPI, bool BBF16, bool DUAL>
__global__ __launch_bounds__(256, DUAL?2:3) void gemm128(
    const unsigned short* __restrict__ A,
    const void* __restrict__ B0v,
    const void* __restrict__ B1v,
    const int Nout, const int K,
    unsigned short* __restrict__ obf,
    float* __restrict__ xacc,
    const float* __restrict__ gamma,
    const float* __restrict__ act)
{
  __shared__ __align__(16) unsigned short smA[128*32];
  __shared__ __align__(16) unsigned short smB[128*32];
  __shared__ __align__(16) unsigned short smB2[DUAL?(128*32):8];

  const int tid  = threadIdx.x;
  const int lane = tid & 63;
  const int wid  = tid >> 6;
  const int wr   = wid >> 1;
  const int wc   = wid & 1;
  const int frow = lane & 15;
  const int k16  = lane >> 4;

  const int nwg = (int)gridDim.x;
  const int bid = (int)blockIdx.x;
  const int swz = ((bid & 7) * (nwg >> 3)) + (bid >> 3);
  const int rowBase = (swz & 31) << 7;
  const int colBase = (swz >> 5) << 7;

  int srow[2], schk[2];
#pragma unroll
  for(int r=0;r<2;++r){
    int t = tid + (r<<8);
    srow[r] = t >> 2;
    schk[r] = (t & 3) ^ ((srow[r] >> 1) & 3);
  }

  const f32x4 vzero = {0.0f,0.0f,0.0f,0.0f};
  f32x4 acc[4][4];
  f32x4 acc2[4][4];
#pragma unroll
  for(int m=0;m<4;++m)
#pragma unroll
    for(int n=0;n<4;++n){ acc[m][n] = vzero; acc2[m][n] = vzero; }

  for(int k0=0;k0<K;k0+=32){
#pragma unroll
    for(int r=0;r<2;++r){
      const unsigned short* s = A + (size_t)(rowBase+srow[r])*K + k0 + schk[r]*8;
      gload_lds16(s, &smA[((r<<8)+(wid<<6))*8]);
    }
    if constexpr (BBF16){
      const unsigned short* B0 = (const unsigned short*)B0v;
#pragma unroll
      for(int r=0;r<2;++r){
        const unsigned short* s = B0 + (size_t)(colBase+srow[r])*K + k0 + schk[r]*8;
        gload_lds16(s, &smB[((r<<8)+(wid<<6))*8]);
      }
    } else {
      const float* B0 = (const float*)B0v;
#pragma unroll
      for(int r=0;r<2;++r){
        const float* s = B0 + (size_t)(colBase+srow[r])*K + k0 + schk[r]*8;
        f32x4 f0 = *(const f32x4*)s;
        f32x4 f1 = *(const f32x4*)(s+4);
        u16x8 o;
#pragma unroll
        for(int j=0;j<4;++j){ o[j] = f2bf(f0[j]); o[4+j] = f2bf(f1[j]); }
        *(u16x8*)&smB[(size_t)(tid+(r<<8))*8] = o;
      }
      if constexpr (DUAL){
        const float* B1 = (const float*)B1v;
#pragma unroll
        for(int r=0;r<2;++r){
          const float* s = B1 + (size_t)(colBase+srow[r])*K + k0 + schk[r]*8;
          f32x4 f0 = *(const f32x4*)s;
          f32x4 f1 = *(const f32x4*)(s+4);
          u16x8 o;
#pragma unroll
          for(int j=0;j<4;++j){ o[j] = f2bf(f0[j]); o[4+j] = f2bf(f1[j]); }
          *(u16x8*)&smB2[(size_t)(tid+(r<<8))*8] = o;
        }
      }
    }
    __syncthreads();

    bf16x8 af[4];
#pragma unroll
    for(int m=0;m<4;++m){
      int rr = (wr<<6)+(m<<4)+frow;
      int ch = k16 ^ ((rr>>1)&3);
      af[m] = *(const bf16x8*)&smA[rr*32 + ch*8];
    }
    bf16x8 bfr[4];
    bf16x8 bfr2[4];
#pragma unroll
    for(int n=0;n<4;++n){
      int rr = (wc<<6)+(n<<4)+frow;
      int ch = k16 ^ ((rr>>1)&3);
      bfr[n] = *(const bf16x8*)&smB[rr*32 + ch*8];
      if constexpr (DUAL) bfr2[n] = *(const bf16x8*)&smB2[rr*32 + ch*8];
    }
#pragma unroll
    for(int m=0;m<4;++m)
#pragma unroll
      for(int n=0;n<4;++n){
        acc[m][n] = __builtin_amdgcn_mfma_f32_16x16x32_bf16(af[m], bfr[n], acc[m][n], 0,0,0);
        if constexpr (DUAL)
          acc2[m][n] = __builtin_amdgcn_mfma_f32_16x16x32_bf16(af[m], bfr2[n], acc2[m][n], 0,0,0);
      }
    __syncthreads();
  }

  const int growB = rowBase + (wr<<6) + (k16<<2);
  const int gcolB = colBase + (wc<<6) + frow;
#pragma unroll
  for(int m=0;m<4;++m){
#pragma unroll
    for(int n=0;n<4;++n){
      const int grow0 = growB + (m<<4);
      const int gcol  = gcolB + (n<<4);
      f32x4 v = acc[m][n];
      if constexpr (EPI==0){
        f32x4 v2 = acc2[m][n];
#pragma unroll
        for(int j=0;j<4;++j){
          float t1 = v[j];
          float hv = (t1/(1.0f+expf(-t1))) * v2[j];
          obf[(size_t)(grow0+j)*Nout + gcol] = f2bf(hv);
        }
      } else if constexpr (EPI==1){
#pragma unroll
        for(int j=0;j<4;++j){
          float t1 = v[j];
          obf[(size_t)(grow0+j)*Nout + gcol] = f2bf(t1/(1.0f+expf(-t1)));
        }
      } else if constexpr (EPI==2){
        const float g = gamma[gcol];
#pragma unroll
        for(int j=0;j<4;++j){
          if(act[grow0+j] != 0.0f){
            const size_t ix = (size_t)(grow0+j)*Nout + gcol;
            xacc[ix] += v[j]*g;
          }
        }
      } else {
        const float g = gamma[gcol];
#pragma unroll
        for(int j=0;j<4;++j){
          const size_t ix = (size_t)(grow0+j)*Nout + gcol;
          xacc[ix] += v[j]*g;
        }
      }
    }
  }
}

// ---------------------------------------------------------------------------
extern "C" void kernel_launch(void* const* d_in, const int* in_sizes, int n_in,
                              void* d_out, int out_size, void* d_ws, size_t ws_size,
                              hipStream_t stream)
{
  (void)in_sizes; (void)n_in; (void)out_size;
  const float* x_in  = (const float*)d_in[0];
  const float* acbnw = (const float*)d_in[1];
  const float* routw = (const float*)d_in[2];
  const float* w1    = (const float*)d_in[3];
  const float* w2    = (const float*)d_in[4];
  const float* w3    = (const float*)d_in[5];
  const float* acbg  = (const float*)d_in[6];
  const float* arlnw = (const float*)d_in[7];
  const float* U     = (const float*)d_in[8];
  const float* Sv    = (const float*)d_in[9];
  const float* V     = (const float*)d_in[10];
  const float* arlg  = (const float*)d_in[11];
  const float* bitnw = (const float*)d_in[12];
  const float* wup   = (const float*)d_in[13];
  const float* wdn   = (const float*)d_in[14];
  const float* bitg  = (const float*)d_in[15];

  float* xs = (float*)d_out;           // x state lives in d_out (fp32 [N,D])
  char* ws = (char*)d_ws;

  const bool big = (ws_size >= (size_t)185000000);

  hipMemcpyAsync(xs, x_in, (size_t)NTOK*D_DIM*sizeof(float),
                 hipMemcpyDeviceToDevice, stream);

  if (big) {
    const size_t MB = 1048576;
    unsigned short* hb   = (unsigned short*)(ws);             // 64 MiB bf16 h
    signed char*    xnq  = (signed char*)(ws + 64*MB);        //  8 MiB i8 xn
    signed char*    hbq  = (signed char*)(ws + 72*MB);        // 32 MiB i8 h
    signed char*    slotA= (signed char*)(ws + 104*MB);       // 16 MiB i8 wts
    signed char*    slotB= (signed char*)(ws + 120*MB);       // 16 MiB i8 wts
    char* tail = ws + 136*MB;
    float*  sxn   = (float*)(tail);                 // 16 KiB
    float*  sh    = (float*)(tail + 16384);         // 16 KiB
    float*  act   = (float*)(tail + 32768);         // 16 KiB
    float*  fpart = (float*)(tail + 49152);         //  4 KiB
    double* dpart = (double*)(tail + 57344);        //  8 KiB
    float*  scb   = (float*)(tail + 65536);         // scales: w1,w3,w2,wup,wdn

    const int gH = 2048;   // (4096/128)*(8192/128)
    const int gD = 512;    // (4096/128)*(2048/128)

    for(int d=0; d<DEPTH; ++d){
      const size_t oD  = (size_t)d*D_DIM;
      const size_t oHD = (size_t)d*H_DIM*D_DIM;
      const size_t oR  = (size_t)d*R_DIM;
      const size_t oDR = (size_t)d*D_DIM*R_DIM;

      // ---- AdaptiveComputeBlock (i8)
      wmax_part<<<1024,256,0,stream>>>(w1+oHD, fpart);
      wmax_final<<<1,256,0,stream>>>(fpart, scb+0);
      wquant_i8<<<2048,256,0,stream>>>(w1+oHD, scb+0, slotA);
      wmax_part<<<1024,256,0,stream>>>(w3+oHD, fpart);
      wmax_final<<<1,256,0,stream>>>(fpart, scb+1);
      wquant_i8<<<2048,256,0,stream>>>(w3+oHD, scb+1, slotB);
      rowpass1_i8<<<NTOK,256,0,stream>>>(xs, acbnw+oD, routw+oD, xnq, sxn, act);
      gemm128q<0,true><<<gH,256,0,stream>>>(
          xnq, slotA, slotB, H_DIM, D_DIM, sxn, scb+0, scb+1,
          hb, nullptr, nullptr, nullptr);
      wmax_part<<<1024,256,0,stream>>>(w2+oHD, fpart);
      wmax_final<<<1,256,0,stream>>>(fpart, scb+2);
      wquant_i8<<<2048,256,0,stream>>>(w2+oHD, scb+2, slotA);
      hquant<<<NTOK,256,0,stream>>>(hb, hbq, sh);
      gemm128q<2,false><<<gD,256,0,stream>>>(
          hbq, slotA, nullptr, D_DIM, H_DIM, sh, scb+2, nullptr,
          nullptr, xs, acbg+oD, act);

      // ---- AdaptiveRankLinear (fp32) + BitLinear input norm -> i8
      rowpass2_i8<<<NTOK,256,0,stream>>>(xs, arlnw+oD, U+oDR, Sv+oR, V+oDR,
                                         arlg+oD, bitnw+oD, xnq, sxn);

      // ---- BitLinear (i8, exact ternary weights)
      abs_part<<<1024,256,0,stream>>>(wup+oHD, dpart);
      abs_final<<<1,256,0,stream>>>(dpart, scb+3);
      tquant_i8<<<2048,256,0,stream>>>(wup+oHD, scb+3, slotB);
      gemm128q<1,false><<<gH,256,0,stream>>>(
          xnq, slotB, nullptr, H_DIM, D_DIM, sxn, scb+3, nullptr,
          hb, nullptr, nullptr, nullptr);
      hquant<<<NTOK,256,0,stream>>>(hb, hbq, sh);
      abs_part<<<1024,256,0,stream>>>(wdn+oHD, dpart);
      abs_final<<<1,256,0,stream>>>(dpart, scb+4);
      tquant_i8<<<2048,256,0,stream>>>(wdn+oHD, scb+4, slotA);
      gemm128q<3,false><<<gD,256,0,stream>>>(
          hbq, slotA, nullptr, D_DIM, H_DIM, sh, scb+4, nullptr,
          nullptr, xs, bitg+oD, nullptr);
    }
  } else {
    // fallback: round-1 layout (bf16 GEMMs, fp32 B reg-staged)
    unsigned short* xn = (unsigned short*)(ws);                 // 16 MiB
    unsigned short* hb = (unsigned short*)(ws + 16777216);      // 64 MiB
    unsigned short* qb = (unsigned short*)(ws + 83886080);      // 32 MiB
    float*  act   = (float*)(ws + 117440512);
    double* parts = (double*)(ws + 117456896);
    float*  scal  = (float*)(ws + 117465088);

    const int gH = 2048;
    const int gD = 512;

    for(int d=0; d<DEPTH; ++d){
      const size_t oD  = (size_t)d*D_DIM;
      const size_t oHD = (size_t)d*H_DIM*D_DIM;
      const size_t oR  = (size_t)d*R_DIM;
      const size_t oDR = (size_t)d*D_DIM*R_DIM;

      rowpass1<<<NTOK,256,0,stream>>>(xs, acbnw+oD, routw+oD, xn, act);
      gemm128<0,false,true><<<gH,256,0,stream>>>(
          xn, w1+oHD, w3+oHD, H_DIM, D_DIM, hb, nullptr, nullptr, nullptr);
      gemm128<2,false,false><<<gD,256,0,stream>>>(
          hb, w2+oHD, nullptr, D_DIM, H_DIM, nullptr, xs, acbg+oD, act);

      rowpass2<<<NTOK,256,0,stream>>>(xs, arlnw+oD, U+oDR, Sv+oR, V+oDR,
                                      arlg+oD, bitnw+oD, xn);

      abs_part<<<1024,256,0,stream>>>(wup+oHD, parts);
      abs_final<<<1,256,0,stream>>>(parts, scal);
      tquant<<<2048,256,0,stream>>>(wup+oHD, scal, qb);
      gemm128<1,true,false><<<gH,256,0,stream>>>(
          xn, qb, nullptr, H_DIM, D_DIM, hb, nullptr, nullptr, nullptr);

      abs_part<<<1024,256,0,stream>>>(wdn+oHD, parts);
      abs_final<<<1,256,0,stream>>>(parts, scal);
      tquant<<<2048,256,0,stream>>>(wdn+oHD, scal, qb);
      gemm128<3,true,false><<<gD,256,0,stream>>>(
          hb, qb, nullptr, D_DIM, H_DIM, nullptr, xs, bitg+oD, nullptr);
    }
  }
}

// Round 6
// 1419.775 us; speedup vs baseline: 2.0461x; 1.1795x over previous
//
#include <hip/hip_runtime.h>

#define D_DIM 2048
#define H_DIM 8192
#define NTOK  4096
#define R_DIM 16
#define DEPTH 2

typedef float f32x4 __attribute__((ext_vector_type(4)));
typedef __bf16 bf16x8 __attribute__((ext_vector_type(8)));
typedef unsigned short u16x4 __attribute__((ext_vector_type(4)));
typedef unsigned short u16x8 __attribute__((ext_vector_type(8)));
typedef int i32x4 __attribute__((ext_vector_type(4)));
typedef int i32x2 __attribute__((ext_vector_type(2)));

typedef __attribute__((address_space(1))) void void_g;
typedef __attribute__((address_space(3))) void void_l;

__device__ __forceinline__ unsigned short f2bf(float f){
  __bf16 b = (__bf16)f;
  return __builtin_bit_cast(unsigned short, b);
}
__device__ __forceinline__ float bf2f(unsigned short u){
  unsigned int x = ((unsigned int)u) << 16;
  return __builtin_bit_cast(float, x);
}

__device__ __forceinline__ float wredf(float v){
#pragma unroll
  for(int o=32;o;o>>=1) v += __shfl_xor(v,o,64);
  return v;
}
__device__ __forceinline__ float wredmax(float v){
#pragma unroll
  for(int o=32;o;o>>=1) v = fmaxf(v, __shfl_xor(v,o,64));
  return v;
}
__device__ __forceinline__ double wredd(double v){
#pragma unroll
  for(int o=32;o;o>>=1) v += __shfl_xor(v,o,64);
  return v;
}

__device__ __forceinline__ void gload_lds16(const void* g, void* l){
  __builtin_amdgcn_global_load_lds((void_g*)g, (void_l*)l, 16, 0, 0);
}

__device__ __forceinline__ int clampi(int v, int lim){
  return v > lim ? lim : (v < -lim ? -lim : v);
}
__device__ __forceinline__ int pack4q(float a, float b, float c, float d,
                                      float inv, int lim){
  int qa = clampi((int)rintf(a*inv), lim);
  int qb = clampi((int)rintf(b*inv), lim);
  int qc = clampi((int)rintf(c*inv), lim);
  int qd = clampi((int)rintf(d*inv), lim);
  return (qa&255) | ((qb&255)<<8) | ((qc&255)<<16) | ((qd&255)<<24);
}

// ---------------------------------------------------------------------------
// Row pass 1 (i8): xn=rms_norm -> per-row i8 quant; gate -> act mask (fp32)
// ---------------------------------------------------------------------------
__global__ __launch_bounds__(256) void rowpass1_i8(
    const float* __restrict__ x, const float* __restrict__ nw,
    const float* __restrict__ rw, signed char* __restrict__ xq,
    float* __restrict__ sxn, float* __restrict__ act)
{
  const int row = blockIdx.x, tid = threadIdx.x;
  const int lane = tid & 63, wid = tid >> 6;
  const float* xr = x + (size_t)row*D_DIM + tid*8;
  f32x4 v0 = *(const f32x4*)xr;
  f32x4 v1 = *(const f32x4*)(xr+4);
  float ssq = 0.0f;
#pragma unroll
  for(int j=0;j<4;++j) ssq += v0[j]*v0[j] + v1[j]*v1[j];
  __shared__ float red[4];
  float t = wredf(ssq);
  if(lane==0) red[wid] = t;
  __syncthreads();
  const float rs = rsqrtf((red[0]+red[1]+red[2]+red[3])*(1.0f/D_DIM) + 1e-6f);

  f32x4 n0 = *(const f32x4*)(nw + tid*8);
  f32x4 n1 = *(const f32x4*)(nw + tid*8 + 4);
  f32x4 r0 = *(const f32x4*)(rw + tid*8);
  f32x4 r1 = *(const f32x4*)(rw + tid*8 + 4);
  float a[8];
  float gp = 0.0f, am = 0.0f;
#pragma unroll
  for(int j=0;j<4;++j){
    a[j]   = v0[j]*rs*n0[j];
    a[4+j] = v1[j]*rs*n1[j];
    gp += a[j]*r0[j] + a[4+j]*r1[j];
    am = fmaxf(am, fmaxf(fabsf(a[j]), fabsf(a[4+j])));
  }
  float wm = wredmax(am);
  __syncthreads();
  if(lane==0) red[wid] = wm;
  __syncthreads();
  const float rowmax = fmaxf(fmaxf(red[0],red[1]), fmaxf(red[2],red[3]));
  const float guard = fmaxf(rowmax, 1e-12f);
  const float inv = 127.0f/guard;
  i32x2 q;
  q[0] = pack4q(a[0],a[1],a[2],a[3], inv, 127);
  q[1] = pack4q(a[4],a[5],a[6],a[7], inv, 127);
  *(i32x2*)(xq + (size_t)row*D_DIM + tid*8) = q;

  float gd = wredf(gp);
  __syncthreads();
  if(lane==0) red[wid] = gd;
  __syncthreads();
  if(tid==0){
    sxn[row] = guard/127.0f;
    float dot = red[0]+red[1]+red[2]+red[3];
    float g = 1.0f/(1.0f+expf(-dot));
    act[row] = (g > 0.35f) ? 1.0f : 0.0f;
  }
}

// ---------------------------------------------------------------------------
// buildmap: deterministic order-preserving compaction of active rows.
// 1 block x 256 threads; thread t owns rows [16t, 16t+16).
// ---------------------------------------------------------------------------
__global__ __launch_bounds__(256) void buildmap(const float* __restrict__ act,
                                                int* __restrict__ rowmap,
                                                int* __restrict__ cntp)
{
  const int tid = threadIdx.x;
  const int lane = tid & 63, wid = tid >> 6;
  int flags[16]; int c = 0;
#pragma unroll
  for(int j=0;j<16;++j){
    flags[j] = (act[tid*16+j] != 0.0f) ? 1 : 0;
    c += flags[j];
  }
  int inc = c;
#pragma unroll
  for(int o=1;o<64;o<<=1){
    int t = __shfl_up(inc, o, 64);
    if(lane >= o) inc += t;
  }
  __shared__ int wsum[4];
  if(lane==63) wsum[wid] = inc;
  __syncthreads();
  int base = inc - c;
  for(int w=0;w<wid;++w) base += wsum[w];
  const int total = wsum[0]+wsum[1]+wsum[2]+wsum[3];
#pragma unroll
  for(int j=0;j<16;++j){
    if(flags[j]) rowmap[base++] = tid*16+j;
  }
  if(tid==0) cntp[0] = total;
  __syncthreads();
  for(int i = total + tid; i < NTOK; i += 256) rowmap[i] = 0;
}

// ---------------------------------------------------------------------------
// Row pass 2 (i8): ARL fp32 fused + next RMSNorm -> per-row i8 quant
// ---------------------------------------------------------------------------
__global__ __launch_bounds__(256) void rowpass2_i8(
    float* __restrict__ x, const float* __restrict__ anw,
    const float* __restrict__ U, const float* __restrict__ Sv,
    const float* __restrict__ V, const float* __restrict__ agam,
    const float* __restrict__ bnw, signed char* __restrict__ xq,
    float* __restrict__ sxn)
{
  const int row = blockIdx.x, tid = threadIdx.x;
  const int lane = tid & 63, wid = tid >> 6;
  float* xr = x + (size_t)row*D_DIM + tid*8;
  f32x4 v0 = *(const f32x4*)xr;
  f32x4 v1 = *(const f32x4*)(xr+4);
  float ssq = 0.0f;
#pragma unroll
  for(int j=0;j<4;++j) ssq += v0[j]*v0[j] + v1[j]*v1[j];
  __shared__ float red[4];
  float t = wredf(ssq);
  if(lane==0) red[wid] = t;
  __syncthreads();
  const float rs = rsqrtf((red[0]+red[1]+red[2]+red[3])*(1.0f/D_DIM) + 1e-6f);

  f32x4 a0 = *(const f32x4*)(anw + tid*8);
  f32x4 a1 = *(const f32x4*)(anw + tid*8 + 4);
  float xn2[8];
#pragma unroll
  for(int j=0;j<4;++j){ xn2[j] = v0[j]*rs*a0[j]; xn2[4+j] = v1[j]*rs*a1[j]; }

  float pl[16];
#pragma unroll
  for(int r2=0;r2<16;++r2) pl[r2] = 0.0f;
#pragma unroll
  for(int j=0;j<8;++j){
    const int k = tid*8 + j;
    const f32x4* Up = (const f32x4*)(U + (size_t)k*R_DIM);
    f32x4 u0=Up[0], u1=Up[1], u2=Up[2], u3=Up[3];
    const float xv = xn2[j];
#pragma unroll
    for(int q=0;q<4;++q){
      pl[q]    += xv*u0[q];
      pl[4+q]  += xv*u1[q];
      pl[8+q]  += xv*u2[q];
      pl[12+q] += xv*u3[q];
    }
  }
#pragma unroll
  for(int r2=0;r2<16;++r2) pl[r2] = wredf(pl[r2]);
  __shared__ float lred[4][16];
  if(lane==0){
#pragma unroll
    for(int r2=0;r2<16;++r2) lred[wid][r2] = pl[r2];
  }
  __syncthreads();
  __shared__ float lowS[16];
  if(tid==0){
    float sa[16]; float totS = 0.0f;
#pragma unroll
    for(int r2=0;r2<16;++r2){ sa[r2] = fabsf(Sv[r2]); totS += sa[r2]; }
    totS = fmaxf(totS, 1e-8f);
    float c = 0.0f;
#pragma unroll
    for(int r2=0;r2<16;++r2){
      float lraw = lred[0][r2]+lred[1][r2]+lred[2][r2]+lred[3][r2];
      float keep = (r2==0) ? 1.0f : ((c/totS < 0.95f) ? 1.0f : 0.0f);
      c += sa[r2];
      lowS[r2] = lraw * Sv[r2] * keep;
    }
  }
  __syncthreads();

  f32x4 d0 = {0,0,0,0}, d1 = {0,0,0,0};
#pragma unroll
  for(int r2=0;r2<16;++r2){
    const float lr = lowS[r2];
    const f32x4* Vp = (const f32x4*)(V + (size_t)r2*D_DIM + tid*8);
    f32x4 q0 = Vp[0], q1 = Vp[1];
#pragma unroll
    for(int j=0;j<4;++j){ d0[j] += lr*q0[j]; d1[j] += lr*q1[j]; }
  }
  f32x4 g0 = *(const f32x4*)(agam + tid*8);
  f32x4 g1 = *(const f32x4*)(agam + tid*8 + 4);
  f32x4 xo0, xo1;
  float ssq2 = 0.0f;
#pragma unroll
  for(int j=0;j<4;++j){
    xo0[j] = v0[j] + d0[j]*g0[j];
    xo1[j] = v1[j] + d1[j]*g1[j];
    ssq2 += xo0[j]*xo0[j] + xo1[j]*xo1[j];
  }
  __syncthreads();
  float t2 = wredf(ssq2);
  if(lane==0) red[wid] = t2;
  __syncthreads();
  const float rs2 = rsqrtf((red[0]+red[1]+red[2]+red[3])*(1.0f/D_DIM) + 1e-6f);
  f32x4 b0 = *(const f32x4*)(bnw + tid*8);
  f32x4 b1 = *(const f32x4*)(bnw + tid*8 + 4);
  float a[8]; float am = 0.0f;
#pragma unroll
  for(int j=0;j<4;++j){
    a[j]   = xo0[j]*rs2*b0[j];
    a[4+j] = xo1[j]*rs2*b1[j];
    am = fmaxf(am, fmaxf(fabsf(a[j]), fabsf(a[4+j])));
  }
  *(f32x4*)xr = xo0;
  *(f32x4*)(xr+4) = xo1;

  float wm = wredmax(am);
  __syncthreads();
  if(lane==0) red[wid] = wm;
  __syncthreads();
  const float rowmax = fmaxf(fmaxf(red[0],red[1]), fmaxf(red[2],red[3]));
  const float guard = fmaxf(rowmax, 1e-12f);
  const float inv = 127.0f/guard;
  i32x2 q;
  q[0] = pack4q(a[0],a[1],a[2],a[3], inv, 127);
  q[1] = pack4q(a[4],a[5],a[6],a[7], inv, 127);
  *(i32x2*)(xq + (size_t)row*D_DIM + tid*8) = q;
  if(tid==0) sxn[row] = guard/127.0f;
}

// ---------------------------------------------------------------------------
// h (bf16) -> per-row i8 + scale; cntp!=nullptr -> only rows < cnt
// ---------------------------------------------------------------------------
__global__ __launch_bounds__(256) void hquant(
    const unsigned short* __restrict__ h, signed char* __restrict__ q,
    float* __restrict__ sh, const int* __restrict__ cntp)
{
  const int row = blockIdx.x, tid = threadIdx.x;
  if(cntp && row >= cntp[0]) return;
  const int lane = tid & 63, wid = tid >> 6;
  const unsigned short* hr = h + (size_t)row*H_DIM + tid*32;
  float v[32]; float am = 0.0f;
#pragma unroll
  for(int c=0;c<4;++c){
    u16x8 u = *(const u16x8*)(hr + c*8);
#pragma unroll
    for(int j=0;j<8;++j){
      float f = bf2f(u[j]);
      v[c*8+j] = f;
      am = fmaxf(am, fabsf(f));
    }
  }
  __shared__ float red[4];
  float wm = wredmax(am);
  if(lane==0) red[wid] = wm;
  __syncthreads();
  const float rowmax = fmaxf(fmaxf(red[0],red[1]), fmaxf(red[2],red[3]));
  const float guard = fmaxf(rowmax, 1e-12f);
  const float inv = 127.0f/guard;
  i32x4 o0, o1;
#pragma unroll
  for(int c=0;c<4;++c)
    o0[c] = pack4q(v[c*4],v[c*4+1],v[c*4+2],v[c*4+3], inv, 127);
#pragma unroll
  for(int c=0;c<4;++c)
    o1[c] = pack4q(v[16+c*4],v[16+c*4+1],v[16+c*4+2],v[16+c*4+3], inv, 127);
  signed char* qp = q + (size_t)row*H_DIM + tid*32;
  *(i32x4*)qp = o0;
  *(i32x4*)(qp+16) = o1;
  if(tid==0) sh[row] = guard/127.0f;
}

// ---------------------------------------------------------------------------
// Fused per-row weight quant: one block per row, single pass (max from regs).
// ---------------------------------------------------------------------------
template<int C>
__global__ __launch_bounds__(256) void wquant_row(const float* __restrict__ w,
                                                  signed char* __restrict__ q,
                                                  float* __restrict__ srow)
{
  constexpr int PER = C/256;
  const int row = blockIdx.x, tid = threadIdx.x;
  const int lane = tid & 63, wid = tid >> 6;
  const float* wr = w + (size_t)row*C + tid*PER;
  float v[PER];
  float am = 0.0f;
#pragma unroll
  for(int j=0;j<PER;j+=4){
    f32x4 t = *(const f32x4*)(wr+j);
#pragma unroll
    for(int e=0;e<4;++e){ v[j+e] = t[e]; am = fmaxf(am, fabsf(t[e])); }
  }
  float wm = wredmax(am);
  __shared__ float red[4];
  if(lane==0) red[wid] = wm;
  __syncthreads();
  const float guard = fmaxf(fmaxf(fmaxf(red[0],red[1]),fmaxf(red[2],red[3])),
                            1e-12f);
  const float inv = 127.0f/guard;
  signed char* qr = q + (size_t)row*C + tid*PER;
#pragma unroll
  for(int j=0;j<PER;j+=8){
    i32x2 o;
    o[0] = pack4q(v[j],v[j+1],v[j+2],v[j+3], inv, 127);
    o[1] = pack4q(v[j+4],v[j+5],v[j+6],v[j+7], inv, 127);
    *(i32x2*)(qr+j) = o;
  }
  if(tid==0) srow[row] = guard/127.0f;
}

// ---------------------------------------------------------------------------
// Ternary absmean (two-stage, deterministic) + ternary quant to i8 {-1,0,1}
// ---------------------------------------------------------------------------
__global__ __launch_bounds__(256) void abs_part(const float* __restrict__ w,
                                                double* __restrict__ part)
{
  const long long n4 = (long long)H_DIM*D_DIM/4;
  const int tid = threadIdx.x;
  const int lane = tid & 63, wid = tid >> 6;
  float s = 0.0f;
  for(long long i = (long long)blockIdx.x*256 + tid; i < n4;
      i += (long long)gridDim.x*256){
    f32x4 v = ((const f32x4*)w)[i];
    s += fabsf(v[0]) + fabsf(v[1]) + fabsf(v[2]) + fabsf(v[3]);
  }
  double ds = wredd((double)s);
  __shared__ double sred[4];
  if(lane==0) sred[wid] = ds;
  __syncthreads();
  if(tid==0) part[blockIdx.x] = sred[0]+sred[1]+sred[2]+sred[3];
}

__global__ __launch_bounds__(256) void abs_final(const double* __restrict__ part,
                                                 float* __restrict__ scale)
{
  const int tid = threadIdx.x;
  const int lane = tid & 63, wid = tid >> 6;
  double s = 0.0;
  for(int i=tid;i<1024;i+=256) s += part[i];
  s = wredd(s);
  __shared__ double sred[4];
  if(lane==0) sred[wid] = s;
  __syncthreads();
  if(tid==0){
    double m = (sred[0]+sred[1]+sred[2]+sred[3]) / ((double)H_DIM*(double)D_DIM);
    scale[0] = (float)fmax(m, 1e-8);
  }
}

__global__ __launch_bounds__(256) void tquant_i8(const float* __restrict__ w,
                                                 const float* __restrict__ scale,
                                                 signed char* __restrict__ q)
{
  const long long n8 = (long long)H_DIM*D_DIM/8;
  const float inv = 1.0f/scale[0];
  for(long long i = (long long)blockIdx.x*256 + threadIdx.x; i < n8;
      i += (long long)gridDim.x*256){
    f32x4 a = ((const f32x4*)w)[2*i];
    f32x4 b = ((const f32x4*)w)[2*i+1];
    i32x2 o;
    o[0] = pack4q(a[0],a[1],a[2],a[3], inv, 1);
    o[1] = pack4q(b[0],b[1],b[2],b[3], inv, 1);
    ((i32x2*)q)[i] = o;
  }
}

// ---------------------------------------------------------------------------
// i8 GEMM, 128x128 tile, BK=128, mfma_i32_16x16x64_i8 (2 k-slices/step).
// LDS row = 128 B = 8 chunks of 16 B; involution chunk swizzle c ^= (row&7).
//  EPI 0: DUAL + A-row GATHER via rowmap; h_c = silu(f1)*f3 -> bf16 (compact)
//  EPI 1: single; silu -> bf16 (full rows; scalar weight scale)
//  EPI 2: single; A compact; SCATTER xacc[rowmap[mc]] += f*gamma (mask mc<cnt)
//  EPI 3: single; xacc += f*gamma (full rows; scalar weight scale)
// Per-col weight scales for EPI 0/2 (sW0/sW1 arrays); scalar for EPI 1/3.
// ---------------------------------------------------------------------------
template<int EPI>
__global__ __launch_bounds__(256, 2) void gemmq(
    const signed char* __restrict__ A,
    const signed char* __restrict__ B0,
    const signed char* __restrict__ B1,
    const int Nout, const int K,
    const float* __restrict__ sArow,
    const float* __restrict__ sW0,
    const float* __restrict__ sW1,
    const int* __restrict__ rowmap,
    const int* __restrict__ cntp,
    unsigned short* __restrict__ obf,
    float* __restrict__ xacc,
    const float* __restrict__ gamma)
{
  constexpr bool DUAL    = (EPI==0);
  constexpr bool GATHER  = (EPI==0);
  constexpr bool SCATTER = (EPI==2);
  constexpr bool CMP     = GATHER || SCATTER;

  __shared__ __align__(16) signed char smA[128*128];
  __shared__ __align__(16) signed char smB[128*128];
  __shared__ __align__(16) signed char smB2[DUAL?(128*128):16];

  int cnt = 0;
  if constexpr (CMP) cnt = cntp[0];
  const int padded = CMP ? ((cnt+127)&~127) : (1<<30);

  const int tid  = threadIdx.x;
  const int lane = tid & 63;
  const int wid  = tid >> 6;
  const int wr   = wid >> 1;
  const int wc   = wid & 1;
  const int frow = lane & 15;
  const int k16  = lane >> 4;

  const int nwg = (int)gridDim.x;
  const int bid = (int)blockIdx.x;
  const int swz = ((bid & 7) * (nwg >> 3)) + (bid >> 3);
  const int rowBase = (swz & 31) << 7;       // 32 M-tiles, rows fast in chunk
  const int colBase = (swz >> 5) << 7;

  if constexpr (CMP){ if(rowBase >= padded) return; }

  // staging map: 4 units x 256 threads = 1024 chunks of 16B per matrix
  const signed char* Asrc[4];
  const signed char* Bsrc[4];
  const signed char* B2src[4];
#pragma unroll
  for(int u=0;u<4;++u){
    int L = u*256 + tid;
    int row = L >> 3, c = L & 7;
    int soff = (c ^ (row & 7)) * 16;
    int arow;
    if constexpr (GATHER) arow = rowmap[rowBase + row];
    else                  arow = rowBase + row;
    Asrc[u] = A + (size_t)arow*K + soff;
    Bsrc[u] = B0 + (size_t)(colBase + row)*K + soff;
    if constexpr (DUAL) B2src[u] = B1 + (size_t)(colBase + row)*K + soff;
  }

  const i32x4 izero = {0,0,0,0};
  i32x4 acc[4][4];
  i32x4 acc2[4][4];
#pragma unroll
  for(int m=0;m<4;++m)
#pragma unroll
    for(int n=0;n<4;++n){ acc[m][n] = izero; acc2[m][n] = izero; }

  for(int k0=0;k0<K;k0+=128){
#pragma unroll
    for(int u=0;u<4;++u) gload_lds16(Asrc[u]+k0, &smA[u*4096 + tid*16]);
#pragma unroll
    for(int u=0;u<4;++u) gload_lds16(Bsrc[u]+k0, &smB[u*4096 + tid*16]);
    if constexpr (DUAL){
#pragma unroll
      for(int u=0;u<4;++u) gload_lds16(B2src[u]+k0, &smB2[u*4096 + tid*16]);
    }
    __syncthreads();

#pragma unroll
    for(int ks=0;ks<2;++ks){
      i32x4 af[4], bfr[4], bfr2[4];
#pragma unroll
      for(int m=0;m<4;++m){
        int rr = (wr<<6)+(m<<4)+frow;
        int cc = (ks*4 + k16) ^ (rr & 7);
        af[m] = *(const i32x4*)&smA[rr*128 + cc*16];
      }
#pragma unroll
      for(int n=0;n<4;++n){
        int rr = (wc<<6)+(n<<4)+frow;
        int cc = (ks*4 + k16) ^ (rr & 7);
        bfr[n] = *(const i32x4*)&smB[rr*128 + cc*16];
        if constexpr (DUAL) bfr2[n] = *(const i32x4*)&smB2[rr*128 + cc*16];
      }
#pragma unroll
      for(int m=0;m<4;++m)
#pragma unroll
        for(int n=0;n<4;++n){
          acc[m][n] = __builtin_amdgcn_mfma_i32_16x16x64_i8(af[m], bfr[n], acc[m][n], 0,0,0);
          if constexpr (DUAL)
            acc2[m][n] = __builtin_amdgcn_mfma_i32_16x16x64_i8(af[m], bfr2[n], acc2[m][n], 0,0,0);
        }
    }
    __syncthreads();
  }

  // ---- epilogue.  C/D layout: col = lane&15, row = (lane>>4)*4 + j
  float fsW0 = 0.0f;
  if constexpr (EPI==1 || EPI==3) fsW0 = sW0[0];
  const int growB = rowBase + (wr<<6) + (k16<<2);
  const int gcolB = colBase + (wc<<6) + frow;
#pragma unroll
  for(int m=0;m<4;++m){
#pragma unroll
    for(int n=0;n<4;++n){
      const int grow0 = growB + (m<<4);
      const int gcol  = gcolB + (n<<4);
      i32x4 v = acc[m][n];
      if constexpr (EPI==0){
        i32x4 v2 = acc2[m][n];
        const float w0 = sW0[gcol];
        const float w1s = sW1[gcol];
#pragma unroll
        for(int j=0;j<4;++j){
          const int mc = grow0 + j;
          const float sa = sArow[rowmap[mc]];
          float f1 = (float)v[j]  * sa * w0;
          float f3 = (float)v2[j] * sa * w1s;
          float hv = (f1/(1.0f+expf(-f1))) * f3;
          obf[(size_t)mc*Nout + gcol] = f2bf(hv);
        }
      } else if constexpr (EPI==1){
#pragma unroll
        for(int j=0;j<4;++j){
          const float sa = sArow[grow0+j];
          float f = (float)v[j] * sa * fsW0;
          obf[(size_t)(grow0+j)*Nout + gcol] = f2bf(f/(1.0f+expf(-f)));
        }
      } else if constexpr (EPI==2){
        const float gw = sW0[gcol]*gamma[gcol];
#pragma unroll
        for(int j=0;j<4;++j){
          const int mc = grow0 + j;
          if(mc < cnt){
            const float sa = sArow[mc];
            xacc[(size_t)rowmap[mc]*Nout + gcol] += (float)v[j] * sa * gw;
          }
        }
      } else {
        const float gw = fsW0*gamma[gcol];
#pragma unroll
        for(int j=0;j<4;++j){
          const float sa = sArow[grow0+j];
          xacc[(size_t)(grow0+j)*Nout + gcol] += (float)v[j] * sa * gw;
        }
      }
    }
  }
}

// ===========================================================================
// Fallback path kernels (round-1 proven): bf16 GEMM, bf16 rowpasses, bf16 tquant
// ===========================================================================
__global__ __launch_bounds__(256) void rowpass1(
    const float* __restrict__ x, const float* __restrict__ nw,
    const float* __restrict__ rw, unsigned short* __restrict__ xn,
    float* __restrict__ act)
{
  const int row = blockIdx.x, tid = threadIdx.x;
  const int lane = tid & 63, wid = tid >> 6;
  const float* xr = x + (size_t)row*D_DIM + tid*8;
  f32x4 v0 = *(const f32x4*)xr;
  f32x4 v1 = *(const f32x4*)(xr+4);
  float ssq = 0.0f;
#pragma unroll
  for(int j=0;j<4;++j) ssq += v0[j]*v0[j] + v1[j]*v1[j];
  __shared__ float red[4];
  float t = wredf(ssq);
  if(lane==0) red[wid] = t;
  __syncthreads();
  const float rs = rsqrtf((red[0]+red[1]+red[2]+red[3])*(1.0f/D_DIM) + 1e-6f);
  f32x4 n0 = *(const f32x4*)(nw + tid*8);
  f32x4 n1 = *(const f32x4*)(nw + tid*8 + 4);
  f32x4 r0 = *(const f32x4*)(rw + tid*8);
  f32x4 r1 = *(const f32x4*)(rw + tid*8 + 4);
  float gp = 0.0f;
  u16x4 o0, o1;
#pragma unroll
  for(int j=0;j<4;++j){
    float a = v0[j]*rs*n0[j];
    float b = v1[j]*rs*n1[j];
    gp += a*r0[j] + b*r1[j];
    o0[j] = f2bf(a);
    o1[j] = f2bf(b);
  }
  unsigned short* xp = xn + (size_t)row*D_DIM + tid*8;
  *(u16x4*)xp = o0;
  *(u16x4*)(xp+4) = o1;
  float gd = wredf(gp);
  __syncthreads();
  if(lane==0) red[wid] = gd;
  __syncthreads();
  if(tid==0){
    float dot = red[0]+red[1]+red[2]+red[3];
    float g = 1.0f/(1.0f+expf(-dot));
    act[row] = (g > 0.35f) ? 1.0f : 0.0f;
  }
}

__global__ __launch_bounds__(256) void rowpass2(
    float* __restrict__ x, const float* __restrict__ anw,
    const float* __restrict__ U, const float* __restrict__ Sv,
    const float* __restrict__ V, const float* __restrict__ agam,
    const float* __restrict__ bnw, unsigned short* __restrict__ xn3)
{
  const int row = blockIdx.x, tid = threadIdx.x;
  const int lane = tid & 63, wid = tid >> 6;
  float* xr = x + (size_t)row*D_DIM + tid*8;
  f32x4 v0 = *(const f32x4*)xr;
  f32x4 v1 = *(const f32x4*)(xr+4);
  float ssq = 0.0f;
#pragma unroll
  for(int j=0;j<4;++j) ssq += v0[j]*v0[j] + v1[j]*v1[j];
  __shared__ float red[4];
  float t = wredf(ssq);
  if(lane==0) red[wid] = t;
  __syncthreads();
  const float rs = rsqrtf((red[0]+red[1]+red[2]+red[3])*(1.0f/D_DIM) + 1e-6f);
  f32x4 a0 = *(const f32x4*)(anw + tid*8);
  f32x4 a1 = *(const f32x4*)(anw + tid*8 + 4);
  float xn2[8];
#pragma unroll
  for(int j=0;j<4;++j){ xn2[j] = v0[j]*rs*a0[j]; xn2[4+j] = v1[j]*rs*a1[j]; }
  float pl[16];
#pragma unroll
  for(int r2=0;r2<16;++r2) pl[r2] = 0.0f;
#pragma unroll
  for(int j=0;j<8;++j){
    const int k = tid*8 + j;
    const f32x4* Up = (const f32x4*)(U + (size_t)k*R_DIM);
    f32x4 u0=Up[0], u1=Up[1], u2=Up[2], u3=Up[3];
    const float xv = xn2[j];
#pragma unroll
    for(int q=0;q<4;++q){
      pl[q] += xv*u0[q]; pl[4+q] += xv*u1[q];
      pl[8+q] += xv*u2[q]; pl[12+q] += xv*u3[q];
    }
  }
#pragma unroll
  for(int r2=0;r2<16;++r2) pl[r2] = wredf(pl[r2]);
  __shared__ float lred[4][16];
  if(lane==0){
#pragma unroll
    for(int r2=0;r2<16;++r2) lred[wid][r2] = pl[r2];
  }
  __syncthreads();
  __shared__ float lowS[16];
  if(tid==0){
    float sa[16]; float totS = 0.0f;
#pragma unroll
    for(int r2=0;r2<16;++r2){ sa[r2] = fabsf(Sv[r2]); totS += sa[r2]; }
    totS = fmaxf(totS, 1e-8f);
    float c = 0.0f;
#pragma unroll
    for(int r2=0;r2<16;++r2){
      float lraw = lred[0][r2]+lred[1][r2]+lred[2][r2]+lred[3][r2];
      float keep = (r2==0) ? 1.0f : ((c/totS < 0.95f) ? 1.0f : 0.0f);
      c += sa[r2];
      lowS[r2] = lraw * Sv[r2] * keep;
    }
  }
  __syncthreads();
  f32x4 d0 = {0,0,0,0}, d1 = {0,0,0,0};
#pragma unroll
  for(int r2=0;r2<16;++r2){
    const float lr = lowS[r2];
    const f32x4* Vp = (const f32x4*)(V + (size_t)r2*D_DIM + tid*8);
    f32x4 q0 = Vp[0], q1 = Vp[1];
#pragma unroll
    for(int j=0;j<4;++j){ d0[j] += lr*q0[j]; d1[j] += lr*q1[j]; }
  }
  f32x4 g0 = *(const f32x4*)(agam + tid*8);
  f32x4 g1 = *(const f32x4*)(agam + tid*8 + 4);
  f32x4 xo0, xo1;
  float ssq2 = 0.0f;
#pragma unroll
  for(int j=0;j<4;++j){
    xo0[j] = v0[j] + d0[j]*g0[j];
    xo1[j] = v1[j] + d1[j]*g1[j];
    ssq2 += xo0[j]*xo0[j] + xo1[j]*xo1[j];
  }
  __syncthreads();
  float t2 = wredf(ssq2);
  if(lane==0) red[wid] = t2;
  __syncthreads();
  const float rs2 = rsqrtf((red[0]+red[1]+red[2]+red[3])*(1.0f/D_DIM) + 1e-6f);
  f32x4 b0 = *(const f32x4*)(bnw + tid*8);
  f32x4 b1 = *(const f32x4*)(bnw + tid*8 + 4);
  u16x4 o0, o1;
#pragma unroll
  for(int j=0;j<4;++j){
    o0[j] = f2bf(xo0[j]*rs2*b0[j]);
    o1[j] = f2bf(xo1[j]*rs2*b1[j]);
  }
  *(f32x4*)xr = xo0;
  *(f32x4*)(xr+4) = xo1;
  unsigned short* xp = xn3 + (size_t)row*D_DIM + tid*8;
  *(u16x4*)xp = o0;
  *(u16x4*)(xp+4) = o1;
}

__global__ __launch_bounds__(256) void tquant(const float* __restrict__ w,
                                              const float* __restrict__ scale,
                                              unsigned short* __restrict__ q)
{
  const long long n4 = (long long)H_DIM*D_DIM/4;
  const float s = scale[0];
  for(long long i = (long long)blockIdx.x*256 + threadIdx.x; i < n4;
      i += (long long)gridDim.x*256){
    f32x4 v = ((const f32x4*)w)[i];
    u16x4 o;
#pragma unroll
    for(int j=0;j<4;++j){
      float r = rintf(v[j]/s);
      r = fminf(1.0f, fmaxf(-1.0f, r));
      o[j] = f2bf(r*s);
    }
    ((u16x4*)q)[i] = o;
  }
}

template<int EPI, bool BBF16, bool DUAL>
__global__ __launch_bounds__(256, DUAL?2:3) void gemm128(
    const unsigned short* __restrict__ A,
    const void* __restrict__ B0v,
    const void* __restrict__ B1v,
    const int Nout, const int K,
    unsigned short* __restrict__ obf,
    float* __restrict__ xacc,
    const float* __restrict__ gamma,
    const float* __restrict__ act)
{
  __shared__ __align__(16) unsigned short smA[128*32];
  __shared__ __align__(16) unsigned short smB[128*32];
  __shared__ __align__(16) unsigned short smB2[DUAL?(128*32):8];

  const int tid  = threadIdx.x;
  const int lane = tid & 63;
  const int wid  = tid >> 6;
  const int wr   = wid >> 1;
  const int wc   = wid & 1;
  const int frow = lane & 15;
  const int k16  = lane >> 4;

  const int nwg = (int)gridDim.x;
  const int bid = (int)blockIdx.x;
  const int swz = ((bid & 7) * (nwg >> 3)) + (bid >> 3);
  const int rowBase = (swz & 31) << 7;
  const int colBase = (swz >> 5) << 7;

  int srow[2], schk[2];
#pragma unroll
  for(int r=0;r<2;++r){
    int t = tid + (r<<8);
    srow[r] = t >> 2;
    schk[r] = (t & 3) ^ ((srow[r] >> 1) & 3);
  }

  const f32x4 vzero = {0.0f,0.0f,0.0f,0.0f};
  f32x4 acc[4][4];
  f32x4 acc2[4][4];
#pragma unroll
  for(int m=0;m<4;++m)
#pragma unroll
    for(int n=0;n<4;++n){ acc[m][n] = vzero; acc2[m][n] = vzero; }

  for(int k0=0;k0<K;k0+=32){
#pragma unroll
    for(int r=0;r<2;++r){
      const unsigned short* s = A + (size_t)(rowBase+srow[r])*K + k0 + schk[r]*8;
      gload_lds16(s, &smA[((r<<8)+(wid<<6))*8]);
    }
    if constexpr (BBF16){
      const unsigned short* B0 = (const unsigned short*)B0v;
#pragma unroll
      for(int r=0;r<2;++r){
        const unsigned short* s = B0 + (size_t)(colBase+srow[r])*K + k0 + schk[r]*8;
        gload_lds16(s, &smB[((r<<8)+(wid<<6))*8]);
      }
    } else {
      const float* B0 = (const float*)B0v;
#pragma unroll
      for(int r=0;r<2;++r){
        const float* s = B0 + (size_t)(colBase+srow[r])*K + k0 + schk[r]*8;
        f32x4 f0 = *(const f32x4*)s;
        f32x4 f1 = *(const f32x4*)(s+4);
        u16x8 o;
#pragma unroll
        for(int j=0;j<4;++j){ o[j] = f2bf(f0[j]); o[4+j] = f2bf(f1[j]); }
        *(u16x8*)&smB[(size_t)(tid+(r<<8))*8] = o;
      }
      if constexpr (DUAL){
        const float* B1 = (const float*)B1v;
#pragma unroll
        for(int r=0;r<2;++r){
          const float* s = B1 + (size_t)(colBase+srow[r])*K + k0 + schk[r]*8;
          f32x4 f0 = *(const f32x4*)s;
          f32x4 f1 = *(const f32x4*)(s+4);
          u16x8 o;
#pragma unroll
          for(int j=0;j<4;++j){ o[j] = f2bf(f0[j]); o[4+j] = f2bf(f1[j]); }
          *(u16x8*)&smB2[(size_t)(tid+(r<<8))*8] = o;
        }
      }
    }
    __syncthreads();

    bf16x8 af[4];
#pragma unroll
    for(int m=0;m<4;++m){
      int rr = (wr<<6)+(m<<4)+frow;
      int ch = k16 ^ ((rr>>1)&3);
      af[m] = *(const bf16x8*)&smA[rr*32 + ch*8];
    }
    bf16x8 bfr[4];
    bf16x8 bfr2[4];
#pragma unroll
    for(int n=0;n<4;++n){
      int rr = (wc<<6)+(n<<4)+frow;
      int ch = k16 ^ ((rr>>1)&3);
      bfr[n] = *(const bf16x8*)&smB[rr*32 + ch*8];
      if constexpr (DUAL) bfr2[n] = *(const bf16x8*)&smB2[rr*32 + ch*8];
    }
#pragma unroll
    for(int m=0;m<4;++m)
#pragma unroll
      for(int n=0;n<4;++n){
        acc[m][n] = __builtin_amdgcn_mfma_f32_16x16x32_bf16(af[m], bfr[n], acc[m][n], 0,0,0);
        if constexpr (DUAL)
          acc2[m][n] = __builtin_amdgcn_mfma_f32_16x16x32_bf16(af[m], bfr2[n], acc2[m][n], 0,0,0);
      }
    __syncthreads();
  }

  const int growB = rowBase + (wr<<6) + (k16<<2);
  const int gcolB = colBase + (wc<<6) + frow;
#pragma unroll
  for(int m=0;m<4;++m){
#pragma unroll
    for(int n=0;n<4;++n){
      const int grow0 = growB + (m<<4);
      const int gcol  = gcolB + (n<<4);
      f32x4 v = acc[m][n];
      if constexpr (EPI==0){
        f32x4 v2 = acc2[m][n];
#pragma unroll
        for(int j=0;j<4;++j){
          float t1 = v[j];
          float hv = (t1/(1.0f+expf(-t1))) * v2[j];
          obf[(size_t)(grow0+j)*Nout + gcol] = f2bf(hv);
        }
      } else if constexpr (EPI==1){
#pragma unroll
        for(int j=0;j<4;++j){
          float t1 = v[j];
          obf[(size_t)(grow0+j)*Nout + gcol] = f2bf(t1/(1.0f+expf(-t1)));
        }
      } else if constexpr (EPI==2){
        const float g = gamma[gcol];
#pragma unroll
        for(int j=0;j<4;++j){
          if(act[grow0+j] != 0.0f){
            const size_t ix = (size_t)(grow0+j)*Nout + gcol;
            xacc[ix] += v[j]*g;
          }
        }
      } else {
        const float g = gamma[gcol];
#pragma unroll
        for(int j=0;j<4;++j){
          const size_t ix = (size_t)(grow0+j)*Nout + gcol;
          xacc[ix] += v[j]*g;
        }
      }
    }
  }
}

// ---------------------------------------------------------------------------
extern "C" void kernel_launch(void* const* d_in, const int* in_sizes, int n_in,
                              void* d_out, int out_size, void* d_ws, size_t ws_size,
                              hipStream_t stream)
{
  (void)in_sizes; (void)n_in; (void)out_size;
  const float* x_in  = (const float*)d_in[0];
  const float* acbnw = (const float*)d_in[1];
  const float* routw = (const float*)d_in[2];
  const float* w1    = (const float*)d_in[3];
  const float* w2    = (const float*)d_in[4];
  const float* w3    = (const float*)d_in[5];
  const float* acbg  = (const float*)d_in[6];
  const float* arlnw = (const float*)d_in[7];
  const float* U     = (const float*)d_in[8];
  const float* Sv    = (const float*)d_in[9];
  const float* V     = (const float*)d_in[10];
  const float* arlg  = (const float*)d_in[11];
  const float* bitnw = (const float*)d_in[12];
  const float* wup   = (const float*)d_in[13];
  const float* wdn   = (const float*)d_in[14];
  const float* bitg  = (const float*)d_in[15];

  float* xs = (float*)d_out;           // x state lives in d_out (fp32 [N,D])
  char* ws = (char*)d_ws;

  const bool big = (ws_size >= (size_t)185000000);

  hipMemcpyAsync(xs, x_in, (size_t)NTOK*D_DIM*sizeof(float),
                 hipMemcpyDeviceToDevice, stream);

  if (big) {
    const size_t MB = 1048576;
    unsigned short* hb   = (unsigned short*)(ws);             // 64 MiB bf16 h
    signed char*    xnq  = (signed char*)(ws + 64*MB);        //  8 MiB i8 xn
    signed char*    hbq  = (signed char*)(ws + 72*MB);        // 32 MiB i8 h
    signed char*    slotA= (signed char*)(ws + 104*MB);       // 16 MiB i8 wts
    signed char*    slotB= (signed char*)(ws + 120*MB);       // 16 MiB i8 wts
    char* tail = ws + 136*MB;
    float*  sxn   = (float*)(tail);                 // 16 KiB
    float*  sh    = (float*)(tail + 16384);         // 16 KiB
    float*  act   = (float*)(tail + 32768);         // 16 KiB
    double* dpart = (double*)(tail + 49152);        //  8 KiB
    float*  scb   = (float*)(tail + 57344);         // ternary scales
    float*  sWA   = (float*)(tail + 65536);         // 32 KiB per-row w scales
    float*  sWB   = (float*)(tail + 98304);         // 32 KiB
    int*    rowmap= (int*)(tail + 131072);          // 16 KiB
    int*    cntp  = (int*)(tail + 147456);          // 4 B

    const int gH = 2048;   // (4096/128)*(8192/128)
    const int gD = 512;    // (4096/128)*(2048/128)

    for(int d=0; d<DEPTH; ++d){
      const size_t oD  = (size_t)d*D_DIM;
      const size_t oHD = (size_t)d*H_DIM*D_DIM;
      const size_t oR  = (size_t)d*R_DIM;
      const size_t oDR = (size_t)d*D_DIM*R_DIM;

      // ---- AdaptiveComputeBlock (i8, row-compacted)
      wquant_row<D_DIM><<<H_DIM,256,0,stream>>>(w1+oHD, slotA, sWA);
      wquant_row<D_DIM><<<H_DIM,256,0,stream>>>(w3+oHD, slotB, sWB);
      rowpass1_i8<<<NTOK,256,0,stream>>>(xs, acbnw+oD, routw+oD, xnq, sxn, act);
      buildmap<<<1,256,0,stream>>>(act, rowmap, cntp);
      gemmq<0><<<gH,256,0,stream>>>(
          xnq, slotA, slotB, H_DIM, D_DIM, sxn, sWA, sWB, rowmap, cntp,
          hb, nullptr, nullptr);
      hquant<<<NTOK,256,0,stream>>>(hb, hbq, sh, cntp);
      wquant_row<H_DIM><<<D_DIM,256,0,stream>>>(w2+oHD, slotA, sWA);
      gemmq<2><<<gD,256,0,stream>>>(
          hbq, slotA, nullptr, D_DIM, H_DIM, sh, sWA, nullptr, rowmap, cntp,
          nullptr, xs, acbg+oD);

      // ---- AdaptiveRankLinear (fp32) + BitLinear input norm -> i8
      rowpass2_i8<<<NTOK,256,0,stream>>>(xs, arlnw+oD, U+oDR, Sv+oR, V+oDR,
                                         arlg+oD, bitnw+oD, xnq, sxn);

      // ---- BitLinear (i8, exact ternary weights)
      abs_part<<<1024,256,0,stream>>>(wup+oHD, dpart);
      abs_final<<<1,256,0,stream>>>(dpart, scb+0);
      tquant_i8<<<2048,256,0,stream>>>(wup+oHD, scb+0, slotB);
      gemmq<1><<<gH,256,0,stream>>>(
          xnq, slotB, nullptr, H_DIM, D_DIM, sxn, scb+0, nullptr,
          nullptr, nullptr, hb, nullptr, nullptr);
      hquant<<<NTOK,256,0,stream>>>(hb, hbq, sh, nullptr);
      abs_part<<<1024,256,0,stream>>>(wdn+oHD, dpart);
      abs_final<<<1,256,0,stream>>>(dpart, scb+1);
      tquant_i8<<<2048,256,0,stream>>>(wdn+oHD, scb+1, slotA);
      gemmq<3><<<gD,256,0,stream>>>(
          hbq, slotA, nullptr, D_DIM, H_DIM, sh, scb+1, nullptr,
          nullptr, nullptr, nullptr, xs, bitg+oD);
    }
  } else {
    // fallback: round-1 layout (bf16 GEMMs, fp32 B reg-staged)
    unsigned short* xn = (unsigned short*)(ws);                 // 16 MiB
    unsigned short* hb = (unsigned short*)(ws + 16777216);      // 64 MiB
    unsigned short* qb = (unsigned short*)(ws + 83886080);      // 32 MiB
    float*  act   = (float*)(ws + 117440512);
    double* parts = (double*)(ws + 117456896);
    float*  scal  = (float*)(ws + 117465088);

    const int gH = 2048;
    const int gD = 512;

    for(int d=0; d<DEPTH; ++d){
      const size_t oD  = (size_t)d*D_DIM;
      const size_t oHD = (size_t)d*H_DIM*D_DIM;
      const size_t oR  = (size_t)d*R_DIM;
      const size_t oDR = (size_t)d*D_DIM*R_DIM;

      rowpass1<<<NTOK,256,0,stream>>>(xs, acbnw+oD, routw+oD, xn, act);
      gemm128<0,false,true><<<gH,256,0,stream>>>(
          xn, w1+oHD, w3+oHD, H_DIM, D_DIM, hb, nullptr, nullptr, nullptr);
      gemm128<2,false,false><<<gD,256,0,stream>>>(
          hb, w2+oHD, nullptr, D_DIM, H_DIM, nullptr, xs, acbg+oD, act);

      rowpass2<<<NTOK,256,0,stream>>>(xs, arlnw+oD, U+oDR, Sv+oR, V+oDR,
                                      arlg+oD, bitnw+oD, xn);

      abs_part<<<1024,256,0,stream>>>(wup+oHD, parts);
      abs_final<<<1,256,0,stream>>>(parts, scal);
      tquant<<<2048,256,0,stream>>>(wup+oHD, scal, qb);
      gemm128<1,true,false><<<gH,256,0,stream>>>(
          xn, qb, nullptr, H_DIM, D_DIM, hb, nullptr, nullptr, nullptr);

      abs_part<<<1024,256,0,stream>>>(wdn+oHD, parts);
      abs_final<<<1,256,0,stream>>>(parts, scal);
      tquant<<<2048,256,0,stream>>>(wdn+oHD, scal, qb);
      gemm128<3,true,false><<<gD,256,0,stream>>>(
          hb, qb, nullptr, D_DIM, H_DIM, nullptr, xs, bitg+oD, nullptr);
    }
  }
}